// Round 8
// baseline (1777.714 us; speedup 1.0000x reference)
//
#include <hip/hip_runtime.h>
#include <hip/hip_bf16.h>

#define N_NODES 50000
#define N_EDGES 800000
#define F_IN 9
#define H 128
#define G_GRAPHS 64
#define HH (H * H)

typedef short bf16x8 __attribute__((ext_vector_type(8)));
typedef float f32x4 __attribute__((ext_vector_type(4)));

static __device__ inline short f2b(float f) {
    __hip_bfloat16 h = __float2bfloat16(f);
    return *reinterpret_cast<short*>(&h);
}
static __device__ inline float blo(unsigned u) { return __uint_as_float(u << 16); }
static __device__ inline float bhi(unsigned u) { return __uint_as_float(u & 0xFFFF0000u); }

// ---------- dtype detection ----------
__global__ __launch_bounds__(256) void k_detect(const unsigned* __restrict__ x, int* flag) {
    __shared__ int cnt;
    if (threadIdx.x == 0) cnt = 0;
    __syncthreads();
    unsigned u = x[threadIdx.x];
    int e = (u >> 7) & 0xFF;
    if (e >= 0x70 && e <= 0x83) atomicAdd(&cnt, 1);
    __syncthreads();
    if (threadIdx.x == 0) *flag = (cnt >= 128) ? 1 : 0;
}

// ---------- batched convert of all float inputs ----------
struct CvtArgs { const void* src[15]; float* dst[15]; };

__global__ __launch_bounds__(256) void k_cvt_all(CvtArgs a, const int* __restrict__ flag) {
    const int sz[15] = {450000, 1152, 128, 16384, 128, 32768, 128, 16384, 128,
                        16384, 128, 4096, 32, 32, 1};
    int i = blockIdx.x * 256 + threadIdx.x;
    int fl = *flag;
    int base = 0;
    #pragma unroll
    for (int s = 0; s < 15; ++s) {
        if (i >= base && i < base + sz[s]) {
            int off = i - base;
            float v = fl ? __bfloat162float(((const __hip_bfloat16*)a.src[s])[off])
                         : ((const float*)a.src[s])[off];
            a.dst[s][off] = v;
        }
        base += sz[s];
    }
}

__global__ __launch_bounds__(256) void k_zero(float* p, int n) {
    int i = blockIdx.x * 256 + threadIdx.x;
    if (i < n) p[i] = 0.f;
}

__global__ __launch_bounds__(256) void k_sub(float* w) {
    int i = blockIdx.x * 256 + threadIdx.x;
    if (i < HH) w[i] -= w[HH + i];
}

// ---------- W[128,NT*16] f32 -> bf16 MFMA B-fragment table ----------
__global__ __launch_bounds__(256) void k_prep(const float* __restrict__ W,
                                              short* __restrict__ Wf, int NT) {
    int tid = blockIdx.x * 256 + threadIdx.x;
    int total = 4 * NT * 64;
    if (tid >= total) return;
    int kc = tid / (NT * 64);
    int ct = (tid / 64) % NT;
    int lane = tid & 63;
    int Nc = NT * 16;
    int kb = kc * 32 + (lane >> 4) * 8;
    int col = ct * 16 + (lane & 15);
    #pragma unroll
    for (int j = 0; j < 8; ++j)
        Wf[tid * 8 + j] = f2b(W[(kb + j) * Nc + col]);
}

// ---------- CSR build ----------
__global__ __launch_bounds__(256) void k_hist(const int* __restrict__ dst, int* cnt) {
    int e = blockIdx.x * 256 + threadIdx.x;
    if (e < N_EDGES) atomicAdd(&cnt[dst[e]], 1);
}

__global__ __launch_bounds__(256) void k_scan1(const int* __restrict__ deg, int* __restrict__ out,
                                               int* __restrict__ blockSums) {
    __shared__ int lds[256];
    int base = blockIdx.x * 2048;
    int t = threadIdx.x;
    int local[8];
    int s = 0;
    #pragma unroll
    for (int j = 0; j < 8; ++j) {
        int idx = base + t * 8 + j;
        int v = (idx < N_NODES) ? deg[idx] : 0;
        local[j] = s;
        s += v;
    }
    lds[t] = s;
    __syncthreads();
    if (t == 0) {
        int run = 0;
        for (int i = 0; i < 256; ++i) { int v = lds[i]; lds[i] = run; run += v; }
        blockSums[blockIdx.x] = run;
    }
    __syncthreads();
    int offs = lds[t];
    #pragma unroll
    for (int j = 0; j < 8; ++j) {
        int idx = base + t * 8 + j;
        if (idx < N_NODES) out[idx] = offs + local[j];
    }
}

__global__ void k_scan2(int* blockSums, int nb, int* rowptr) {
    int run = 0;
    for (int i = 0; i < nb; ++i) { int v = blockSums[i]; blockSums[i] = run; run += v; }
    rowptr[N_NODES] = N_EDGES;
}

__global__ __launch_bounds__(256) void k_scan3(int* rowptr, const int* __restrict__ blockSums) {
    int idx = blockIdx.x * 256 + threadIdx.x;
    if (idx < N_NODES) rowptr[idx] += blockSums[idx >> 11];
}

__global__ __launch_bounds__(256) void k_scatter(const int* __restrict__ src, const int* __restrict__ dst,
                                                 const int* __restrict__ rowptr, int* cursor,
                                                 int* __restrict__ csr_src) {
    int e = blockIdx.x * 256 + threadIdx.x;
    if (e >= N_EDGES) return;
    int d = dst[e];
    int pos = rowptr[d] + atomicAdd(&cursor[d], 1);
    csr_src[pos] = src[e];
}

__global__ __launch_bounds__(256) void k_dis(const int* __restrict__ rowptr, float* dis) {
    int n = blockIdx.x * 256 + threadIdx.x;
    if (n < N_NODES) {
        float deg = (float)(rowptr[n + 1] - rowptr[n]);
        dis[n] = rsqrtf(deg + 1.0f);
    }
}

// ---------- counts per graph ----------
__global__ __launch_bounds__(256) void k_counts(const int* __restrict__ batch, float* counts) {
    __shared__ float lc[G_GRAPHS];
    int tid = threadIdx.x;
    if (tid < G_GRAPHS) lc[tid] = 0.f;
    __syncthreads();
    int n = blockIdx.x * 256 + tid;
    if (n < N_NODES) atomicAdd(&lc[batch[n]], 1.0f);
    __syncthreads();
    if (tid < G_GRAPHS && lc[tid] > 0.f) atomicAdd(&counts[tid], lc[tid]);
}

// ---------- GCN1 GEMM: out = (x[M,9] @ W1[9,128]) * dis[row], bf16 ----------
__global__ __launch_bounds__(256) void k_gemm_f32bf_scale(const float* __restrict__ A,
                                                          const float* __restrict__ W,
                                                          const float* __restrict__ dis,
                                                          short* __restrict__ out, int M) {
    __shared__ float w_lds[F_IN * H];
    for (int i = threadIdx.x; i < F_IN * H; i += 256) w_lds[i] = W[i];
    __syncthreads();
    int row = blockIdx.x * 8 + threadIdx.x / 32;
    int c4 = (threadIdx.x & 31) << 2;
    if (row >= M) return;
    const float* a = A + (size_t)row * F_IN;
    float acc0 = 0.f, acc1 = 0.f, acc2 = 0.f, acc3 = 0.f;
    #pragma unroll
    for (int k = 0; k < F_IN; ++k) {
        float av = a[k];
        float4 w = *reinterpret_cast<const float4*>(&w_lds[k * H + c4]);
        acc0 = fmaf(av, w.x, acc0);
        acc1 = fmaf(av, w.y, acc1);
        acc2 = fmaf(av, w.z, acc2);
        acc3 = fmaf(av, w.w, acc3);
    }
    float dv = dis[row];
    short* op = &out[(size_t)row * H + c4];
    op[0] = f2b(acc0 * dv); op[1] = f2b(acc1 * dv);
    op[2] = f2b(acc2 * dv); op[3] = f2b(acc3 * dv);
}

// ---------- dual MFMA GEMM: U = A@WU + be1 ; V = A@WV ----------
__global__ __launch_bounds__(256) void k_gemm_dual(const short* __restrict__ A,
                                                   const short* __restrict__ WfU,
                                                   const short* __restrict__ WfV,
                                                   const float* __restrict__ be1,
                                                   short* __restrict__ U,
                                                   short* __restrict__ V, int M) {
    __shared__ short wl[32768];
    for (int i = threadIdx.x * 8; i < 16384; i += 2048) {
        *reinterpret_cast<f32x4*>(&wl[i])         = *reinterpret_cast<const f32x4*>(&WfU[i]);
        *reinterpret_cast<f32x4*>(&wl[16384 + i]) = *reinterpret_cast<const f32x4*>(&WfV[i]);
    }
    __syncthreads();
    int wv = threadIdx.x >> 6, lane = threadIdx.x & 63;
    int er = lane & 15, kg = lane >> 4;
    int row0 = (blockIdx.x * 4 + wv) * 16;
    if (row0 >= M) return;
    bf16x8 af[4];
    #pragma unroll
    for (int kc = 0; kc < 4; ++kc)
        af[kc] = *reinterpret_cast<const bf16x8*>(&A[(size_t)(row0 + er) * H + kc * 32 + kg * 8]);
    const f32x4 vzero = {0.f, 0.f, 0.f, 0.f};
    f32x4 acc[8];
    #pragma unroll
    for (int ct = 0; ct < 8; ++ct) acc[ct] = vzero;
    #pragma unroll
    for (int kc = 0; kc < 4; ++kc)
        #pragma unroll
        for (int ct = 0; ct < 8; ++ct) {
            bf16x8 bf = *reinterpret_cast<const bf16x8*>(&wl[((kc * 8 + ct) * 64 + lane) * 8]);
            acc[ct] = __builtin_amdgcn_mfma_f32_16x16x32_bf16(af[kc], bf, acc[ct], 0, 0, 0);
        }
    #pragma unroll
    for (int ct = 0; ct < 8; ++ct) {
        int col = ct * 16 + er;
        float bv = be1[col];
        #pragma unroll
        for (int r = 0; r < 4; ++r)
            U[(size_t)(row0 + kg * 4 + r) * H + col] = f2b(acc[ct][r] + bv);
    }
    #pragma unroll
    for (int ct = 0; ct < 8; ++ct) acc[ct] = vzero;
    #pragma unroll
    for (int kc = 0; kc < 4; ++kc)
        #pragma unroll
        for (int ct = 0; ct < 8; ++ct) {
            bf16x8 bf = *reinterpret_cast<const bf16x8*>(&wl[16384 + ((kc * 8 + ct) * 64 + lane) * 8]);
            acc[ct] = __builtin_amdgcn_mfma_f32_16x16x32_bf16(af[kc], bf, acc[ct], 0, 0, 0);
        }
    #pragma unroll
    for (int ct = 0; ct < 8; ++ct) {
        int col = ct * 16 + er;
        #pragma unroll
        for (int r = 0; r < 4; ++r)
            V[(size_t)(row0 + kg * 4 + r) * H + col] = f2b(acc[ct][r]);
    }
}

// ---------- MFMA GEMM with dis-scale epilogue ----------
__global__ __launch_bounds__(256) void k_gemm_scale(const short* __restrict__ A,
                                                    const short* __restrict__ Wf,
                                                    const float* __restrict__ dis,
                                                    short* __restrict__ out, int M) {
    __shared__ short wl[16384];
    for (int i = threadIdx.x * 8; i < 16384; i += 2048)
        *reinterpret_cast<f32x4*>(&wl[i]) = *reinterpret_cast<const f32x4*>(&Wf[i]);
    __syncthreads();
    int wv = threadIdx.x >> 6, lane = threadIdx.x & 63;
    int er = lane & 15, kg = lane >> 4;
    int row0 = (blockIdx.x * 4 + wv) * 16;
    if (row0 >= M) return;
    bf16x8 af[4];
    #pragma unroll
    for (int kc = 0; kc < 4; ++kc)
        af[kc] = *reinterpret_cast<const bf16x8*>(&A[(size_t)(row0 + er) * H + kc * 32 + kg * 8]);
    const f32x4 vzero = {0.f, 0.f, 0.f, 0.f};
    f32x4 acc[8];
    #pragma unroll
    for (int ct = 0; ct < 8; ++ct) acc[ct] = vzero;
    #pragma unroll
    for (int kc = 0; kc < 4; ++kc)
        #pragma unroll
        for (int ct = 0; ct < 8; ++ct) {
            bf16x8 bf = *reinterpret_cast<const bf16x8*>(&wl[((kc * 8 + ct) * 64 + lane) * 8]);
            acc[ct] = __builtin_amdgcn_mfma_f32_16x16x32_bf16(af[kc], bf, acc[ct], 0, 0, 0);
        }
    float dv[4];
    #pragma unroll
    for (int r = 0; r < 4; ++r) dv[r] = dis[row0 + kg * 4 + r];
    #pragma unroll
    for (int ct = 0; ct < 8; ++ct) {
        int col = ct * 16 + er;
        #pragma unroll
        for (int r = 0; r < 4; ++r)
            out[(size_t)(row0 + kg * 4 + r) * H + col] = f2b(acc[ct][r] * dv[r]);
    }
}

// ---------- GCN fused agg+combine (CSR, pre-scaled rows, 8-way unrolled) ----------
__global__ __launch_bounds__(256, 8) void k_gcn_fused(const int* __restrict__ rowptr,
                                                      const int* __restrict__ csr_src,
                                                      const short* __restrict__ hWs,
                                                      const float* __restrict__ dis,
                                                      const float* __restrict__ bias,
                                                      short* __restrict__ out) {
    int wv = threadIdx.x >> 6, lane = threadIdx.x & 63;
    const unsigned* hw = (const unsigned*)hWs;
    for (int n = blockIdx.x * 4 + wv; n < N_NODES; n += gridDim.x * 4) {
        int beg = rowptr[n], end = rowptr[n + 1];
        float a0 = 0.f, a1 = 0.f, b0 = 0.f, b1 = 0.f;
        float c0 = 0.f, c1 = 0.f, d0 = 0.f, d1 = 0.f;
        int e = beg;
        for (; e + 8 <= end; e += 8) {
            int s0 = csr_src[e],     s1 = csr_src[e + 1], s2 = csr_src[e + 2], s3 = csr_src[e + 3];
            int s4 = csr_src[e + 4], s5 = csr_src[e + 5], s6 = csr_src[e + 6], s7 = csr_src[e + 7];
            unsigned w0 = hw[(size_t)s0 * 64 + lane];
            unsigned w1 = hw[(size_t)s1 * 64 + lane];
            unsigned w2 = hw[(size_t)s2 * 64 + lane];
            unsigned w3 = hw[(size_t)s3 * 64 + lane];
            unsigned w4 = hw[(size_t)s4 * 64 + lane];
            unsigned w5 = hw[(size_t)s5 * 64 + lane];
            unsigned w6 = hw[(size_t)s6 * 64 + lane];
            unsigned w7 = hw[(size_t)s7 * 64 + lane];
            a0 += blo(w0); a1 += bhi(w0);
            b0 += blo(w1); b1 += bhi(w1);
            c0 += blo(w2); c1 += bhi(w2);
            d0 += blo(w3); d1 += bhi(w3);
            a0 += blo(w4); a1 += bhi(w4);
            b0 += blo(w5); b1 += bhi(w5);
            c0 += blo(w6); c1 += bhi(w6);
            d0 += blo(w7); d1 += bhi(w7);
        }
        for (; e + 4 <= end; e += 4) {
            int s0 = csr_src[e], s1 = csr_src[e + 1], s2 = csr_src[e + 2], s3 = csr_src[e + 3];
            unsigned w0 = hw[(size_t)s0 * 64 + lane];
            unsigned w1 = hw[(size_t)s1 * 64 + lane];
            unsigned w2 = hw[(size_t)s2 * 64 + lane];
            unsigned w3 = hw[(size_t)s3 * 64 + lane];
            a0 += blo(w0); a1 += bhi(w0);
            b0 += blo(w1); b1 += bhi(w1);
            c0 += blo(w2); c1 += bhi(w2);
            d0 += blo(w3); d1 += bhi(w3);
        }
        for (; e < end; ++e) {
            unsigned w = hw[(size_t)csr_src[e] * 64 + lane];
            a0 += blo(w); a1 += bhi(w);
        }
        float s0f = (a0 + b0) + (c0 + d0);
        float s1f = (a1 + b1) + (c1 + d1);
        float dn = dis[n];
        unsigned wn = hw[(size_t)n * 64 + lane];
        float r0 = tanhf(dn * (s0f + blo(wn)) + bias[lane * 2]);
        float r1 = tanhf(dn * (s1f + bhi(wn)) + bias[lane * 2 + 1]);
        unsigned o = (unsigned)(unsigned short)f2b(r0) | ((unsigned)(unsigned short)f2b(r1) << 16);
        *reinterpret_cast<unsigned*>(&out[(size_t)n * H + lane * 2]) = o;
    }
}

// ---------- EdgeConv via MFMA: even/odd V buffers, per-kc A-frag, next-node U prefetch ----------
__global__ __launch_bounds__(256, 3) void k_edge_mfma(const int* __restrict__ rowptr,
                                                      const int* __restrict__ csr_src,
                                                      const short* __restrict__ U,
                                                      const short* __restrict__ V,
                                                      const short* __restrict__ We2f,
                                                      const float* __restrict__ be2,
                                                      short* __restrict__ out) {
    __shared__ short wl[16384];
    for (int i = threadIdx.x * 8; i < 16384; i += 2048)
        *reinterpret_cast<f32x4*>(&wl[i]) = *reinterpret_cast<const f32x4*>(&We2f[i]);
    __syncthreads();
    int wv = threadIdx.x >> 6, lane = threadIdx.x & 63;
    int er = lane & 15, kg = lane >> 4, kseg = kg * 8;
    const int stride = gridDim.x * 4;
    int n = blockIdx.x * 4 + wv;
    if (n >= N_NODES) return;
    uint4 ub[4];
    #pragma unroll
    for (int kc = 0; kc < 4; ++kc)
        ub[kc] = *reinterpret_cast<const uint4*>(&U[(size_t)n * H + kc * 32 + kseg]);
    while (true) {
        int nNext = n + stride;
        uint4 ubN[4];
        if (nNext < N_NODES) {
            #pragma unroll
            for (int kc = 0; kc < 4; ++kc)
                ubN[kc] = *reinterpret_cast<const uint4*>(&U[(size_t)nNext * H + kc * 32 + kseg]);
        }
        int beg = rowptr[n], end = rowptr[n + 1];
        int deg = end - beg;
        float cm[8];
        #pragma unroll
        for (int ct = 0; ct < 8; ++ct) cm[ct] = -INFINITY;
        if (deg > 0) {
            int ntiles = (deg + 15) >> 4;
            uint4 bufA[4], bufB[4];
            auto loadTile = [&](int t, uint4* buf) {
                int ei = beg + t * 16 + er;
                int s = csr_src[ei < end ? ei : end - 1];
                #pragma unroll
                for (int kc = 0; kc < 4; ++kc)
                    buf[kc] = *reinterpret_cast<const uint4*>(&V[(size_t)s * H + kc * 32 + kseg]);
            };
            auto compute = [&](const uint4* vb) {
                const f32x4 vzero = {0.f, 0.f, 0.f, 0.f};
                f32x4 acc[8];
                #pragma unroll
                for (int ct = 0; ct < 8; ++ct) acc[ct] = vzero;
                #pragma unroll
                for (int kc = 0; kc < 4; ++kc) {
                    bf16x8 af;
                    unsigned uu, vv;
                    uu = ub[kc].x; vv = vb[kc].x;
                    af[0] = f2b(fmaxf(blo(uu) + blo(vv), 0.f));
                    af[1] = f2b(fmaxf(bhi(uu) + bhi(vv), 0.f));
                    uu = ub[kc].y; vv = vb[kc].y;
                    af[2] = f2b(fmaxf(blo(uu) + blo(vv), 0.f));
                    af[3] = f2b(fmaxf(bhi(uu) + bhi(vv), 0.f));
                    uu = ub[kc].z; vv = vb[kc].z;
                    af[4] = f2b(fmaxf(blo(uu) + blo(vv), 0.f));
                    af[5] = f2b(fmaxf(bhi(uu) + bhi(vv), 0.f));
                    uu = ub[kc].w; vv = vb[kc].w;
                    af[6] = f2b(fmaxf(blo(uu) + blo(vv), 0.f));
                    af[7] = f2b(fmaxf(bhi(uu) + bhi(vv), 0.f));
                    #pragma unroll
                    for (int ct = 0; ct < 8; ++ct) {
                        bf16x8 bf = *reinterpret_cast<const bf16x8*>(&wl[((kc * 8 + ct) * 64 + lane) * 8]);
                        acc[ct] = __builtin_amdgcn_mfma_f32_16x16x32_bf16(af, bf, acc[ct], 0, 0, 0);
                    }
                }
                #pragma unroll
                for (int ct = 0; ct < 8; ++ct)
                    cm[ct] = fmaxf(cm[ct], fmaxf(fmaxf(acc[ct][0], acc[ct][1]),
                                                 fmaxf(acc[ct][2], acc[ct][3])));
            };
            loadTile(0, bufA);
            int t = 0;
            while (true) {
                if (t + 1 < ntiles) loadTile(t + 1, bufB);
                compute(bufA);
                if (++t >= ntiles) break;
                if (t + 1 < ntiles) loadTile(t + 1, bufA);
                compute(bufB);
                if (++t >= ntiles) break;
            }
            #pragma unroll
            for (int ct = 0; ct < 8; ++ct) {
                float v = cm[ct];
                v = fmaxf(v, __shfl_xor(v, 16));
                v = fmaxf(v, __shfl_xor(v, 32));
                cm[ct] = v;
            }
            float vA, vB;
            if (kg == 0)      { vA = cm[0]; vB = cm[1]; }
            else if (kg == 1) { vA = cm[2]; vB = cm[3]; }
            else if (kg == 2) { vA = cm[4]; vB = cm[5]; }
            else              { vA = cm[6]; vB = cm[7]; }
            int colA = (kg * 2) * 16 + er;
            int colB = (kg * 2 + 1) * 16 + er;
            out[(size_t)n * H + colA] = f2b(tanhf(vA + be2[colA]));
            out[(size_t)n * H + colB] = f2b(tanhf(vB + be2[colB]));
        } else {
            int colA = (kg * 2) * 16 + er;
            int colB = (kg * 2 + 1) * 16 + er;
            out[(size_t)n * H + colA] = 0;
            out[(size_t)n * H + colB] = 0;
        }
        if (nNext >= N_NODES) break;
        n = nNext;
        #pragma unroll
        for (int kc = 0; kc < 4; ++kc) ub[kc] = ubN[kc];
    }
}

// ---------- fused final MLP + pooling ----------
__global__ __launch_bounds__(256) void k_final_mlp(const short* __restrict__ h,
                                                   const short* __restrict__ WfF1,
                                                   const short* __restrict__ WfF2,
                                                   const float* __restrict__ bf1,
                                                   const float* __restrict__ bf2,
                                                   const float* __restrict__ Wf3,
                                                   const float* __restrict__ bf3,
                                                   const int* __restrict__ batch,
                                                   float* pooled, int M) {
    __shared__ short wl1[16384];
    __shared__ short wl2[4096];
    __shared__ short tb[4][2048];
    __shared__ float lp[G_GRAPHS];
    for (int i = threadIdx.x * 8; i < 16384; i += 2048)
        *reinterpret_cast<f32x4*>(&wl1[i]) = *reinterpret_cast<const f32x4*>(&WfF1[i]);
    for (int i = threadIdx.x * 8; i < 4096; i += 2048)
        *reinterpret_cast<f32x4*>(&wl2[i]) = *reinterpret_cast<const f32x4*>(&WfF2[i]);
    if (threadIdx.x < G_GRAPHS) lp[threadIdx.x] = 0.f;
    __syncthreads();
    int wv = threadIdx.x >> 6, lane = threadIdx.x & 63;
    int er = lane & 15, kg = lane >> 4;
    int row0 = (blockIdx.x * 4 + wv) * 16;
    bool active = row0 < M;
    const f32x4 vzero = {0.f, 0.f, 0.f, 0.f};
    if (active) {
        bf16x8 af[4];
        #pragma unroll
        for (int kc = 0; kc < 4; ++kc)
            af[kc] = *reinterpret_cast<const bf16x8*>(&h[(size_t)(row0 + er) * H + kc * 32 + kg * 8]);
        f32x4 acc[8];
        #pragma unroll
        for (int ct = 0; ct < 8; ++ct) acc[ct] = vzero;
        #pragma unroll
        for (int kc = 0; kc < 4; ++kc)
            #pragma unroll
            for (int ct = 0; ct < 8; ++ct) {
                bf16x8 bf = *reinterpret_cast<const bf16x8*>(&wl1[((kc * 8 + ct) * 64 + lane) * 8]);
                acc[ct] = __builtin_amdgcn_mfma_f32_16x16x32_bf16(af[kc], bf, acc[ct], 0, 0, 0);
            }
        #pragma unroll
        for (int ct = 0; ct < 8; ++ct) {
            int col = ct * 16 + er;
            float bv = bf1[col];
            #pragma unroll
            for (int r = 0; r < 4; ++r)
                tb[wv][(kg * 4 + r) * 128 + col] = f2b(tanhf(acc[ct][r] + bv));
        }
    }
    __syncthreads();
    if (active) {
        bf16x8 af2[4];
        #pragma unroll
        for (int kc = 0; kc < 4; ++kc)
            af2[kc] = *reinterpret_cast<const bf16x8*>(&tb[wv][er * 128 + kc * 32 + kg * 8]);
        f32x4 a2[2];
        a2[0] = vzero; a2[1] = vzero;
        #pragma unroll
        for (int kc = 0; kc < 4; ++kc)
            #pragma unroll
            for (int ct = 0; ct < 2; ++ct) {
                bf16x8 bf = *reinterpret_cast<const bf16x8*>(&wl2[((kc * 2 + ct) * 64 + lane) * 8]);
                a2[ct] = __builtin_amdgcn_mfma_f32_16x16x32_bf16(af2[kc], bf, a2[ct], 0, 0, 0);
            }
        float w3a = Wf3[er], w3b = Wf3[16 + er];
        float b2a = bf2[er], b2b = bf2[16 + er];
        float bf3v = bf3[0];
        float psum[4];
        #pragma unroll
        for (int r = 0; r < 4; ++r) {
            float f2a = tanhf(a2[0][r] + b2a);
            float f2c = tanhf(a2[1][r] + b2b);
            float p = f2a * w3a + f2c * w3b;
            p += __shfl_xor(p, 1);
            p += __shfl_xor(p, 2);
            p += __shfl_xor(p, 4);
            p += __shfl_xor(p, 8);
            psum[r] = p + bf3v;
        }
        if (er == 0) {
            #pragma unroll
            for (int r = 0; r < 4; ++r) {
                int n = row0 + kg * 4 + r;
                if (n < M) atomicAdd(&lp[batch[n]], psum[r]);
            }
        }
    }
    __syncthreads();
    if (threadIdx.x < G_GRAPHS && lp[threadIdx.x] != 0.f)
        atomicAdd(&pooled[threadIdx.x], lp[threadIdx.x]);
}

__global__ __launch_bounds__(64) void k_final(const float* pooled, const float* counts,
                                              void* out, const int* __restrict__ flag) {
    int g = threadIdx.x;
    if (g < G_GRAPHS) {
        float v = pooled[g] / fmaxf(counts[g], 1.0f);
        float s = 1.0f / (1.0f + expf(-v));
        if (*flag) ((__hip_bfloat16*)out)[g] = __float2bfloat16(s);
        else       ((float*)out)[g] = s;
    }
}

extern "C" void kernel_launch(void* const* d_in, const int* in_sizes, int n_in,
                              void* d_out, int out_size, void* d_ws, size_t ws_size,
                              hipStream_t stream) {
    const int* ei    = (const int*)d_in[1];
    const int* src   = ei;
    const int* dst   = ei + N_EDGES;
    const int* batch = (const int*)d_in[2];

    float* ws = (float*)d_ws;
    size_t off = 0;
    auto alloc = [&](size_t n) { off = (off + 3) & ~(size_t)3; float* p = ws + off; off += n; return p; };

    const size_t NH = (size_t)N_NODES * H;
    short* hb     = (short*)alloc(NH / 2);
    short* Ub     = (short*)alloc(NH / 2);
    short* Vb     = (short*)alloc(NH / 2);
    float* xf     = alloc((size_t)N_NODES * F_IN);
    float* dis    = alloc(N_NODES);
    float* pooled = alloc(G_GRAPHS);
    float* counts = alloc(G_GRAPHS);
    int*   flag   = (int*)alloc(1);
    int*   rowptr = (int*)alloc(N_NODES + 1);
    int*   cursor = (int*)alloc(N_NODES);
    int*   csrsrc = (int*)alloc(N_EDGES);
    int*   bsums  = (int*)alloc(32);

    float* W1  = alloc(F_IN * H);
    float* b1  = alloc(H);
    float* W2  = alloc(HH);
    float* b2  = alloc(H);
    float* We1 = alloc(2 * HH);
    float* be1 = alloc(H);
    float* We2 = alloc(HH);
    float* be2 = alloc(H);
    float* Wf1 = alloc(HH);
    float* bf1 = alloc(H);
    float* Wf2 = alloc(H * 32);
    float* bf2 = alloc(32);
    float* Wf3 = alloc(32);
    float* bf3 = alloc(4);
    short* WfU  = (short*)alloc(8192);
    short* WfV  = (short*)alloc(8192);
    short* WfW2 = (short*)alloc(8192);
    short* WfF1 = (short*)alloc(8192);
    short* WfF2 = (short*)alloc(2048);
    short* We2f = (short*)alloc(8192);

    const int eB    = (N_EDGES + 255) / 256;
    const int nB    = (N_NODES + 255) / 256;
    const int scanB = (N_NODES + 2047) / 2048;
    const int mfmaB = (N_NODES / 16 + 3) / 4;      // 782
    const int gcnB  = (N_NODES + 3) / 4;           // 12500

    k_detect<<<1, 256, 0, stream>>>((const unsigned*)d_in[0], flag);

    CvtArgs ca;
    const int srcIdx[15] = {0, 3, 4, 5, 6, 7, 8, 9, 10, 11, 12, 13, 14, 15, 16};
    float* dsts[15] = {xf, W1, b1, W2, b2, We1, be1, We2, be2, Wf1, bf1, Wf2, bf2, Wf3, bf3};
    for (int s = 0; s < 15; ++s) { ca.src[s] = d_in[srcIdx[s]]; ca.dst[s] = dsts[s]; }
    const int cvtTotal = 450000 + 1152 + 128 + 16384 + 128 + 32768 + 128 + 16384 + 128
                       + 16384 + 128 + 4096 + 32 + 32 + 1;       // 537873
    k_cvt_all<<<(cvtTotal + 255) / 256, 256, 0, stream>>>(ca, flag);

    k_sub<<<(HH + 255) / 256, 256, 0, stream>>>(We1);
    k_prep<<<8, 256, 0, stream>>>(We1, WfU, 8);
    k_prep<<<8, 256, 0, stream>>>(We1 + HH, WfV, 8);
    k_prep<<<8, 256, 0, stream>>>(W2, WfW2, 8);
    k_prep<<<8, 256, 0, stream>>>(Wf1, WfF1, 8);
    k_prep<<<2, 256, 0, stream>>>(Wf2, WfF2, 2);
    k_prep<<<8, 256, 0, stream>>>(We2, We2f, 8);

    // CSR build (sorted by dst)
    k_zero<<<nB, 256, 0, stream>>>((float*)cursor, N_NODES);
    k_hist<<<eB, 256, 0, stream>>>(dst, cursor);
    k_scan1<<<scanB, 256, 0, stream>>>(cursor, rowptr, bsums);
    k_scan2<<<1, 1, 0, stream>>>(bsums, scanB, rowptr);
    k_scan3<<<nB, 256, 0, stream>>>(rowptr, bsums);
    k_zero<<<nB, 256, 0, stream>>>((float*)cursor, N_NODES);
    k_scatter<<<eB, 256, 0, stream>>>(src, dst, rowptr, cursor, csrsrc);
    k_dis<<<nB, 256, 0, stream>>>(rowptr, dis);
    k_zero<<<1, 256, 0, stream>>>(pooled, 2 * G_GRAPHS);
    k_counts<<<nB, 256, 0, stream>>>(batch, counts);

    // GCN1
    k_gemm_f32bf_scale<<<(N_NODES + 7) / 8, 256, 0, stream>>>(xf, W1, dis, Ub, N_NODES);
    k_gcn_fused<<<gcnB, 256, 0, stream>>>(rowptr, csrsrc, Ub, dis, b1, hb);

    for (int iter = 0; iter < 3; ++iter) {
        k_gemm_dual<<<mfmaB, 256, 0, stream>>>(hb, WfU, WfV, be1, Ub, Vb, N_NODES);
        k_edge_mfma<<<2048, 256, 0, stream>>>(rowptr, csrsrc, Ub, Vb, We2f, be2, hb);
        if (iter < 2) {
            k_gemm_scale<<<mfmaB, 256, 0, stream>>>(hb, WfW2, dis, Ub, N_NODES);
            k_gcn_fused<<<gcnB, 256, 0, stream>>>(rowptr, csrsrc, Ub, dis, b2, hb);
        }
    }

    k_final_mlp<<<mfmaB, 256, 0, stream>>>(hb, WfF1, WfF2, bf1, bf2, Wf3, bf3,
                                           batch, pooled, N_NODES);
    k_final<<<1, 64, 0, stream>>>(pooled, counts, d_out, flag);
}

// Round 9
// 700.890 us; speedup vs baseline: 2.5364x; 2.5364x over previous
//
#include <hip/hip_runtime.h>
#include <hip/hip_bf16.h>

#define N_NODES 50000
#define N_EDGES 800000
#define F_IN 9
#define H 128
#define G_GRAPHS 64
#define HH (H * H)
#define MAXT (N_EDGES / 16 + N_NODES)   // 100000 upper bound on tile count

typedef short bf16x8 __attribute__((ext_vector_type(8)));
typedef float f32x4 __attribute__((ext_vector_type(4)));

static __device__ inline short f2b(float f) {
    __hip_bfloat16 h = __float2bfloat16(f);
    return *reinterpret_cast<short*>(&h);
}
static __device__ inline float blo(unsigned u) { return __uint_as_float(u << 16); }
static __device__ inline float bhi(unsigned u) { return __uint_as_float(u & 0xFFFF0000u); }
static __device__ inline unsigned encodef(float f) {
    unsigned u = __float_as_uint(f);
    return (u & 0x80000000u) ? ~u : (u | 0x80000000u);
}
static __device__ inline float decodef(unsigned u) {
    return __uint_as_float((u & 0x80000000u) ? (u ^ 0x80000000u) : ~u);
}

// ---------- dtype detection ----------
__global__ __launch_bounds__(256) void k_detect(const unsigned* __restrict__ x, int* flag) {
    __shared__ int cnt;
    if (threadIdx.x == 0) cnt = 0;
    __syncthreads();
    unsigned u = x[threadIdx.x];
    int e = (u >> 7) & 0xFF;
    if (e >= 0x70 && e <= 0x83) atomicAdd(&cnt, 1);
    __syncthreads();
    if (threadIdx.x == 0) *flag = (cnt >= 128) ? 1 : 0;
}

// ---------- batched convert of all float inputs ----------
struct CvtArgs { const void* src[15]; float* dst[15]; };

__global__ __launch_bounds__(256) void k_cvt_all(CvtArgs a, const int* __restrict__ flag) {
    const int sz[15] = {450000, 1152, 128, 16384, 128, 32768, 128, 16384, 128,
                        16384, 128, 4096, 32, 32, 1};
    int i = blockIdx.x * 256 + threadIdx.x;
    int fl = *flag;
    int base = 0;
    #pragma unroll
    for (int s = 0; s < 15; ++s) {
        if (i >= base && i < base + sz[s]) {
            int off = i - base;
            float v = fl ? __bfloat162float(((const __hip_bfloat16*)a.src[s])[off])
                         : ((const float*)a.src[s])[off];
            a.dst[s][off] = v;
        }
        base += sz[s];
    }
}

__global__ __launch_bounds__(256) void k_zero(float* p, int n) {
    int i = blockIdx.x * 256 + threadIdx.x;
    if (i < n) p[i] = 0.f;
}

__global__ __launch_bounds__(256) void k_sub(float* w) {
    int i = blockIdx.x * 256 + threadIdx.x;
    if (i < HH) w[i] -= w[HH + i];
}

// ---------- W[128,NT*16] f32 -> bf16 MFMA B-fragment table ----------
__global__ __launch_bounds__(256) void k_prep(const float* __restrict__ W,
                                              short* __restrict__ Wf, int NT) {
    int tid = blockIdx.x * 256 + threadIdx.x;
    int total = 4 * NT * 64;
    if (tid >= total) return;
    int kc = tid / (NT * 64);
    int ct = (tid / 64) % NT;
    int lane = tid & 63;
    int Nc = NT * 16;
    int kb = kc * 32 + (lane >> 4) * 8;
    int col = ct * 16 + (lane & 15);
    #pragma unroll
    for (int j = 0; j < 8; ++j)
        Wf[tid * 8 + j] = f2b(W[(kb + j) * Nc + col]);
}

// ---------- CSR build ----------
__global__ __launch_bounds__(256) void k_hist(const int* __restrict__ dst, int* cnt) {
    int e = blockIdx.x * 256 + threadIdx.x;
    if (e < N_EDGES) atomicAdd(&cnt[dst[e]], 1);
}

__global__ __launch_bounds__(256) void k_scan1(const int* __restrict__ deg, int* __restrict__ out,
                                               int* __restrict__ blockSums) {
    __shared__ int lds[256];
    int base = blockIdx.x * 2048;
    int t = threadIdx.x;
    int local[8];
    int s = 0;
    #pragma unroll
    for (int j = 0; j < 8; ++j) {
        int idx = base + t * 8 + j;
        int v = (idx < N_NODES) ? deg[idx] : 0;
        local[j] = s;
        s += v;
    }
    lds[t] = s;
    __syncthreads();
    if (t == 0) {
        int run = 0;
        for (int i = 0; i < 256; ++i) { int v = lds[i]; lds[i] = run; run += v; }
        blockSums[blockIdx.x] = run;
    }
    __syncthreads();
    int offs = lds[t];
    #pragma unroll
    for (int j = 0; j < 8; ++j) {
        int idx = base + t * 8 + j;
        if (idx < N_NODES) out[idx] = offs + local[j];
    }
}

__global__ void k_scan2(int* blockSums, int nb, int* rowptr) {
    int run = 0;
    for (int i = 0; i < nb; ++i) { int v = blockSums[i]; blockSums[i] = run; run += v; }
    rowptr[N_NODES] = N_EDGES;
}

// scan finalize for tile starts: also records total tile count
__global__ void k_scan2t(int* blockSums, int nb, int* tstart, int* ntiles) {
    int run = 0;
    for (int i = 0; i < nb; ++i) { int v = blockSums[i]; blockSums[i] = run; run += v; }
    tstart[N_NODES] = run;
    *ntiles = run;
}

__global__ __launch_bounds__(256) void k_scan3(int* rowptr, const int* __restrict__ blockSums) {
    int idx = blockIdx.x * 256 + threadIdx.x;
    if (idx < N_NODES) rowptr[idx] += blockSums[idx >> 11];
}

__global__ __launch_bounds__(256) void k_scatter(const int* __restrict__ src, const int* __restrict__ dst,
                                                 const int* __restrict__ rowptr, int* cursor,
                                                 int* __restrict__ csr_src) {
    int e = blockIdx.x * 256 + threadIdx.x;
    if (e >= N_EDGES) return;
    int d = dst[e];
    int pos = rowptr[d] + atomicAdd(&cursor[d], 1);
    csr_src[pos] = src[e];
}

__global__ __launch_bounds__(256) void k_dis(const int* __restrict__ rowptr, float* dis) {
    int n = blockIdx.x * 256 + threadIdx.x;
    if (n < N_NODES) {
        float deg = (float)(rowptr[n + 1] - rowptr[n]);
        dis[n] = rsqrtf(deg + 1.0f);
    }
}

// ---------- tile list build: one wave-tile per 16 edges of a node ----------
__global__ __launch_bounds__(256) void k_tcnt(const int* __restrict__ rowptr, int* tcnt) {
    int n = blockIdx.x * 256 + threadIdx.x;
    if (n < N_NODES) tcnt[n] = (rowptr[n + 1] - rowptr[n] + 15) >> 4;
}

__global__ __launch_bounds__(256) void k_tfill(const int* __restrict__ rowptr,
                                               const int* __restrict__ tstart,
                                               int* __restrict__ tileN,
                                               int* __restrict__ tileBeg) {
    int n = blockIdx.x * 256 + threadIdx.x;
    if (n >= N_NODES) return;
    int t0 = tstart[n], t1 = tstart[n + 1];
    int beg = rowptr[n];
    for (int t = t0; t < t1; ++t) {
        tileN[t] = n;
        tileBeg[t] = beg + (t - t0) * 16;
    }
}

// ---------- counts per graph ----------
__global__ __launch_bounds__(256) void k_counts(const int* __restrict__ batch, float* counts) {
    __shared__ float lc[G_GRAPHS];
    int tid = threadIdx.x;
    if (tid < G_GRAPHS) lc[tid] = 0.f;
    __syncthreads();
    int n = blockIdx.x * 256 + tid;
    if (n < N_NODES) atomicAdd(&lc[batch[n]], 1.0f);
    __syncthreads();
    if (tid < G_GRAPHS && lc[tid] > 0.f) atomicAdd(&counts[tid], lc[tid]);
}

// ---------- GCN1 GEMM: out = (x[M,9] @ W1[9,128]) * dis[row], bf16 ----------
__global__ __launch_bounds__(256) void k_gemm_f32bf_scale(const float* __restrict__ A,
                                                          const float* __restrict__ W,
                                                          const float* __restrict__ dis,
                                                          short* __restrict__ out, int M) {
    __shared__ float w_lds[F_IN * H];
    for (int i = threadIdx.x; i < F_IN * H; i += 256) w_lds[i] = W[i];
    __syncthreads();
    int row = blockIdx.x * 8 + threadIdx.x / 32;
    int c4 = (threadIdx.x & 31) << 2;
    if (row >= M) return;
    const float* a = A + (size_t)row * F_IN;
    float acc0 = 0.f, acc1 = 0.f, acc2 = 0.f, acc3 = 0.f;
    #pragma unroll
    for (int k = 0; k < F_IN; ++k) {
        float av = a[k];
        float4 w = *reinterpret_cast<const float4*>(&w_lds[k * H + c4]);
        acc0 = fmaf(av, w.x, acc0);
        acc1 = fmaf(av, w.y, acc1);
        acc2 = fmaf(av, w.z, acc2);
        acc3 = fmaf(av, w.w, acc3);
    }
    float dv = dis[row];
    short* op = &out[(size_t)row * H + c4];
    op[0] = f2b(acc0 * dv); op[1] = f2b(acc1 * dv);
    op[2] = f2b(acc2 * dv); op[3] = f2b(acc3 * dv);
}

// ---------- dual MFMA GEMM: U = A@WU + be1 ; V = A@WV ----------
__global__ __launch_bounds__(256) void k_gemm_dual(const short* __restrict__ A,
                                                   const short* __restrict__ WfU,
                                                   const short* __restrict__ WfV,
                                                   const float* __restrict__ be1,
                                                   short* __restrict__ U,
                                                   short* __restrict__ V, int M) {
    __shared__ short wl[32768];
    for (int i = threadIdx.x * 8; i < 16384; i += 2048) {
        *reinterpret_cast<f32x4*>(&wl[i])         = *reinterpret_cast<const f32x4*>(&WfU[i]);
        *reinterpret_cast<f32x4*>(&wl[16384 + i]) = *reinterpret_cast<const f32x4*>(&WfV[i]);
    }
    __syncthreads();
    int wv = threadIdx.x >> 6, lane = threadIdx.x & 63;
    int er = lane & 15, kg = lane >> 4;
    int row0 = (blockIdx.x * 4 + wv) * 16;
    if (row0 >= M) return;
    bf16x8 af[4];
    #pragma unroll
    for (int kc = 0; kc < 4; ++kc)
        af[kc] = *reinterpret_cast<const bf16x8*>(&A[(size_t)(row0 + er) * H + kc * 32 + kg * 8]);
    const f32x4 vzero = {0.f, 0.f, 0.f, 0.f};
    f32x4 acc[8];
    #pragma unroll
    for (int ct = 0; ct < 8; ++ct) acc[ct] = vzero;
    #pragma unroll
    for (int kc = 0; kc < 4; ++kc)
        #pragma unroll
        for (int ct = 0; ct < 8; ++ct) {
            bf16x8 bf = *reinterpret_cast<const bf16x8*>(&wl[((kc * 8 + ct) * 64 + lane) * 8]);
            acc[ct] = __builtin_amdgcn_mfma_f32_16x16x32_bf16(af[kc], bf, acc[ct], 0, 0, 0);
        }
    #pragma unroll
    for (int ct = 0; ct < 8; ++ct) {
        int col = ct * 16 + er;
        float bv = be1[col];
        #pragma unroll
        for (int r = 0; r < 4; ++r)
            U[(size_t)(row0 + kg * 4 + r) * H + col] = f2b(acc[ct][r] + bv);
    }
    #pragma unroll
    for (int ct = 0; ct < 8; ++ct) acc[ct] = vzero;
    #pragma unroll
    for (int kc = 0; kc < 4; ++kc)
        #pragma unroll
        for (int ct = 0; ct < 8; ++ct) {
            bf16x8 bf = *reinterpret_cast<const bf16x8*>(&wl[16384 + ((kc * 8 + ct) * 64 + lane) * 8]);
            acc[ct] = __builtin_amdgcn_mfma_f32_16x16x32_bf16(af[kc], bf, acc[ct], 0, 0, 0);
        }
    #pragma unroll
    for (int ct = 0; ct < 8; ++ct) {
        int col = ct * 16 + er;
        #pragma unroll
        for (int r = 0; r < 4; ++r)
            V[(size_t)(row0 + kg * 4 + r) * H + col] = f2b(acc[ct][r]);
    }
}

// ---------- MFMA GEMM with dis-scale epilogue ----------
__global__ __launch_bounds__(256) void k_gemm_scale(const short* __restrict__ A,
                                                    const short* __restrict__ Wf,
                                                    const float* __restrict__ dis,
                                                    short* __restrict__ out, int M) {
    __shared__ short wl[16384];
    for (int i = threadIdx.x * 8; i < 16384; i += 2048)
        *reinterpret_cast<f32x4*>(&wl[i]) = *reinterpret_cast<const f32x4*>(&Wf[i]);
    __syncthreads();
    int wv = threadIdx.x >> 6, lane = threadIdx.x & 63;
    int er = lane & 15, kg = lane >> 4;
    int row0 = (blockIdx.x * 4 + wv) * 16;
    if (row0 >= M) return;
    bf16x8 af[4];
    #pragma unroll
    for (int kc = 0; kc < 4; ++kc)
        af[kc] = *reinterpret_cast<const bf16x8*>(&A[(size_t)(row0 + er) * H + kc * 32 + kg * 8]);
    const f32x4 vzero = {0.f, 0.f, 0.f, 0.f};
    f32x4 acc[8];
    #pragma unroll
    for (int ct = 0; ct < 8; ++ct) acc[ct] = vzero;
    #pragma unroll
    for (int kc = 0; kc < 4; ++kc)
        #pragma unroll
        for (int ct = 0; ct < 8; ++ct) {
            bf16x8 bf = *reinterpret_cast<const bf16x8*>(&wl[((kc * 8 + ct) * 64 + lane) * 8]);
            acc[ct] = __builtin_amdgcn_mfma_f32_16x16x32_bf16(af[kc], bf, acc[ct], 0, 0, 0);
        }
    float dv[4];
    #pragma unroll
    for (int r = 0; r < 4; ++r) dv[r] = dis[row0 + kg * 4 + r];
    #pragma unroll
    for (int ct = 0; ct < 8; ++ct) {
        int col = ct * 16 + er;
        #pragma unroll
        for (int r = 0; r < 4; ++r)
            out[(size_t)(row0 + kg * 4 + r) * H + col] = f2b(acc[ct][r] * dv[r]);
    }
}

// ---------- GCN fused agg+combine (CSR, pre-scaled rows, 8-way unrolled) ----------
__global__ __launch_bounds__(256) void k_gcn_fused(const int* __restrict__ rowptr,
                                                   const int* __restrict__ csr_src,
                                                   const short* __restrict__ hWs,
                                                   const float* __restrict__ dis,
                                                   const float* __restrict__ bias,
                                                   short* __restrict__ out) {
    int wv = threadIdx.x >> 6, lane = threadIdx.x & 63;
    const unsigned* hw = (const unsigned*)hWs;
    for (int n = blockIdx.x * 4 + wv; n < N_NODES; n += gridDim.x * 4) {
        int beg = rowptr[n], end = rowptr[n + 1];
        float a0 = 0.f, a1 = 0.f, b0 = 0.f, b1 = 0.f;
        float c0 = 0.f, c1 = 0.f, d0 = 0.f, d1 = 0.f;
        int e = beg;
        for (; e + 8 <= end; e += 8) {
            int s0 = csr_src[e],     s1 = csr_src[e + 1], s2 = csr_src[e + 2], s3 = csr_src[e + 3];
            int s4 = csr_src[e + 4], s5 = csr_src[e + 5], s6 = csr_src[e + 6], s7 = csr_src[e + 7];
            unsigned w0 = hw[(size_t)s0 * 64 + lane];
            unsigned w1 = hw[(size_t)s1 * 64 + lane];
            unsigned w2 = hw[(size_t)s2 * 64 + lane];
            unsigned w3 = hw[(size_t)s3 * 64 + lane];
            unsigned w4 = hw[(size_t)s4 * 64 + lane];
            unsigned w5 = hw[(size_t)s5 * 64 + lane];
            unsigned w6 = hw[(size_t)s6 * 64 + lane];
            unsigned w7 = hw[(size_t)s7 * 64 + lane];
            a0 += blo(w0); a1 += bhi(w0);
            b0 += blo(w1); b1 += bhi(w1);
            c0 += blo(w2); c1 += bhi(w2);
            d0 += blo(w3); d1 += bhi(w3);
            a0 += blo(w4); a1 += bhi(w4);
            b0 += blo(w5); b1 += bhi(w5);
            c0 += blo(w6); c1 += bhi(w6);
            d0 += blo(w7); d1 += bhi(w7);
        }
        for (; e + 4 <= end; e += 4) {
            int s0 = csr_src[e], s1 = csr_src[e + 1], s2 = csr_src[e + 2], s3 = csr_src[e + 3];
            unsigned w0 = hw[(size_t)s0 * 64 + lane];
            unsigned w1 = hw[(size_t)s1 * 64 + lane];
            unsigned w2 = hw[(size_t)s2 * 64 + lane];
            unsigned w3 = hw[(size_t)s3 * 64 + lane];
            a0 += blo(w0); a1 += bhi(w0);
            b0 += blo(w1); b1 += bhi(w1);
            c0 += blo(w2); c1 += bhi(w2);
            d0 += blo(w3); d1 += bhi(w3);
        }
        for (; e < end; ++e) {
            unsigned w = hw[(size_t)csr_src[e] * 64 + lane];
            a0 += blo(w); a1 += bhi(w);
        }
        float s0f = (a0 + b0) + (c0 + d0);
        float s1f = (a1 + b1) + (c1 + d1);
        float dn = dis[n];
        unsigned wn = hw[(size_t)n * 64 + lane];
        float r0 = tanhf(dn * (s0f + blo(wn)) + bias[lane * 2]);
        float r1 = tanhf(dn * (s1f + bhi(wn)) + bias[lane * 2 + 1]);
        unsigned o = (unsigned)(unsigned short)f2b(r0) | ((unsigned)(unsigned short)f2b(r1) << 16);
        *reinterpret_cast<unsigned*>(&out[(size_t)n * H + lane * 2]) = o;
    }
}

// ---------- EdgeConv: one wave per 16-edge tile; partial max -> global atomicMax ----------
__global__ __launch_bounds__(256) void k_edge_tile(const int* __restrict__ rowptr,
                                                   const int* __restrict__ csr_src,
                                                   const int* __restrict__ tileN,
                                                   const int* __restrict__ tileBeg,
                                                   const int* __restrict__ ntilesp,
                                                   const short* __restrict__ U,
                                                   const short* __restrict__ V,
                                                   const short* __restrict__ We2f,
                                                   unsigned* aggEnc) {
    int nt = *ntilesp;
    if ((int)(blockIdx.x * 4) >= nt) return;     // uniform early-out for whole block
    __shared__ short wl[16384];
    for (int i = threadIdx.x * 8; i < 16384; i += 2048)
        *reinterpret_cast<f32x4*>(&wl[i]) = *reinterpret_cast<const f32x4*>(&We2f[i]);
    __syncthreads();
    int wv = threadIdx.x >> 6, lane = threadIdx.x & 63;
    int er = lane & 15, kg = lane >> 4, kseg = kg * 8;
    int tid = blockIdx.x * 4 + wv;
    if (tid >= nt) return;
    int n = tileN[tid];
    int ebeg = tileBeg[tid];
    int eend = rowptr[n + 1];
    int ei = ebeg + er;
    int s = csr_src[ei < eend ? ei : eend - 1];  // pad rows duplicate last edge (max-safe)
    const f32x4 vzero = {0.f, 0.f, 0.f, 0.f};
    f32x4 acc[8];
    #pragma unroll
    for (int ct = 0; ct < 8; ++ct) acc[ct] = vzero;
    #pragma unroll
    for (int kc = 0; kc < 4; ++kc) {
        uint4 uu4 = *reinterpret_cast<const uint4*>(&U[(size_t)n * H + kc * 32 + kseg]);
        uint4 vv4 = *reinterpret_cast<const uint4*>(&V[(size_t)s * H + kc * 32 + kseg]);
        bf16x8 af;
        unsigned uu, vv;
        uu = uu4.x; vv = vv4.x;
        af[0] = f2b(fmaxf(blo(uu) + blo(vv), 0.f));
        af[1] = f2b(fmaxf(bhi(uu) + bhi(vv), 0.f));
        uu = uu4.y; vv = vv4.y;
        af[2] = f2b(fmaxf(blo(uu) + blo(vv), 0.f));
        af[3] = f2b(fmaxf(bhi(uu) + bhi(vv), 0.f));
        uu = uu4.z; vv = vv4.z;
        af[4] = f2b(fmaxf(blo(uu) + blo(vv), 0.f));
        af[5] = f2b(fmaxf(bhi(uu) + bhi(vv), 0.f));
        uu = uu4.w; vv = vv4.w;
        af[6] = f2b(fmaxf(blo(uu) + blo(vv), 0.f));
        af[7] = f2b(fmaxf(bhi(uu) + bhi(vv), 0.f));
        #pragma unroll
        for (int ct = 0; ct < 8; ++ct) {
            bf16x8 bf = *reinterpret_cast<const bf16x8*>(&wl[((kc * 8 + ct) * 64 + lane) * 8]);
            acc[ct] = __builtin_amdgcn_mfma_f32_16x16x32_bf16(af, bf, acc[ct], 0, 0, 0);
        }
    }
    float cm[8];
    #pragma unroll
    for (int ct = 0; ct < 8; ++ct) {
        float v = fmaxf(fmaxf(acc[ct][0], acc[ct][1]), fmaxf(acc[ct][2], acc[ct][3]));
        v = fmaxf(v, __shfl_xor(v, 16));
        v = fmaxf(v, __shfl_xor(v, 32));
        cm[ct] = v;
    }
    float vA, vB;
    if (kg == 0)      { vA = cm[0]; vB = cm[1]; }
    else if (kg == 1) { vA = cm[2]; vB = cm[3]; }
    else if (kg == 2) { vA = cm[4]; vB = cm[5]; }
    else              { vA = cm[6]; vB = cm[7]; }
    int colA = (kg * 2) * 16 + er;
    int colB = (kg * 2 + 1) * 16 + er;
    atomicMax(&aggEnc[(size_t)n * H + colA], encodef(vA));
    atomicMax(&aggEnc[(size_t)n * H + colB], encodef(vB));
}

// ---------- EdgeConv combine: out = tanh(empty ? 0 : decode(max)+be2), bf16 ----------
__global__ __launch_bounds__(256) void k_edge_combine(const unsigned* __restrict__ aggEnc,
                                                      const float* __restrict__ be2,
                                                      short* __restrict__ out) {
    int i = blockIdx.x * 256 + threadIdx.x;      // N*64 threads, 2 cols each
    if (i >= N_NODES * 64) return;
    int n = i >> 6, c2 = (i & 63) << 1;
    unsigned u0 = aggEnc[(size_t)n * H + c2];
    unsigned u1 = aggEnc[(size_t)n * H + c2 + 1];
    float r0 = tanhf(u0 ? (decodef(u0) + be2[c2]) : 0.f);
    float r1 = tanhf(u1 ? (decodef(u1) + be2[c2 + 1]) : 0.f);
    unsigned o = (unsigned)(unsigned short)f2b(r0) | ((unsigned)(unsigned short)f2b(r1) << 16);
    *reinterpret_cast<unsigned*>(&out[(size_t)n * H + c2]) = o;
}

// ---------- fused final MLP + pooling ----------
__global__ __launch_bounds__(256) void k_final_mlp(const short* __restrict__ h,
                                                   const short* __restrict__ WfF1,
                                                   const short* __restrict__ WfF2,
                                                   const float* __restrict__ bf1,
                                                   const float* __restrict__ bf2,
                                                   const float* __restrict__ Wf3,
                                                   const float* __restrict__ bf3,
                                                   const int* __restrict__ batch,
                                                   float* pooled, int M) {
    __shared__ short wl1[16384];
    __shared__ short wl2[4096];
    __shared__ short tb[4][2048];
    __shared__ float lp[G_GRAPHS];
    for (int i = threadIdx.x * 8; i < 16384; i += 2048)
        *reinterpret_cast<f32x4*>(&wl1[i]) = *reinterpret_cast<const f32x4*>(&WfF1[i]);
    for (int i = threadIdx.x * 8; i < 4096; i += 2048)
        *reinterpret_cast<f32x4*>(&wl2[i]) = *reinterpret_cast<const f32x4*>(&WfF2[i]);
    if (threadIdx.x < G_GRAPHS) lp[threadIdx.x] = 0.f;
    __syncthreads();
    int wv = threadIdx.x >> 6, lane = threadIdx.x & 63;
    int er = lane & 15, kg = lane >> 4;
    int row0 = (blockIdx.x * 4 + wv) * 16;
    bool active = row0 < M;
    const f32x4 vzero = {0.f, 0.f, 0.f, 0.f};
    if (active) {
        bf16x8 af[4];
        #pragma unroll
        for (int kc = 0; kc < 4; ++kc)
            af[kc] = *reinterpret_cast<const bf16x8*>(&h[(size_t)(row0 + er) * H + kc * 32 + kg * 8]);
        f32x4 acc[8];
        #pragma unroll
        for (int ct = 0; ct < 8; ++ct) acc[ct] = vzero;
        #pragma unroll
        for (int kc = 0; kc < 4; ++kc)
            #pragma unroll
            for (int ct = 0; ct < 8; ++ct) {
                bf16x8 bf = *reinterpret_cast<const bf16x8*>(&wl1[((kc * 8 + ct) * 64 + lane) * 8]);
                acc[ct] = __builtin_amdgcn_mfma_f32_16x16x32_bf16(af[kc], bf, acc[ct], 0, 0, 0);
            }
        #pragma unroll
        for (int ct = 0; ct < 8; ++ct) {
            int col = ct * 16 + er;
            float bv = bf1[col];
            #pragma unroll
            for (int r = 0; r < 4; ++r)
                tb[wv][(kg * 4 + r) * 128 + col] = f2b(tanhf(acc[ct][r] + bv));
        }
    }
    __syncthreads();
    if (active) {
        bf16x8 af2[4];
        #pragma unroll
        for (int kc = 0; kc < 4; ++kc)
            af2[kc] = *reinterpret_cast<const bf16x8*>(&tb[wv][er * 128 + kc * 32 + kg * 8]);
        f32x4 a2[2];
        a2[0] = vzero; a2[1] = vzero;
        #pragma unroll
        for (int kc = 0; kc < 4; ++kc)
            #pragma unroll
            for (int ct = 0; ct < 2; ++ct) {
                bf16x8 bf = *reinterpret_cast<const bf16x8*>(&wl2[((kc * 2 + ct) * 64 + lane) * 8]);
                a2[ct] = __builtin_amdgcn_mfma_f32_16x16x32_bf16(af2[kc], bf, a2[ct], 0, 0, 0);
            }
        float w3a = Wf3[er], w3b = Wf3[16 + er];
        float b2a = bf2[er], b2b = bf2[16 + er];
        float bf3v = bf3[0];
        float psum[4];
        #pragma unroll
        for (int r = 0; r < 4; ++r) {
            float f2a = tanhf(a2[0][r] + b2a);
            float f2c = tanhf(a2[1][r] + b2b);
            float p = f2a * w3a + f2c * w3b;
            p += __shfl_xor(p, 1);
            p += __shfl_xor(p, 2);
            p += __shfl_xor(p, 4);
            p += __shfl_xor(p, 8);
            psum[r] = p + bf3v;
        }
        if (er == 0) {
            #pragma unroll
            for (int r = 0; r < 4; ++r) {
                int n = row0 + kg * 4 + r;
                if (n < M) atomicAdd(&lp[batch[n]], psum[r]);
            }
        }
    }
    __syncthreads();
    if (threadIdx.x < G_GRAPHS && lp[threadIdx.x] != 0.f)
        atomicAdd(&pooled[threadIdx.x], lp[threadIdx.x]);
}

__global__ __launch_bounds__(64) void k_final(const float* pooled, const float* counts,
                                              void* out, const int* __restrict__ flag) {
    int g = threadIdx.x;
    if (g < G_GRAPHS) {
        float v = pooled[g] / fmaxf(counts[g], 1.0f);
        float s = 1.0f / (1.0f + expf(-v));
        if (*flag) ((__hip_bfloat16*)out)[g] = __float2bfloat16(s);
        else       ((float*)out)[g] = s;
    }
}

extern "C" void kernel_launch(void* const* d_in, const int* in_sizes, int n_in,
                              void* d_out, int out_size, void* d_ws, size_t ws_size,
                              hipStream_t stream) {
    const int* ei    = (const int*)d_in[1];
    const int* src   = ei;
    const int* dst   = ei + N_EDGES;
    const int* batch = (const int*)d_in[2];

    float* ws = (float*)d_ws;
    size_t off = 0;
    auto alloc = [&](size_t n) { off = (off + 3) & ~(size_t)3; float* p = ws + off; off += n; return p; };

    const size_t NH = (size_t)N_NODES * H;
    short* hb     = (short*)alloc(NH / 2);
    short* Ub     = (short*)alloc(NH / 2);
    short* Vb     = (short*)alloc(NH / 2);
    unsigned* aggEnc = (unsigned*)alloc(NH);      // encoded max buffer (u32 per col)
    float* xf     = alloc((size_t)N_NODES * F_IN);
    float* dis    = alloc(N_NODES);
    float* pooled = alloc(G_GRAPHS);
    float* counts = alloc(G_GRAPHS);
    int*   flag   = (int*)alloc(1);
    int*   rowptr = (int*)alloc(N_NODES + 1);
    int*   cursor = (int*)alloc(N_NODES);
    int*   csrsrc = (int*)alloc(N_EDGES);
    int*   bsums  = (int*)alloc(32);
    int*   bsums2 = (int*)alloc(32);
    int*   tstart = (int*)alloc(N_NODES + 1);
    int*   ntiles = (int*)alloc(1);
    int*   tileN  = (int*)alloc(MAXT);
    int*   tileBeg= (int*)alloc(MAXT);

    float* W1  = alloc(F_IN * H);
    float* b1  = alloc(H);
    float* W2  = alloc(HH);
    float* b2  = alloc(H);
    float* We1 = alloc(2 * HH);
    float* be1 = alloc(H);
    float* We2 = alloc(HH);
    float* be2 = alloc(H);
    float* Wf1 = alloc(HH);
    float* bf1 = alloc(H);
    float* Wf2 = alloc(H * 32);
    float* bf2 = alloc(32);
    float* Wf3 = alloc(32);
    float* bf3 = alloc(4);
    short* WfU  = (short*)alloc(8192);
    short* WfV  = (short*)alloc(8192);
    short* WfW2 = (short*)alloc(8192);
    short* WfF1 = (short*)alloc(8192);
    short* WfF2 = (short*)alloc(2048);
    short* We2f = (short*)alloc(8192);

    const int eB    = (N_EDGES + 255) / 256;
    const int nB    = (N_NODES + 255) / 256;
    const int scanB = (N_NODES + 2047) / 2048;
    const int mfmaB = (N_NODES / 16 + 3) / 4;      // 782
    const int gcnB  = (N_NODES + 3) / 4;           // 12500
    const int tileB = MAXT / 4;                    // 25000 (waves early-exit past ntiles)
    const int zAggB = (int)((NH + 255) / 256);     // 25000
    const int combB = (N_NODES * 64 + 255) / 256;  // 12500

    k_detect<<<1, 256, 0, stream>>>((const unsigned*)d_in[0], flag);

    CvtArgs ca;
    const int srcIdx[15] = {0, 3, 4, 5, 6, 7, 8, 9, 10, 11, 12, 13, 14, 15, 16};
    float* dsts[15] = {xf, W1, b1, W2, b2, We1, be1, We2, be2, Wf1, bf1, Wf2, bf2, Wf3, bf3};
    for (int s = 0; s < 15; ++s) { ca.src[s] = d_in[srcIdx[s]]; ca.dst[s] = dsts[s]; }
    const int cvtTotal = 450000 + 1152 + 128 + 16384 + 128 + 32768 + 128 + 16384 + 128
                       + 16384 + 128 + 4096 + 32 + 32 + 1;       // 537873
    k_cvt_all<<<(cvtTotal + 255) / 256, 256, 0, stream>>>(ca, flag);

    k_sub<<<(HH + 255) / 256, 256, 0, stream>>>(We1);
    k_prep<<<8, 256, 0, stream>>>(We1, WfU, 8);
    k_prep<<<8, 256, 0, stream>>>(We1 + HH, WfV, 8);
    k_prep<<<8, 256, 0, stream>>>(W2, WfW2, 8);
    k_prep<<<8, 256, 0, stream>>>(Wf1, WfF1, 8);
    k_prep<<<2, 256, 0, stream>>>(Wf2, WfF2, 2);
    k_prep<<<8, 256, 0, stream>>>(We2, We2f, 8);

    // CSR build (sorted by dst)
    k_zero<<<nB, 256, 0, stream>>>((float*)cursor, N_NODES);
    k_hist<<<eB, 256, 0, stream>>>(dst, cursor);
    k_scan1<<<scanB, 256, 0, stream>>>(cursor, rowptr, bsums);
    k_scan2<<<1, 1, 0, stream>>>(bsums, scanB, rowptr);
    k_scan3<<<nB, 256, 0, stream>>>(rowptr, bsums);
    k_zero<<<nB, 256, 0, stream>>>((float*)cursor, N_NODES);
    k_scatter<<<eB, 256, 0, stream>>>(src, dst, rowptr, cursor, csrsrc);
    k_dis<<<nB, 256, 0, stream>>>(rowptr, dis);
    k_zero<<<1, 256, 0, stream>>>(pooled, 2 * G_GRAPHS);
    k_counts<<<nB, 256, 0, stream>>>(batch, counts);

    // tile list: tstart = exclusive-scan(ceil(deg/16)); tileN/tileBeg flat list
    k_tcnt<<<nB, 256, 0, stream>>>(rowptr, cursor);
    k_scan1<<<scanB, 256, 0, stream>>>(cursor, tstart, bsums2);
    k_scan2t<<<1, 1, 0, stream>>>(bsums2, scanB, tstart, ntiles);
    k_scan3<<<nB, 256, 0, stream>>>(tstart, bsums2);
    k_tfill<<<nB, 256, 0, stream>>>(rowptr, tstart, tileN, tileBeg);

    // GCN1
    k_gemm_f32bf_scale<<<(N_NODES + 7) / 8, 256, 0, stream>>>(xf, W1, dis, Ub, N_NODES);
    k_gcn_fused<<<gcnB, 256, 0, stream>>>(rowptr, csrsrc, Ub, dis, b1, hb);

    for (int iter = 0; iter < 3; ++iter) {
        k_gemm_dual<<<mfmaB, 256, 0, stream>>>(hb, WfU, WfV, be1, Ub, Vb, N_NODES);
        k_zero<<<zAggB, 256, 0, stream>>>((float*)aggEnc, (int)NH);
        k_edge_tile<<<tileB, 256, 0, stream>>>(rowptr, csrsrc, tileN, tileBeg, ntiles,
                                               Ub, Vb, We2f, aggEnc);
        k_edge_combine<<<combB, 256, 0, stream>>>(aggEnc, be2, hb);
        if (iter < 2) {
            k_gemm_scale<<<mfmaB, 256, 0, stream>>>(hb, WfW2, dis, Ub, N_NODES);
            k_gcn_fused<<<gcnB, 256, 0, stream>>>(rowptr, csrsrc, Ub, dis, b2, hb);
        }
    }

    k_final_mlp<<<mfmaB, 256, 0, stream>>>(hb, WfF1, WfF2, bf1, bf2, Wf3, bf3,
                                           batch, pooled, N_NODES);
    k_final<<<1, 64, 0, stream>>>(pooled, counts, d_out, flag);
}

// Round 10
// 559.173 us; speedup vs baseline: 3.1792x; 1.2534x over previous
//
#include <hip/hip_runtime.h>
#include <hip/hip_bf16.h>

#define N_NODES 50000
#define N_EDGES 800000
#define F_IN 9
#define H 128
#define G_GRAPHS 64
#define HH (H * H)
#define MAXT (N_EDGES / 16 + N_NODES)   // 100000 upper bound on tile count

typedef short bf16x8 __attribute__((ext_vector_type(8)));
typedef float f32x4 __attribute__((ext_vector_type(4)));

static __device__ inline short f2b(float f) {
    __hip_bfloat16 h = __float2bfloat16(f);
    return *reinterpret_cast<short*>(&h);
}
static __device__ inline float blo(unsigned u) { return __uint_as_float(u << 16); }
static __device__ inline float bhi(unsigned u) { return __uint_as_float(u & 0xFFFF0000u); }
static __device__ inline unsigned encodef(float f) {
    unsigned u = __float_as_uint(f);
    return (u & 0x80000000u) ? ~u : (u | 0x80000000u);
}
static __device__ inline float decodef(unsigned u) {
    return __uint_as_float((u & 0x80000000u) ? (u ^ 0x80000000u) : ~u);
}

// ---------- dtype detection ----------
__global__ __launch_bounds__(256) void k_detect(const unsigned* __restrict__ x, int* flag) {
    __shared__ int cnt;
    if (threadIdx.x == 0) cnt = 0;
    __syncthreads();
    unsigned u = x[threadIdx.x];
    int e = (u >> 7) & 0xFF;
    if (e >= 0x70 && e <= 0x83) atomicAdd(&cnt, 1);
    __syncthreads();
    if (threadIdx.x == 0) *flag = (cnt >= 128) ? 1 : 0;
}

// ---------- batched convert of all float inputs ----------
struct CvtArgs { const void* src[15]; float* dst[15]; };

__global__ __launch_bounds__(256) void k_cvt_all(CvtArgs a, const int* __restrict__ flag) {
    const int sz[15] = {450000, 1152, 128, 16384, 128, 32768, 128, 16384, 128,
                        16384, 128, 4096, 32, 32, 1};
    int i = blockIdx.x * 256 + threadIdx.x;
    int fl = *flag;
    int base = 0;
    #pragma unroll
    for (int s = 0; s < 15; ++s) {
        if (i >= base && i < base + sz[s]) {
            int off = i - base;
            float v = fl ? __bfloat162float(((const __hip_bfloat16*)a.src[s])[off])
                         : ((const float*)a.src[s])[off];
            a.dst[s][off] = v;
        }
        base += sz[s];
    }
}

__global__ __launch_bounds__(256) void k_zero(float* p, int n) {
    int i = blockIdx.x * 256 + threadIdx.x;
    if (i < n) p[i] = 0.f;
}

__global__ __launch_bounds__(256) void k_sub(float* w) {
    int i = blockIdx.x * 256 + threadIdx.x;
    if (i < HH) w[i] -= w[HH + i];
}

// ---------- W[128,NT*16] f32 -> bf16 MFMA B-fragment table ----------
__global__ __launch_bounds__(256) void k_prep(const float* __restrict__ W,
                                              short* __restrict__ Wf, int NT) {
    int tid = blockIdx.x * 256 + threadIdx.x;
    int total = 4 * NT * 64;
    if (tid >= total) return;
    int kc = tid / (NT * 64);
    int ct = (tid / 64) % NT;
    int lane = tid & 63;
    int Nc = NT * 16;
    int kb = kc * 32 + (lane >> 4) * 8;
    int col = ct * 16 + (lane & 15);
    #pragma unroll
    for (int j = 0; j < 8; ++j)
        Wf[tid * 8 + j] = f2b(W[(kb + j) * Nc + col]);
}

// ---------- CSR build ----------
__global__ __launch_bounds__(256) void k_hist(const int* __restrict__ dst, int* cnt) {
    int e = blockIdx.x * 256 + threadIdx.x;
    if (e < N_EDGES) atomicAdd(&cnt[dst[e]], 1);
}

__global__ __launch_bounds__(256) void k_scan1(const int* __restrict__ deg, int* __restrict__ out,
                                               int* __restrict__ blockSums) {
    __shared__ int lds[256];
    int base = blockIdx.x * 2048;
    int t = threadIdx.x;
    int local[8];
    int s = 0;
    #pragma unroll
    for (int j = 0; j < 8; ++j) {
        int idx = base + t * 8 + j;
        int v = (idx < N_NODES) ? deg[idx] : 0;
        local[j] = s;
        s += v;
    }
    lds[t] = s;
    __syncthreads();
    if (t == 0) {
        int run = 0;
        for (int i = 0; i < 256; ++i) { int v = lds[i]; lds[i] = run; run += v; }
        blockSums[blockIdx.x] = run;
    }
    __syncthreads();
    int offs = lds[t];
    #pragma unroll
    for (int j = 0; j < 8; ++j) {
        int idx = base + t * 8 + j;
        if (idx < N_NODES) out[idx] = offs + local[j];
    }
}

__global__ void k_scan2(int* blockSums, int nb, int* rowptr) {
    int run = 0;
    for (int i = 0; i < nb; ++i) { int v = blockSums[i]; blockSums[i] = run; run += v; }
    rowptr[N_NODES] = N_EDGES;
}

// scan finalize for tile starts: also records total tile count
__global__ void k_scan2t(int* blockSums, int nb, int* tstart, int* ntiles) {
    int run = 0;
    for (int i = 0; i < nb; ++i) { int v = blockSums[i]; blockSums[i] = run; run += v; }
    tstart[N_NODES] = run;
    *ntiles = run;
}

__global__ __launch_bounds__(256) void k_scan3(int* rowptr, const int* __restrict__ blockSums) {
    int idx = blockIdx.x * 256 + threadIdx.x;
    if (idx < N_NODES) rowptr[idx] += blockSums[idx >> 11];
}

__global__ __launch_bounds__(256) void k_scatter(const int* __restrict__ src, const int* __restrict__ dst,
                                                 const int* __restrict__ rowptr, int* cursor,
                                                 int* __restrict__ csr_src) {
    int e = blockIdx.x * 256 + threadIdx.x;
    if (e >= N_EDGES) return;
    int d = dst[e];
    int pos = rowptr[d] + atomicAdd(&cursor[d], 1);
    csr_src[pos] = src[e];
}

// dis + tile-count in one pass
__global__ __launch_bounds__(256) void k_dis_tcnt(const int* __restrict__ rowptr, float* dis, int* tcnt) {
    int n = blockIdx.x * 256 + threadIdx.x;
    if (n < N_NODES) {
        int deg = rowptr[n + 1] - rowptr[n];
        dis[n] = rsqrtf((float)deg + 1.0f);
        tcnt[n] = (deg + 15) >> 4;
    }
}

// ---------- tile list: tileN + padded per-tile src indices ----------
__global__ __launch_bounds__(256) void k_tfill(const int* __restrict__ rowptr,
                                               const int* __restrict__ csr_src,
                                               const int* __restrict__ tstart,
                                               int* __restrict__ tileN,
                                               int* __restrict__ tileSrc) {
    int n = blockIdx.x * 256 + threadIdx.x;
    if (n >= N_NODES) return;
    int t0 = tstart[n], t1 = tstart[n + 1];
    int beg = rowptr[n], end = rowptr[n + 1];
    for (int t = t0; t < t1; ++t) {
        tileN[t] = n;
        int tb = beg + (t - t0) * 16;
        #pragma unroll 4
        for (int j = 0; j < 16; ++j) {
            int ei = tb + j;
            tileSrc[t * 16 + j] = csr_src[ei < end ? ei : end - 1];
        }
    }
}

// ---------- counts per graph ----------
__global__ __launch_bounds__(256) void k_counts(const int* __restrict__ batch, float* counts) {
    __shared__ float lc[G_GRAPHS];
    int tid = threadIdx.x;
    if (tid < G_GRAPHS) lc[tid] = 0.f;
    __syncthreads();
    int n = blockIdx.x * 256 + tid;
    if (n < N_NODES) atomicAdd(&lc[batch[n]], 1.0f);
    __syncthreads();
    if (tid < G_GRAPHS && lc[tid] > 0.f) atomicAdd(&counts[tid], lc[tid]);
}

// ---------- GCN1 GEMM: out = (x[M,9] @ W1[9,128]) * dis[row], bf16 ----------
__global__ __launch_bounds__(256) void k_gemm_f32bf_scale(const float* __restrict__ A,
                                                          const float* __restrict__ W,
                                                          const float* __restrict__ dis,
                                                          short* __restrict__ out, int M) {
    __shared__ float w_lds[F_IN * H];
    for (int i = threadIdx.x; i < F_IN * H; i += 256) w_lds[i] = W[i];
    __syncthreads();
    int row = blockIdx.x * 8 + threadIdx.x / 32;
    int c4 = (threadIdx.x & 31) << 2;
    if (row >= M) return;
    const float* a = A + (size_t)row * F_IN;
    float acc0 = 0.f, acc1 = 0.f, acc2 = 0.f, acc3 = 0.f;
    #pragma unroll
    for (int k = 0; k < F_IN; ++k) {
        float av = a[k];
        float4 w = *reinterpret_cast<const float4*>(&w_lds[k * H + c4]);
        acc0 = fmaf(av, w.x, acc0);
        acc1 = fmaf(av, w.y, acc1);
        acc2 = fmaf(av, w.z, acc2);
        acc3 = fmaf(av, w.w, acc3);
    }
    float dv = dis[row];
    short* op = &out[(size_t)row * H + c4];
    op[0] = f2b(acc0 * dv); op[1] = f2b(acc1 * dv);
    op[2] = f2b(acc2 * dv); op[3] = f2b(acc3 * dv);
}

// ---------- dual MFMA GEMM (512 thr, 8 waves): U = A@WU + be1 ; V = A@WV ----------
__global__ __launch_bounds__(512) void k_gemm_dual(const short* __restrict__ A,
                                                   const short* __restrict__ WfU,
                                                   const short* __restrict__ WfV,
                                                   const float* __restrict__ be1,
                                                   short* __restrict__ U,
                                                   short* __restrict__ V, int M) {
    __shared__ short wl[32768];
    for (int i = threadIdx.x * 8; i < 16384; i += 4096) {
        *reinterpret_cast<f32x4*>(&wl[i])         = *reinterpret_cast<const f32x4*>(&WfU[i]);
        *reinterpret_cast<f32x4*>(&wl[16384 + i]) = *reinterpret_cast<const f32x4*>(&WfV[i]);
    }
    __syncthreads();
    int wv = threadIdx.x >> 6, lane = threadIdx.x & 63;
    int er = lane & 15, kg = lane >> 4;
    int row0 = (blockIdx.x * 8 + wv) * 16;
    if (row0 >= M) return;
    bf16x8 af[4];
    #pragma unroll
    for (int kc = 0; kc < 4; ++kc)
        af[kc] = *reinterpret_cast<const bf16x8*>(&A[(size_t)(row0 + er) * H + kc * 32 + kg * 8]);
    const f32x4 vzero = {0.f, 0.f, 0.f, 0.f};
    f32x4 acc[8];
    #pragma unroll
    for (int ct = 0; ct < 8; ++ct) acc[ct] = vzero;
    #pragma unroll
    for (int kc = 0; kc < 4; ++kc)
        #pragma unroll
        for (int ct = 0; ct < 8; ++ct) {
            bf16x8 bf = *reinterpret_cast<const bf16x8*>(&wl[((kc * 8 + ct) * 64 + lane) * 8]);
            acc[ct] = __builtin_amdgcn_mfma_f32_16x16x32_bf16(af[kc], bf, acc[ct], 0, 0, 0);
        }
    #pragma unroll
    for (int ct = 0; ct < 8; ++ct) {
        int col = ct * 16 + er;
        float bv = be1[col];
        #pragma unroll
        for (int r = 0; r < 4; ++r)
            U[(size_t)(row0 + kg * 4 + r) * H + col] = f2b(acc[ct][r] + bv);
    }
    #pragma unroll
    for (int ct = 0; ct < 8; ++ct) acc[ct] = vzero;
    #pragma unroll
    for (int kc = 0; kc < 4; ++kc)
        #pragma unroll
        for (int ct = 0; ct < 8; ++ct) {
            bf16x8 bf = *reinterpret_cast<const bf16x8*>(&wl[16384 + ((kc * 8 + ct) * 64 + lane) * 8]);
            acc[ct] = __builtin_amdgcn_mfma_f32_16x16x32_bf16(af[kc], bf, acc[ct], 0, 0, 0);
        }
    #pragma unroll
    for (int ct = 0; ct < 8; ++ct) {
        int col = ct * 16 + er;
        #pragma unroll
        for (int r = 0; r < 4; ++r)
            V[(size_t)(row0 + kg * 4 + r) * H + col] = f2b(acc[ct][r]);
    }
}

// ---------- MFMA GEMM with dis-scale epilogue (512 thr) ----------
__global__ __launch_bounds__(512) void k_gemm_scale(const short* __restrict__ A,
                                                    const short* __restrict__ Wf,
                                                    const float* __restrict__ dis,
                                                    short* __restrict__ out, int M) {
    __shared__ short wl[16384];
    for (int i = threadIdx.x * 8; i < 16384; i += 4096)
        *reinterpret_cast<f32x4*>(&wl[i]) = *reinterpret_cast<const f32x4*>(&Wf[i]);
    __syncthreads();
    int wv = threadIdx.x >> 6, lane = threadIdx.x & 63;
    int er = lane & 15, kg = lane >> 4;
    int row0 = (blockIdx.x * 8 + wv) * 16;
    if (row0 >= M) return;
    bf16x8 af[4];
    #pragma unroll
    for (int kc = 0; kc < 4; ++kc)
        af[kc] = *reinterpret_cast<const bf16x8*>(&A[(size_t)(row0 + er) * H + kc * 32 + kg * 8]);
    const f32x4 vzero = {0.f, 0.f, 0.f, 0.f};
    f32x4 acc[8];
    #pragma unroll
    for (int ct = 0; ct < 8; ++ct) acc[ct] = vzero;
    #pragma unroll
    for (int kc = 0; kc < 4; ++kc)
        #pragma unroll
        for (int ct = 0; ct < 8; ++ct) {
            bf16x8 bf = *reinterpret_cast<const bf16x8*>(&wl[((kc * 8 + ct) * 64 + lane) * 8]);
            acc[ct] = __builtin_amdgcn_mfma_f32_16x16x32_bf16(af[kc], bf, acc[ct], 0, 0, 0);
        }
    float dv[4];
    #pragma unroll
    for (int r = 0; r < 4; ++r) dv[r] = dis[row0 + kg * 4 + r];
    #pragma unroll
    for (int ct = 0; ct < 8; ++ct) {
        int col = ct * 16 + er;
        #pragma unroll
        for (int r = 0; r < 4; ++r)
            out[(size_t)(row0 + kg * 4 + r) * H + col] = f2b(acc[ct][r] * dv[r]);
    }
}

// ---------- GCN fused agg+combine (CSR, pre-scaled rows, 8-way unrolled) ----------
__global__ __launch_bounds__(256) void k_gcn_fused(const int* __restrict__ rowptr,
                                                   const int* __restrict__ csr_src,
                                                   const short* __restrict__ hWs,
                                                   const float* __restrict__ dis,
                                                   const float* __restrict__ bias,
                                                   short* __restrict__ out) {
    int wv = threadIdx.x >> 6, lane = threadIdx.x & 63;
    const unsigned* hw = (const unsigned*)hWs;
    for (int n = blockIdx.x * 4 + wv; n < N_NODES; n += gridDim.x * 4) {
        int beg = rowptr[n], end = rowptr[n + 1];
        float a0 = 0.f, a1 = 0.f, b0 = 0.f, b1 = 0.f;
        float c0 = 0.f, c1 = 0.f, d0 = 0.f, d1 = 0.f;
        int e = beg;
        for (; e + 8 <= end; e += 8) {
            int s0 = csr_src[e],     s1 = csr_src[e + 1], s2 = csr_src[e + 2], s3 = csr_src[e + 3];
            int s4 = csr_src[e + 4], s5 = csr_src[e + 5], s6 = csr_src[e + 6], s7 = csr_src[e + 7];
            unsigned w0 = hw[(size_t)s0 * 64 + lane];
            unsigned w1 = hw[(size_t)s1 * 64 + lane];
            unsigned w2 = hw[(size_t)s2 * 64 + lane];
            unsigned w3 = hw[(size_t)s3 * 64 + lane];
            unsigned w4 = hw[(size_t)s4 * 64 + lane];
            unsigned w5 = hw[(size_t)s5 * 64 + lane];
            unsigned w6 = hw[(size_t)s6 * 64 + lane];
            unsigned w7 = hw[(size_t)s7 * 64 + lane];
            a0 += blo(w0); a1 += bhi(w0);
            b0 += blo(w1); b1 += bhi(w1);
            c0 += blo(w2); c1 += bhi(w2);
            d0 += blo(w3); d1 += bhi(w3);
            a0 += blo(w4); a1 += bhi(w4);
            b0 += blo(w5); b1 += bhi(w5);
            c0 += blo(w6); c1 += bhi(w6);
            d0 += blo(w7); d1 += bhi(w7);
        }
        for (; e + 4 <= end; e += 4) {
            int s0 = csr_src[e], s1 = csr_src[e + 1], s2 = csr_src[e + 2], s3 = csr_src[e + 3];
            unsigned w0 = hw[(size_t)s0 * 64 + lane];
            unsigned w1 = hw[(size_t)s1 * 64 + lane];
            unsigned w2 = hw[(size_t)s2 * 64 + lane];
            unsigned w3 = hw[(size_t)s3 * 64 + lane];
            a0 += blo(w0); a1 += bhi(w0);
            b0 += blo(w1); b1 += bhi(w1);
            c0 += blo(w2); c1 += bhi(w2);
            d0 += blo(w3); d1 += bhi(w3);
        }
        for (; e < end; ++e) {
            unsigned w = hw[(size_t)csr_src[e] * 64 + lane];
            a0 += blo(w); a1 += bhi(w);
        }
        float s0f = (a0 + b0) + (c0 + d0);
        float s1f = (a1 + b1) + (c1 + d1);
        float dn = dis[n];
        unsigned wn = hw[(size_t)n * 64 + lane];
        float r0 = tanhf(dn * (s0f + blo(wn)) + bias[lane * 2]);
        float r1 = tanhf(dn * (s1f + bhi(wn)) + bias[lane * 2 + 1]);
        unsigned o = (unsigned)(unsigned short)f2b(r0) | ((unsigned)(unsigned short)f2b(r1) << 16);
        *reinterpret_cast<unsigned*>(&out[(size_t)n * H + lane * 2]) = o;
    }
}

// ---------- EdgeConv: one wave per 16-edge tile (512 thr); precomputed tileSrc ----------
__global__ __launch_bounds__(512) void k_edge_tile(const int* __restrict__ tileN,
                                                   const int* __restrict__ tileSrc,
                                                   const int* __restrict__ ntilesp,
                                                   const short* __restrict__ U,
                                                   const short* __restrict__ V,
                                                   const short* __restrict__ We2f,
                                                   unsigned* aggEnc) {
    int nt = *ntilesp;
    if ((int)(blockIdx.x * 8) >= nt) return;     // uniform early-out for whole block
    __shared__ short wl[16384];
    for (int i = threadIdx.x * 8; i < 16384; i += 4096)
        *reinterpret_cast<f32x4*>(&wl[i]) = *reinterpret_cast<const f32x4*>(&We2f[i]);
    __syncthreads();
    int wv = threadIdx.x >> 6, lane = threadIdx.x & 63;
    int er = lane & 15, kg = lane >> 4, kseg = kg * 8;
    int tid = blockIdx.x * 8 + wv;
    if (tid >= nt) return;
    int n = tileN[tid];
    int s = tileSrc[tid * 16 + er];              // padded rows duplicate last edge (max-safe)
    const f32x4 vzero = {0.f, 0.f, 0.f, 0.f};
    f32x4 acc[8];
    #pragma unroll
    for (int ct = 0; ct < 8; ++ct) acc[ct] = vzero;
    #pragma unroll
    for (int kc = 0; kc < 4; ++kc) {
        uint4 uu4 = *reinterpret_cast<const uint4*>(&U[(size_t)n * H + kc * 32 + kseg]);
        uint4 vv4 = *reinterpret_cast<const uint4*>(&V[(size_t)s * H + kc * 32 + kseg]);
        bf16x8 af;
        unsigned uu, vv;
        uu = uu4.x; vv = vv4.x;
        af[0] = f2b(fmaxf(blo(uu) + blo(vv), 0.f));
        af[1] = f2b(fmaxf(bhi(uu) + bhi(vv), 0.f));
        uu = uu4.y; vv = vv4.y;
        af[2] = f2b(fmaxf(blo(uu) + blo(vv), 0.f));
        af[3] = f2b(fmaxf(bhi(uu) + bhi(vv), 0.f));
        uu = uu4.z; vv = vv4.z;
        af[4] = f2b(fmaxf(blo(uu) + blo(vv), 0.f));
        af[5] = f2b(fmaxf(bhi(uu) + bhi(vv), 0.f));
        uu = uu4.w; vv = vv4.w;
        af[6] = f2b(fmaxf(blo(uu) + blo(vv), 0.f));
        af[7] = f2b(fmaxf(bhi(uu) + bhi(vv), 0.f));
        #pragma unroll
        for (int ct = 0; ct < 8; ++ct) {
            bf16x8 bf = *reinterpret_cast<const bf16x8*>(&wl[((kc * 8 + ct) * 64 + lane) * 8]);
            acc[ct] = __builtin_amdgcn_mfma_f32_16x16x32_bf16(af, bf, acc[ct], 0, 0, 0);
        }
    }
    float cm[8];
    #pragma unroll
    for (int ct = 0; ct < 8; ++ct) {
        float v = fmaxf(fmaxf(acc[ct][0], acc[ct][1]), fmaxf(acc[ct][2], acc[ct][3]));
        v = fmaxf(v, __shfl_xor(v, 16));
        v = fmaxf(v, __shfl_xor(v, 32));
        cm[ct] = v;
    }
    float vA, vB;
    if (kg == 0)      { vA = cm[0]; vB = cm[1]; }
    else if (kg == 1) { vA = cm[2]; vB = cm[3]; }
    else if (kg == 2) { vA = cm[4]; vB = cm[5]; }
    else              { vA = cm[6]; vB = cm[7]; }
    int colA = (kg * 2) * 16 + er;
    int colB = (kg * 2 + 1) * 16 + er;
    atomicMax(&aggEnc[(size_t)n * H + colA], encodef(vA));
    atomicMax(&aggEnc[(size_t)n * H + colB], encodef(vB));
}

// ---------- EdgeConv combine: out = tanh(empty ? 0 : decode(max)+be2), bf16 ----------
__global__ __launch_bounds__(256) void k_edge_combine(const unsigned* __restrict__ aggEnc,
                                                      const float* __restrict__ be2,
                                                      short* __restrict__ out) {
    int i = blockIdx.x * 256 + threadIdx.x;      // N*64 threads, 2 cols each
    if (i >= N_NODES * 64) return;
    int n = i >> 6, c2 = (i & 63) << 1;
    unsigned u0 = aggEnc[(size_t)n * H + c2];
    unsigned u1 = aggEnc[(size_t)n * H + c2 + 1];
    float r0 = tanhf(u0 ? (decodef(u0) + be2[c2]) : 0.f);
    float r1 = tanhf(u1 ? (decodef(u1) + be2[c2 + 1]) : 0.f);
    unsigned o = (unsigned)(unsigned short)f2b(r0) | ((unsigned)(unsigned short)f2b(r1) << 16);
    *reinterpret_cast<unsigned*>(&out[(size_t)n * H + c2]) = o;
}

// ---------- fused final MLP + pooling (512 thr, 8 waves) ----------
__global__ __launch_bounds__(512) void k_final_mlp(const short* __restrict__ h,
                                                   const short* __restrict__ WfF1,
                                                   const short* __restrict__ WfF2,
                                                   const float* __restrict__ bf1,
                                                   const float* __restrict__ bf2,
                                                   const float* __restrict__ Wf3,
                                                   const float* __restrict__ bf3,
                                                   const int* __restrict__ batch,
                                                   float* pooled, int M) {
    __shared__ short wl1[16384];
    __shared__ short wl2[4096];
    __shared__ short tb[8][2048];
    __shared__ float lp[G_GRAPHS];
    for (int i = threadIdx.x * 8; i < 16384; i += 4096)
        *reinterpret_cast<f32x4*>(&wl1[i]) = *reinterpret_cast<const f32x4*>(&WfF1[i]);
    if (threadIdx.x < 512) {
        int i = threadIdx.x * 8;
        if (i < 4096)
            *reinterpret_cast<f32x4*>(&wl2[i]) = *reinterpret_cast<const f32x4*>(&WfF2[i]);
    }
    if (threadIdx.x < G_GRAPHS) lp[threadIdx.x] = 0.f;
    __syncthreads();
    int wv = threadIdx.x >> 6, lane = threadIdx.x & 63;
    int er = lane & 15, kg = lane >> 4;
    int row0 = (blockIdx.x * 8 + wv) * 16;
    bool active = row0 < M;
    const f32x4 vzero = {0.f, 0.f, 0.f, 0.f};
    if (active) {
        bf16x8 af[4];
        #pragma unroll
        for (int kc = 0; kc < 4; ++kc)
            af[kc] = *reinterpret_cast<const bf16x8*>(&h[(size_t)(row0 + er) * H + kc * 32 + kg * 8]);
        f32x4 acc[8];
        #pragma unroll
        for (int ct = 0; ct < 8; ++ct) acc[ct] = vzero;
        #pragma unroll
        for (int kc = 0; kc < 4; ++kc)
            #pragma unroll
            for (int ct = 0; ct < 8; ++ct) {
                bf16x8 bf = *reinterpret_cast<const bf16x8*>(&wl1[((kc * 8 + ct) * 64 + lane) * 8]);
                acc[ct] = __builtin_amdgcn_mfma_f32_16x16x32_bf16(af[kc], bf, acc[ct], 0, 0, 0);
            }
        #pragma unroll
        for (int ct = 0; ct < 8; ++ct) {
            int col = ct * 16 + er;
            float bv = bf1[col];
            #pragma unroll
            for (int r = 0; r < 4; ++r)
                tb[wv][(kg * 4 + r) * 128 + col] = f2b(tanhf(acc[ct][r] + bv));
        }
    }
    __syncthreads();
    if (active) {
        bf16x8 af2[4];
        #pragma unroll
        for (int kc = 0; kc < 4; ++kc)
            af2[kc] = *reinterpret_cast<const bf16x8*>(&tb[wv][er * 128 + kc * 32 + kg * 8]);
        f32x4 a2[2];
        a2[0] = vzero; a2[1] = vzero;
        #pragma unroll
        for (int kc = 0; kc < 4; ++kc)
            #pragma unroll
            for (int ct = 0; ct < 2; ++ct) {
                bf16x8 bf = *reinterpret_cast<const bf16x8*>(&wl2[((kc * 2 + ct) * 64 + lane) * 8]);
                a2[ct] = __builtin_amdgcn_mfma_f32_16x16x32_bf16(af2[kc], bf, a2[ct], 0, 0, 0);
            }
        float w3a = Wf3[er], w3b = Wf3[16 + er];
        float b2a = bf2[er], b2b = bf2[16 + er];
        float bf3v = bf3[0];
        float psum[4];
        #pragma unroll
        for (int r = 0; r < 4; ++r) {
            float f2a = tanhf(a2[0][r] + b2a);
            float f2c = tanhf(a2[1][r] + b2b);
            float p = f2a * w3a + f2c * w3b;
            p += __shfl_xor(p, 1);
            p += __shfl_xor(p, 2);
            p += __shfl_xor(p, 4);
            p += __shfl_xor(p, 8);
            psum[r] = p + bf3v;
        }
        if (er == 0) {
            #pragma unroll
            for (int r = 0; r < 4; ++r) {
                int n = row0 + kg * 4 + r;
                if (n < M) atomicAdd(&lp[batch[n]], psum[r]);
            }
        }
    }
    __syncthreads();
    if (threadIdx.x < G_GRAPHS && lp[threadIdx.x] != 0.f)
        atomicAdd(&pooled[threadIdx.x], lp[threadIdx.x]);
}

__global__ __launch_bounds__(64) void k_final(const float* pooled, const float* counts,
                                              void* out, const int* __restrict__ flag) {
    int g = threadIdx.x;
    if (g < G_GRAPHS) {
        float v = pooled[g] / fmaxf(counts[g], 1.0f);
        float s = 1.0f / (1.0f + expf(-v));
        if (*flag) ((__hip_bfloat16*)out)[g] = __float2bfloat16(s);
        else       ((float*)out)[g] = s;
    }
}

extern "C" void kernel_launch(void* const* d_in, const int* in_sizes, int n_in,
                              void* d_out, int out_size, void* d_ws, size_t ws_size,
                              hipStream_t stream) {
    const int* ei    = (const int*)d_in[1];
    const int* src   = ei;
    const int* dst   = ei + N_EDGES;
    const int* batch = (const int*)d_in[2];

    float* ws = (float*)d_ws;
    size_t off = 0;
    auto alloc = [&](size_t n) { off = (off + 3) & ~(size_t)3; float* p = ws + off; off += n; return p; };

    const size_t NH = (size_t)N_NODES * H;
    short* hb     = (short*)alloc(NH / 2);
    short* Ub     = (short*)alloc(NH / 2);
    short* Vb     = (short*)alloc(NH / 2);
    unsigned* aggEnc = (unsigned*)alloc(NH);
    float* xf     = alloc((size_t)N_NODES * F_IN);
    float* dis    = alloc(N_NODES);
    float* pooled = alloc(G_GRAPHS);
    float* counts = alloc(G_GRAPHS);
    int*   flag   = (int*)alloc(1);
    int*   rowptr = (int*)alloc(N_NODES + 1);
    int*   cursor = (int*)alloc(N_NODES);
    int*   csrsrc = (int*)alloc(N_EDGES);
    int*   bsums  = (int*)alloc(32);
    int*   bsums2 = (int*)alloc(32);
    int*   tstart = (int*)alloc(N_NODES + 1);
    int*   ntiles = (int*)alloc(1);
    int*   tileN  = (int*)alloc(MAXT);
    int*   tileSrc= (int*)alloc((size_t)MAXT * 16);

    float* W1  = alloc(F_IN * H);
    float* b1  = alloc(H);
    float* W2  = alloc(HH);
    float* b2  = alloc(H);
    float* We1 = alloc(2 * HH);
    float* be1 = alloc(H);
    float* We2 = alloc(HH);
    float* be2 = alloc(H);
    float* Wf1 = alloc(HH);
    float* bf1 = alloc(H);
    float* Wf2 = alloc(H * 32);
    float* bf2 = alloc(32);
    float* Wf3 = alloc(32);
    float* bf3 = alloc(4);
    short* WfU  = (short*)alloc(8192);
    short* WfV  = (short*)alloc(8192);
    short* WfW2 = (short*)alloc(8192);
    short* WfF1 = (short*)alloc(8192);
    short* WfF2 = (short*)alloc(2048);
    short* We2f = (short*)alloc(8192);

    const int eB    = (N_EDGES + 255) / 256;
    const int nB    = (N_NODES + 255) / 256;
    const int scanB = (N_NODES + 2047) / 2048;
    const int mfmaB = (N_NODES / 16 + 7) / 8;      // 391 blocks of 512 (8 strips each)
    const int gcnB  = (N_NODES + 3) / 4;           // 12500
    const int tileB = (MAXT + 7) / 8;              // 12500 blocks of 512
    const int zAggB = (int)((NH + 255) / 256);
    const int combB = (N_NODES * 64 + 255) / 256;

    k_detect<<<1, 256, 0, stream>>>((const unsigned*)d_in[0], flag);

    CvtArgs ca;
    const int srcIdx[15] = {0, 3, 4, 5, 6, 7, 8, 9, 10, 11, 12, 13, 14, 15, 16};
    float* dsts[15] = {xf, W1, b1, W2, b2, We1, be1, We2, be2, Wf1, bf1, Wf2, bf2, Wf3, bf3};
    for (int s = 0; s < 15; ++s) { ca.src[s] = d_in[srcIdx[s]]; ca.dst[s] = dsts[s]; }
    const int cvtTotal = 450000 + 1152 + 128 + 16384 + 128 + 32768 + 128 + 16384 + 128
                       + 16384 + 128 + 4096 + 32 + 32 + 1;       // 537873
    k_cvt_all<<<(cvtTotal + 255) / 256, 256, 0, stream>>>(ca, flag);

    k_sub<<<(HH + 255) / 256, 256, 0, stream>>>(We1);
    k_prep<<<8, 256, 0, stream>>>(We1, WfU, 8);
    k_prep<<<8, 256, 0, stream>>>(We1 + HH, WfV, 8);
    k_prep<<<8, 256, 0, stream>>>(W2, WfW2, 8);
    k_prep<<<8, 256, 0, stream>>>(Wf1, WfF1, 8);
    k_prep<<<2, 256, 0, stream>>>(Wf2, WfF2, 2);
    k_prep<<<8, 256, 0, stream>>>(We2, We2f, 8);

    // CSR build (sorted by dst)
    k_zero<<<nB, 256, 0, stream>>>((float*)cursor, N_NODES);
    k_hist<<<eB, 256, 0, stream>>>(dst, cursor);
    k_scan1<<<scanB, 256, 0, stream>>>(cursor, rowptr, bsums);
    k_scan2<<<1, 1, 0, stream>>>(bsums, scanB, rowptr);
    k_scan3<<<nB, 256, 0, stream>>>(rowptr, bsums);
    k_zero<<<nB, 256, 0, stream>>>((float*)cursor, N_NODES);
    k_scatter<<<eB, 256, 0, stream>>>(src, dst, rowptr, cursor, csrsrc);
    k_dis_tcnt<<<nB, 256, 0, stream>>>(rowptr, dis, cursor);
    k_zero<<<1, 256, 0, stream>>>(pooled, 2 * G_GRAPHS);
    k_counts<<<nB, 256, 0, stream>>>(batch, counts);

    // tile list: tstart = exclusive-scan(ceil(deg/16)); tileN + padded tileSrc
    k_scan1<<<scanB, 256, 0, stream>>>(cursor, tstart, bsums2);
    k_scan2t<<<1, 1, 0, stream>>>(bsums2, scanB, tstart, ntiles);
    k_scan3<<<nB, 256, 0, stream>>>(tstart, bsums2);
    k_tfill<<<nB, 256, 0, stream>>>(rowptr, csrsrc, tstart, tileN, tileSrc);

    // GCN1
    k_gemm_f32bf_scale<<<(N_NODES + 7) / 8, 256, 0, stream>>>(xf, W1, dis, Ub, N_NODES);
    k_gcn_fused<<<gcnB, 256, 0, stream>>>(rowptr, csrsrc, Ub, dis, b1, hb);

    for (int iter = 0; iter < 3; ++iter) {
        k_gemm_dual<<<mfmaB, 512, 0, stream>>>(hb, WfU, WfV, be1, Ub, Vb, N_NODES);
        k_zero<<<zAggB, 256, 0, stream>>>((float*)aggEnc, (int)NH);
        k_edge_tile<<<tileB, 512, 0, stream>>>(tileN, tileSrc, ntiles, Ub, Vb, We2f, aggEnc);
        k_edge_combine<<<combB, 256, 0, stream>>>(aggEnc, be2, hb);
        if (iter < 2) {
            k_gemm_scale<<<mfmaB, 512, 0, stream>>>(hb, WfW2, dis, Ub, N_NODES);
            k_gcn_fused<<<gcnB, 256, 0, stream>>>(rowptr, csrsrc, Ub, dis, b2, hb);
        }
    }

    k_final_mlp<<<mfmaB, 512, 0, stream>>>(hb, WfF1, WfF2, bf1, bf2, Wf3, bf3,
                                           batch, pooled, N_NODES);
    k_final<<<1, 64, 0, stream>>>(pooled, counts, d_out, flag);
}

// Round 11
// 528.952 us; speedup vs baseline: 3.3608x; 1.0571x over previous
//
#include <hip/hip_runtime.h>
#include <hip/hip_bf16.h>

#define N_NODES 50000
#define N_EDGES 800000
#define F_IN 9
#define H 128
#define G_GRAPHS 64
#define HH (H * H)
#define MAXT (N_EDGES / 16 + N_NODES)   // 100000 upper bound on tile count

typedef short bf16x8 __attribute__((ext_vector_type(8)));
typedef float f32x4 __attribute__((ext_vector_type(4)));

static __device__ inline short f2b(float f) {
    __hip_bfloat16 h = __float2bfloat16(f);
    return *reinterpret_cast<short*>(&h);
}
static __device__ inline float blo(unsigned u) { return __uint_as_float(u << 16); }
static __device__ inline float bhi(unsigned u) { return __uint_as_float(u & 0xFFFF0000u); }
static __device__ inline unsigned encodef(float f) {
    unsigned u = __float_as_uint(f);
    return (u & 0x80000000u) ? ~u : (u | 0x80000000u);
}
static __device__ inline float decodef(unsigned u) {
    return __uint_as_float((u & 0x80000000u) ? (u ^ 0x80000000u) : ~u);
}
// packed RNE f32->bf16 pair: dst.lo = cvt(lo), dst.hi = cvt(hi)  [gfx950, no builtin]
static __device__ inline unsigned cvtpk(float lo, float hi) {
    unsigned r;
    asm("v_cvt_pk_bf16_f32 %0, %1, %2" : "=v"(r) : "v"(lo), "v"(hi));
    return r;
}

// ---------- dtype detection (+ zero pooled/counts) ----------
__global__ __launch_bounds__(256) void k_detect(const unsigned* __restrict__ x, int* flag,
                                                float* pooled, float* counts) {
    __shared__ int cnt;
    if (threadIdx.x == 0) cnt = 0;
    __syncthreads();
    unsigned u = x[threadIdx.x];
    int e = (u >> 7) & 0xFF;
    if (e >= 0x70 && e <= 0x83) atomicAdd(&cnt, 1);
    if (threadIdx.x < G_GRAPHS) { pooled[threadIdx.x] = 0.f; counts[threadIdx.x] = 0.f; }
    __syncthreads();
    if (threadIdx.x == 0) *flag = (cnt >= 128) ? 1 : 0;
}

// ---------- batched convert of all float inputs ----------
struct CvtArgs { const void* src[15]; float* dst[15]; };

__global__ __launch_bounds__(256) void k_cvt_all(CvtArgs a, const int* __restrict__ flag) {
    const int sz[15] = {450000, 1152, 128, 16384, 128, 32768, 128, 16384, 128,
                        16384, 128, 4096, 32, 32, 1};
    int i = blockIdx.x * 256 + threadIdx.x;
    int fl = *flag;
    int base = 0;
    #pragma unroll
    for (int s = 0; s < 15; ++s) {
        if (i >= base && i < base + sz[s]) {
            int off = i - base;
            float v = fl ? __bfloat162float(((const __hip_bfloat16*)a.src[s])[off])
                         : ((const float*)a.src[s])[off];
            a.dst[s][off] = v;
        }
        base += sz[s];
    }
}

__global__ __launch_bounds__(256) void k_zero(float* p, int n) {
    int i = blockIdx.x * 256 + threadIdx.x;
    if (i < n) p[i] = 0.f;
}

// ---------- all weight fragment tables in one kernel (42 blocks) ----------
__global__ __launch_bounds__(256) void k_prep_all(const float* __restrict__ We1,
                                                  const float* __restrict__ W2,
                                                  const float* __restrict__ Wf1,
                                                  const float* __restrict__ Wf2,
                                                  const float* __restrict__ We2,
                                                  short* WfU, short* WfV, short* WfW2,
                                                  short* WfF1, short* WfF2, short* We2f) {
    int b = blockIdx.x;
    const float* W; const float* Wm = nullptr; short* out; int NT = 8; int tid;
    if (b < 8)       { W = We1;      Wm = We1 + HH; out = WfU;  tid = b * 256 + threadIdx.x; }
    else if (b < 16) { W = We1 + HH; out = WfV;  tid = (b - 8) * 256 + threadIdx.x; }
    else if (b < 24) { W = W2;       out = WfW2; tid = (b - 16) * 256 + threadIdx.x; }
    else if (b < 32) { W = Wf1;      out = WfF1; tid = (b - 24) * 256 + threadIdx.x; }
    else if (b < 40) { W = We2;      out = We2f; tid = (b - 32) * 256 + threadIdx.x; }
    else             { W = Wf2;      out = WfF2; NT = 2; tid = (b - 40) * 256 + threadIdx.x; }
    int total = 4 * NT * 64;
    if (tid >= total) return;
    int kc = tid / (NT * 64);
    int ct = (tid / 64) % NT;
    int lane = tid & 63;
    int Nc = NT * 16;
    int kb = kc * 32 + (lane >> 4) * 8;
    int col = ct * 16 + (lane & 15);
    #pragma unroll
    for (int j = 0; j < 8; ++j) {
        float w = W[(kb + j) * Nc + col];
        if (Wm) w -= Wm[(kb + j) * Nc + col];
        out[tid * 8 + j] = f2b(w);
    }
}

// ---------- CSR build ----------
__global__ __launch_bounds__(256) void k_hist(const int* __restrict__ dst, int* cnt) {
    int e = blockIdx.x * 256 + threadIdx.x;
    if (e < N_EDGES) atomicAdd(&cnt[dst[e]], 1);
}

// dual exclusive scan: A = deg, B = ceil(deg/16)
__global__ __launch_bounds__(256) void k_scan1d(const int* __restrict__ deg,
                                                int* __restrict__ outA, int* __restrict__ outB,
                                                int* __restrict__ bsA, int* __restrict__ bsB) {
    __shared__ int ldsA[256], ldsB[256];
    int base = blockIdx.x * 2048;
    int t = threadIdx.x;
    int localA[8], localB[8];
    int sA = 0, sB = 0;
    #pragma unroll
    for (int j = 0; j < 8; ++j) {
        int idx = base + t * 8 + j;
        int v = (idx < N_NODES) ? deg[idx] : 0;
        int tc = (v + 15) >> 4;
        localA[j] = sA; sA += v;
        localB[j] = sB; sB += tc;
    }
    ldsA[t] = sA; ldsB[t] = sB;
    __syncthreads();
    if (t == 0) {
        int run = 0;
        for (int i = 0; i < 256; ++i) { int v = ldsA[i]; ldsA[i] = run; run += v; }
        bsA[blockIdx.x] = run;
        run = 0;
        for (int i = 0; i < 256; ++i) { int v = ldsB[i]; ldsB[i] = run; run += v; }
        bsB[blockIdx.x] = run;
    }
    __syncthreads();
    int oA = ldsA[t], oB = ldsB[t];
    #pragma unroll
    for (int j = 0; j < 8; ++j) {
        int idx = base + t * 8 + j;
        if (idx < N_NODES) { outA[idx] = oA + localA[j]; outB[idx] = oB + localB[j]; }
    }
}

__global__ void k_scan2d(int* bsA, int* bsB, int nb, int* rowptr, int* tstart, int* ntiles) {
    int run = 0;
    for (int i = 0; i < nb; ++i) { int v = bsA[i]; bsA[i] = run; run += v; }
    rowptr[N_NODES] = N_EDGES;
    run = 0;
    for (int i = 0; i < nb; ++i) { int v = bsB[i]; bsB[i] = run; run += v; }
    tstart[N_NODES] = run;
    *ntiles = run;
}

__global__ __launch_bounds__(256) void k_scan3d(int* rowptr, int* tstart,
                                                const int* __restrict__ bsA,
                                                const int* __restrict__ bsB) {
    int idx = blockIdx.x * 256 + threadIdx.x;
    if (idx < N_NODES) {
        rowptr[idx] += bsA[idx >> 11];
        tstart[idx] += bsB[idx >> 11];
    }
}

__global__ __launch_bounds__(256) void k_scatter(const int* __restrict__ src, const int* __restrict__ dst,
                                                 const int* __restrict__ rowptr, int* cursor,
                                                 int* __restrict__ csr_src) {
    int e = blockIdx.x * 256 + threadIdx.x;
    if (e >= N_EDGES) return;
    int d = dst[e];
    int pos = rowptr[d] + atomicAdd(&cursor[d], 1);
    csr_src[pos] = src[e];
}

// dis + per-graph counts in one pass
__global__ __launch_bounds__(256) void k_dis_counts(const int* __restrict__ rowptr, float* dis,
                                                    const int* __restrict__ batch, float* counts) {
    __shared__ float lc[G_GRAPHS];
    if (threadIdx.x < G_GRAPHS) lc[threadIdx.x] = 0.f;
    __syncthreads();
    int n = blockIdx.x * 256 + threadIdx.x;
    if (n < N_NODES) {
        int deg = rowptr[n + 1] - rowptr[n];
        dis[n] = rsqrtf((float)deg + 1.0f);
        atomicAdd(&lc[batch[n]], 1.0f);
    }
    __syncthreads();
    if (threadIdx.x < G_GRAPHS && lc[threadIdx.x] > 0.f)
        atomicAdd(&counts[threadIdx.x], lc[threadIdx.x]);
}

// ---------- tile list: tileN + padded per-tile src indices ----------
__global__ __launch_bounds__(256) void k_tfill(const int* __restrict__ rowptr,
                                               const int* __restrict__ csr_src,
                                               const int* __restrict__ tstart,
                                               int* __restrict__ tileN,
                                               int* __restrict__ tileSrc) {
    int n = blockIdx.x * 256 + threadIdx.x;
    if (n >= N_NODES) return;
    int t0 = tstart[n], t1 = tstart[n + 1];
    int beg = rowptr[n], end = rowptr[n + 1];
    for (int t = t0; t < t1; ++t) {
        tileN[t] = n;
        int tb = beg + (t - t0) * 16;
        #pragma unroll 4
        for (int j = 0; j < 16; ++j) {
            int ei = tb + j;
            tileSrc[t * 16 + j] = csr_src[ei < end ? ei : end - 1];
        }
    }
}

// ---------- GCN1 GEMM: out = (x[M,9] @ W1[9,128]) * dis[row], bf16 ----------
__global__ __launch_bounds__(256) void k_gemm_f32bf_scale(const float* __restrict__ A,
                                                          const float* __restrict__ W,
                                                          const float* __restrict__ dis,
                                                          short* __restrict__ out, int M) {
    __shared__ float w_lds[F_IN * H];
    for (int i = threadIdx.x; i < F_IN * H; i += 256) w_lds[i] = W[i];
    __syncthreads();
    int row = blockIdx.x * 8 + threadIdx.x / 32;
    int c4 = (threadIdx.x & 31) << 2;
    if (row >= M) return;
    const float* a = A + (size_t)row * F_IN;
    float acc0 = 0.f, acc1 = 0.f, acc2 = 0.f, acc3 = 0.f;
    #pragma unroll
    for (int k = 0; k < F_IN; ++k) {
        float av = a[k];
        float4 w = *reinterpret_cast<const float4*>(&w_lds[k * H + c4]);
        acc0 = fmaf(av, w.x, acc0);
        acc1 = fmaf(av, w.y, acc1);
        acc2 = fmaf(av, w.z, acc2);
        acc3 = fmaf(av, w.w, acc3);
    }
    float dv = dis[row];
    uint2 o = make_uint2(cvtpk(acc0 * dv, acc1 * dv), cvtpk(acc2 * dv, acc3 * dv));
    *reinterpret_cast<uint2*>(&out[(size_t)row * H + c4]) = o;
}

// ---------- dual MFMA GEMM (512 thr, 8 waves): U = A@WU + be1 ; V = A@WV ----------
__global__ __launch_bounds__(512) void k_gemm_dual(const short* __restrict__ A,
                                                   const short* __restrict__ WfU,
                                                   const short* __restrict__ WfV,
                                                   const float* __restrict__ be1,
                                                   short* __restrict__ U,
                                                   short* __restrict__ V, int M) {
    __shared__ short wl[32768];
    for (int i = threadIdx.x * 8; i < 16384; i += 4096) {
        *reinterpret_cast<f32x4*>(&wl[i])         = *reinterpret_cast<const f32x4*>(&WfU[i]);
        *reinterpret_cast<f32x4*>(&wl[16384 + i]) = *reinterpret_cast<const f32x4*>(&WfV[i]);
    }
    __syncthreads();
    int wv = threadIdx.x >> 6, lane = threadIdx.x & 63;
    int er = lane & 15, kg = lane >> 4;
    int row0 = (blockIdx.x * 8 + wv) * 16;
    if (row0 >= M) return;
    bf16x8 af[4];
    #pragma unroll
    for (int kc = 0; kc < 4; ++kc)
        af[kc] = *reinterpret_cast<const bf16x8*>(&A[(size_t)(row0 + er) * H + kc * 32 + kg * 8]);
    const f32x4 vzero = {0.f, 0.f, 0.f, 0.f};
    f32x4 acc[8];
    #pragma unroll
    for (int ct = 0; ct < 8; ++ct) acc[ct] = vzero;
    #pragma unroll
    for (int kc = 0; kc < 4; ++kc)
        #pragma unroll
        for (int ct = 0; ct < 8; ++ct) {
            bf16x8 bf = *reinterpret_cast<const bf16x8*>(&wl[((kc * 8 + ct) * 64 + lane) * 8]);
            acc[ct] = __builtin_amdgcn_mfma_f32_16x16x32_bf16(af[kc], bf, acc[ct], 0, 0, 0);
        }
    #pragma unroll
    for (int ct = 0; ct < 8; ++ct) {
        int col = ct * 16 + er;
        float bv = be1[col];
        #pragma unroll
        for (int r = 0; r < 4; ++r)
            U[(size_t)(row0 + kg * 4 + r) * H + col] = f2b(acc[ct][r] + bv);
    }
    #pragma unroll
    for (int ct = 0; ct < 8; ++ct) acc[ct] = vzero;
    #pragma unroll
    for (int kc = 0; kc < 4; ++kc)
        #pragma unroll
        for (int ct = 0; ct < 8; ++ct) {
            bf16x8 bf = *reinterpret_cast<const bf16x8*>(&wl[16384 + ((kc * 8 + ct) * 64 + lane) * 8]);
            acc[ct] = __builtin_amdgcn_mfma_f32_16x16x32_bf16(af[kc], bf, acc[ct], 0, 0, 0);
        }
    #pragma unroll
    for (int ct = 0; ct < 8; ++ct) {
        int col = ct * 16 + er;
        #pragma unroll
        for (int r = 0; r < 4; ++r)
            V[(size_t)(row0 + kg * 4 + r) * H + col] = f2b(acc[ct][r]);
    }
}

// ---------- MFMA GEMM reading EdgeConv aggregate: A = tanh(decode(agg)+be2) (0 if empty);
//            out = (A@W2) * dis[row]  (512 thr) ----------
__global__ __launch_bounds__(512) void k_gemm_scale_agg(const unsigned* __restrict__ aggEnc,
                                                        const float* __restrict__ be2,
                                                        const short* __restrict__ Wf,
                                                        const float* __restrict__ dis,
                                                        short* __restrict__ out, int M) {
    __shared__ short wl[16384];
    for (int i = threadIdx.x * 8; i < 16384; i += 4096)
        *reinterpret_cast<f32x4*>(&wl[i]) = *reinterpret_cast<const f32x4*>(&Wf[i]);
    __syncthreads();
    int wv = threadIdx.x >> 6, lane = threadIdx.x & 63;
    int er = lane & 15, kg = lane >> 4;
    int row0 = (blockIdx.x * 8 + wv) * 16;
    if (row0 >= M) return;
    bf16x8 af[4];
    #pragma unroll
    for (int kc = 0; kc < 4; ++kc) {
        int basec = kc * 32 + kg * 8;
        const unsigned* ap = &aggEnc[(size_t)(row0 + er) * H + basec];
        uint4 q0 = *reinterpret_cast<const uint4*>(ap);
        uint4 q1 = *reinterpret_cast<const uint4*>(ap + 4);
        float f0 = q0.x ? tanhf(decodef(q0.x) + be2[basec + 0]) : 0.f;
        float f1 = q0.y ? tanhf(decodef(q0.y) + be2[basec + 1]) : 0.f;
        float f2 = q0.z ? tanhf(decodef(q0.z) + be2[basec + 2]) : 0.f;
        float f3 = q0.w ? tanhf(decodef(q0.w) + be2[basec + 3]) : 0.f;
        float f4 = q1.x ? tanhf(decodef(q1.x) + be2[basec + 4]) : 0.f;
        float f5 = q1.y ? tanhf(decodef(q1.y) + be2[basec + 5]) : 0.f;
        float f6 = q1.z ? tanhf(decodef(q1.z) + be2[basec + 6]) : 0.f;
        float f7 = q1.w ? tanhf(decodef(q1.w) + be2[basec + 7]) : 0.f;
        union { unsigned u[4]; bf16x8 v; } A;
        A.u[0] = cvtpk(f0, f1); A.u[1] = cvtpk(f2, f3);
        A.u[2] = cvtpk(f4, f5); A.u[3] = cvtpk(f6, f7);
        af[kc] = A.v;
    }
    const f32x4 vzero = {0.f, 0.f, 0.f, 0.f};
    f32x4 acc[8];
    #pragma unroll
    for (int ct = 0; ct < 8; ++ct) acc[ct] = vzero;
    #pragma unroll
    for (int kc = 0; kc < 4; ++kc)
        #pragma unroll
        for (int ct = 0; ct < 8; ++ct) {
            bf16x8 bf = *reinterpret_cast<const bf16x8*>(&wl[((kc * 8 + ct) * 64 + lane) * 8]);
            acc[ct] = __builtin_amdgcn_mfma_f32_16x16x32_bf16(af[kc], bf, acc[ct], 0, 0, 0);
        }
    float dv[4];
    #pragma unroll
    for (int r = 0; r < 4; ++r) dv[r] = dis[row0 + kg * 4 + r];
    #pragma unroll
    for (int ct = 0; ct < 8; ++ct) {
        int col = ct * 16 + er;
        #pragma unroll
        for (int r = 0; r < 4; ++r)
            out[(size_t)(row0 + kg * 4 + r) * H + col] = f2b(acc[ct][r] * dv[r]);
    }
}

// ---------- GCN fused agg+combine (CSR, pre-scaled rows, 8-way unrolled) ----------
__global__ __launch_bounds__(256) void k_gcn_fused(const int* __restrict__ rowptr,
                                                   const int* __restrict__ csr_src,
                                                   const short* __restrict__ hWs,
                                                   const float* __restrict__ dis,
                                                   const float* __restrict__ bias,
                                                   short* __restrict__ out) {
    int wv = threadIdx.x >> 6, lane = threadIdx.x & 63;
    const unsigned* hw = (const unsigned*)hWs;
    for (int n = blockIdx.x * 4 + wv; n < N_NODES; n += gridDim.x * 4) {
        int beg = rowptr[n], end = rowptr[n + 1];
        float a0 = 0.f, a1 = 0.f, b0 = 0.f, b1 = 0.f;
        float c0 = 0.f, c1 = 0.f, d0 = 0.f, d1 = 0.f;
        int e = beg;
        for (; e + 8 <= end; e += 8) {
            int s0 = csr_src[e],     s1 = csr_src[e + 1], s2 = csr_src[e + 2], s3 = csr_src[e + 3];
            int s4 = csr_src[e + 4], s5 = csr_src[e + 5], s6 = csr_src[e + 6], s7 = csr_src[e + 7];
            unsigned w0 = hw[(size_t)s0 * 64 + lane];
            unsigned w1 = hw[(size_t)s1 * 64 + lane];
            unsigned w2 = hw[(size_t)s2 * 64 + lane];
            unsigned w3 = hw[(size_t)s3 * 64 + lane];
            unsigned w4 = hw[(size_t)s4 * 64 + lane];
            unsigned w5 = hw[(size_t)s5 * 64 + lane];
            unsigned w6 = hw[(size_t)s6 * 64 + lane];
            unsigned w7 = hw[(size_t)s7 * 64 + lane];
            a0 += blo(w0); a1 += bhi(w0);
            b0 += blo(w1); b1 += bhi(w1);
            c0 += blo(w2); c1 += bhi(w2);
            d0 += blo(w3); d1 += bhi(w3);
            a0 += blo(w4); a1 += bhi(w4);
            b0 += blo(w5); b1 += bhi(w5);
            c0 += blo(w6); c1 += bhi(w6);
            d0 += blo(w7); d1 += bhi(w7);
        }
        for (; e + 4 <= end; e += 4) {
            int s0 = csr_src[e], s1 = csr_src[e + 1], s2 = csr_src[e + 2], s3 = csr_src[e + 3];
            unsigned w0 = hw[(size_t)s0 * 64 + lane];
            unsigned w1 = hw[(size_t)s1 * 64 + lane];
            unsigned w2 = hw[(size_t)s2 * 64 + lane];
            unsigned w3 = hw[(size_t)s3 * 64 + lane];
            a0 += blo(w0); a1 += bhi(w0);
            b0 += blo(w1); b1 += bhi(w1);
            c0 += blo(w2); c1 += bhi(w2);
            d0 += blo(w3); d1 += bhi(w3);
        }
        for (; e < end; ++e) {
            unsigned w = hw[(size_t)csr_src[e] * 64 + lane];
            a0 += blo(w); a1 += bhi(w);
        }
        float s0f = (a0 + b0) + (c0 + d0);
        float s1f = (a1 + b1) + (c1 + d1);
        float dn = dis[n];
        unsigned wn = hw[(size_t)n * 64 + lane];
        float r0 = tanhf(dn * (s0f + blo(wn)) + bias[lane * 2]);
        float r1 = tanhf(dn * (s1f + bhi(wn)) + bias[lane * 2 + 1]);
        *reinterpret_cast<unsigned*>(&out[(size_t)n * H + lane * 2]) = cvtpk(r0, r1);
    }
}

// ---------- EdgeConv: one wave per 16-edge tile (512 thr); cvt_pk A-build ----------
__global__ __launch_bounds__(512) void k_edge_tile(const int* __restrict__ tileN,
                                                   const int* __restrict__ tileSrc,
                                                   const int* __restrict__ ntilesp,
                                                   const short* __restrict__ U,
                                                   const short* __restrict__ V,
                                                   const short* __restrict__ We2f,
                                                   unsigned* aggEnc) {
    int nt = *ntilesp;
    if ((int)(blockIdx.x * 8) >= nt) return;
    __shared__ short wl[16384];
    for (int i = threadIdx.x * 8; i < 16384; i += 4096)
        *reinterpret_cast<f32x4*>(&wl[i]) = *reinterpret_cast<const f32x4*>(&We2f[i]);
    __syncthreads();
    int wv = threadIdx.x >> 6, lane = threadIdx.x & 63;
    int er = lane & 15, kg = lane >> 4, kseg = kg * 8;
    int tid = blockIdx.x * 8 + wv;
    if (tid >= nt) return;
    int n = tileN[tid];
    int s = tileSrc[tid * 16 + er];
    const f32x4 vzero = {0.f, 0.f, 0.f, 0.f};
    f32x4 acc[8];
    #pragma unroll
    for (int ct = 0; ct < 8; ++ct) acc[ct] = vzero;
    #pragma unroll
    for (int kc = 0; kc < 4; ++kc) {
        uint4 uu4 = *reinterpret_cast<const uint4*>(&U[(size_t)n * H + kc * 32 + kseg]);
        uint4 vv4 = *reinterpret_cast<const uint4*>(&V[(size_t)s * H + kc * 32 + kseg]);
        union { unsigned u[4]; bf16x8 v; } A;
        A.u[0] = cvtpk(fmaxf(blo(uu4.x) + blo(vv4.x), 0.f), fmaxf(bhi(uu4.x) + bhi(vv4.x), 0.f));
        A.u[1] = cvtpk(fmaxf(blo(uu4.y) + blo(vv4.y), 0.f), fmaxf(bhi(uu4.y) + bhi(vv4.y), 0.f));
        A.u[2] = cvtpk(fmaxf(blo(uu4.z) + blo(vv4.z), 0.f), fmaxf(bhi(uu4.z) + bhi(vv4.z), 0.f));
        A.u[3] = cvtpk(fmaxf(blo(uu4.w) + blo(vv4.w), 0.f), fmaxf(bhi(uu4.w) + bhi(vv4.w), 0.f));
        #pragma unroll
        for (int ct = 0; ct < 8; ++ct) {
            bf16x8 bf = *reinterpret_cast<const bf16x8*>(&wl[((kc * 8 + ct) * 64 + lane) * 8]);
            acc[ct] = __builtin_amdgcn_mfma_f32_16x16x32_bf16(A.v, bf, acc[ct], 0, 0, 0);
        }
    }
    float cm[8];
    #pragma unroll
    for (int ct = 0; ct < 8; ++ct) {
        float v = fmaxf(fmaxf(acc[ct][0], acc[ct][1]), fmaxf(acc[ct][2], acc[ct][3]));
        v = fmaxf(v, __shfl_xor(v, 16));
        v = fmaxf(v, __shfl_xor(v, 32));
        cm[ct] = v;
    }
    float vA, vB;
    if (kg == 0)      { vA = cm[0]; vB = cm[1]; }
    else if (kg == 1) { vA = cm[2]; vB = cm[3]; }
    else if (kg == 2) { vA = cm[4]; vB = cm[5]; }
    else              { vA = cm[6]; vB = cm[7]; }
    int colA = (kg * 2) * 16 + er;
    int colB = (kg * 2 + 1) * 16 + er;
    atomicMax(&aggEnc[(size_t)n * H + colA], encodef(vA));
    atomicMax(&aggEnc[(size_t)n * H + colB], encodef(vB));
}

// ---------- fused final MLP + pooling, reading EdgeConv aggregate directly ----------
__global__ __launch_bounds__(512) void k_final_mlp_agg(const unsigned* __restrict__ aggEnc,
                                                       const float* __restrict__ be2,
                                                       const short* __restrict__ WfF1,
                                                       const short* __restrict__ WfF2,
                                                       const float* __restrict__ bf1,
                                                       const float* __restrict__ bf2,
                                                       const float* __restrict__ Wf3,
                                                       const float* __restrict__ bf3,
                                                       const int* __restrict__ batch,
                                                       float* pooled, int M) {
    __shared__ short wl1[16384];
    __shared__ short wl2[4096];
    __shared__ short tb[8][2048];
    __shared__ float lp[G_GRAPHS];
    for (int i = threadIdx.x * 8; i < 16384; i += 4096)
        *reinterpret_cast<f32x4*>(&wl1[i]) = *reinterpret_cast<const f32x4*>(&WfF1[i]);
    {
        int i = threadIdx.x * 8;
        if (i < 4096)
            *reinterpret_cast<f32x4*>(&wl2[i]) = *reinterpret_cast<const f32x4*>(&WfF2[i]);
    }
    if (threadIdx.x < G_GRAPHS) lp[threadIdx.x] = 0.f;
    __syncthreads();
    int wv = threadIdx.x >> 6, lane = threadIdx.x & 63;
    int er = lane & 15, kg = lane >> 4;
    int row0 = (blockIdx.x * 8 + wv) * 16;
    bool active = row0 < M;
    const f32x4 vzero = {0.f, 0.f, 0.f, 0.f};
    if (active) {
        bf16x8 af[4];
        #pragma unroll
        for (int kc = 0; kc < 4; ++kc) {
            int basec = kc * 32 + kg * 8;
            const unsigned* ap = &aggEnc[(size_t)(row0 + er) * H + basec];
            uint4 q0 = *reinterpret_cast<const uint4*>(ap);
            uint4 q1 = *reinterpret_cast<const uint4*>(ap + 4);
            float f0 = q0.x ? tanhf(decodef(q0.x) + be2[basec + 0]) : 0.f;
            float f1 = q0.y ? tanhf(decodef(q0.y) + be2[basec + 1]) : 0.f;
            float f2 = q0.z ? tanhf(decodef(q0.z) + be2[basec + 2]) : 0.f;
            float f3 = q0.w ? tanhf(decodef(q0.w) + be2[basec + 3]) : 0.f;
            float f4 = q1.x ? tanhf(decodef(q1.x) + be2[basec + 4]) : 0.f;
            float f5 = q1.y ? tanhf(decodef(q1.y) + be2[basec + 5]) : 0.f;
            float f6 = q1.z ? tanhf(decodef(q1.z) + be2[basec + 6]) : 0.f;
            float f7 = q1.w ? tanhf(decodef(q1.w) + be2[basec + 7]) : 0.f;
            union { unsigned u[4]; bf16x8 v; } A;
            A.u[0] = cvtpk(f0, f1); A.u[1] = cvtpk(f2, f3);
            A.u[2] = cvtpk(f4, f5); A.u[3] = cvtpk(f6, f7);
            af[kc] = A.v;
        }
        f32x4 acc[8];
        #pragma unroll
        for (int ct = 0; ct < 8; ++ct) acc[ct] = vzero;
        #pragma unroll
        for (int kc = 0; kc < 4; ++kc)
            #pragma unroll
            for (int ct = 0; ct < 8; ++ct) {
                bf16x8 bf = *reinterpret_cast<const bf16x8*>(&wl1[((kc * 8 + ct) * 64 + lane) * 8]);
                acc[ct] = __builtin_amdgcn_mfma_f32_16x16x32_bf16(af[kc], bf, acc[ct], 0, 0, 0);
            }
        #pragma unroll
        for (int ct = 0; ct < 8; ++ct) {
            int col = ct * 16 + er;
            float bv = bf1[col];
            #pragma unroll
            for (int r = 0; r < 4; ++r)
                tb[wv][(kg * 4 + r) * 128 + col] = f2b(tanhf(acc[ct][r] + bv));
        }
    }
    __syncthreads();
    if (active) {
        bf16x8 af2[4];
        #pragma unroll
        for (int kc = 0; kc < 4; ++kc)
            af2[kc] = *reinterpret_cast<const bf16x8*>(&tb[wv][er * 128 + kc * 32 + kg * 8]);
        f32x4 a2[2];
        a2[0] = vzero; a2[1] = vzero;
        #pragma unroll
        for (int kc = 0; kc < 4; ++kc)
            #pragma unroll
            for (int ct = 0; ct < 2; ++ct) {
                bf16x8 bf = *reinterpret_cast<const bf16x8*>(&wl2[((kc * 2 + ct) * 64 + lane) * 8]);
                a2[ct] = __builtin_amdgcn_mfma_f32_16x16x32_bf16(af2[kc], bf, a2[ct], 0, 0, 0);
            }
        float w3a = Wf3[er], w3b = Wf3[16 + er];
        float b2a = bf2[er], b2b = bf2[16 + er];
        float bf3v = bf3[0];
        float psum[4];
        #pragma unroll
        for (int r = 0; r < 4; ++r) {
            float f2a = tanhf(a2[0][r] + b2a);
            float f2c = tanhf(a2[1][r] + b2b);
            float p = f2a * w3a + f2c * w3b;
            p += __shfl_xor(p, 1);
            p += __shfl_xor(p, 2);
            p += __shfl_xor(p, 4);
            p += __shfl_xor(p, 8);
            psum[r] = p + bf3v;
        }
        if (er == 0) {
            #pragma unroll
            for (int r = 0; r < 4; ++r) {
                int n = row0 + kg * 4 + r;
                if (n < M) atomicAdd(&lp[batch[n]], psum[r]);
            }
        }
    }
    __syncthreads();
    if (threadIdx.x < G_GRAPHS && lp[threadIdx.x] != 0.f)
        atomicAdd(&pooled[threadIdx.x], lp[threadIdx.x]);
}

__global__ __launch_bounds__(64) void k_final(const float* pooled, const float* counts,
                                              void* out, const int* __restrict__ flag) {
    int g = threadIdx.x;
    if (g < G_GRAPHS) {
        float v = pooled[g] / fmaxf(counts[g], 1.0f);
        float s = 1.0f / (1.0f + expf(-v));
        if (*flag) ((__hip_bfloat16*)out)[g] = __float2bfloat16(s);
        else       ((float*)out)[g] = s;
    }
}

extern "C" void kernel_launch(void* const* d_in, const int* in_sizes, int n_in,
                              void* d_out, int out_size, void* d_ws, size_t ws_size,
                              hipStream_t stream) {
    const int* ei    = (const int*)d_in[1];
    const int* src   = ei;
    const int* dst   = ei + N_EDGES;
    const int* batch = (const int*)d_in[2];

    float* ws = (float*)d_ws;
    size_t off = 0;
    auto alloc = [&](size_t n) { off = (off + 3) & ~(size_t)3; float* p = ws + off; off += n; return p; };

    const size_t NH = (size_t)N_NODES * H;
    short* hb     = (short*)alloc(NH / 2);
    short* Ub     = (short*)alloc(NH / 2);
    short* Vb     = (short*)alloc(NH / 2);
    unsigned* aggEnc = (unsigned*)alloc(NH);
    float* xf     = alloc((size_t)N_NODES * F_IN);
    float* dis    = alloc(N_NODES);
    float* pooled = alloc(G_GRAPHS);
    float* counts = alloc(G_GRAPHS);
    int*   flag   = (int*)alloc(1);
    int*   rowptr = (int*)alloc(N_NODES + 1);
    int*   cursor = (int*)alloc(N_NODES);
    int*   csrsrc = (int*)alloc(N_EDGES);
    int*   bsums  = (int*)alloc(32);
    int*   bsums2 = (int*)alloc(32);
    int*   tstart = (int*)alloc(N_NODES + 1);
    int*   ntiles = (int*)alloc(1);
    int*   tileN  = (int*)alloc(MAXT);
    int*   tileSrc= (int*)alloc((size_t)MAXT * 16);

    float* W1  = alloc(F_IN * H);
    float* b1  = alloc(H);
    float* W2  = alloc(HH);
    float* b2  = alloc(H);
    float* We1 = alloc(2 * HH);
    float* be1 = alloc(H);
    float* We2 = alloc(HH);
    float* be2 = alloc(H);
    float* Wf1 = alloc(HH);
    float* bf1 = alloc(H);
    float* Wf2 = alloc(H * 32);
    float* bf2 = alloc(32);
    float* Wf3 = alloc(32);
    float* bf3 = alloc(4);
    short* WfU  = (short*)alloc(8192);
    short* WfV  = (short*)alloc(8192);
    short* WfW2 = (short*)alloc(8192);
    short* WfF1 = (short*)alloc(8192);
    short* WfF2 = (short*)alloc(2048);
    short* We2f = (short*)alloc(8192);

    const int eB    = (N_EDGES + 255) / 256;
    const int nB    = (N_NODES + 255) / 256;
    const int scanB = (N_NODES + 2047) / 2048;
    const int mfmaB = (N_NODES / 16 + 7) / 8;      // 391 blocks of 512
    const int gcnB  = (N_NODES + 3) / 4;           // 12500
    const int tileB = (MAXT + 7) / 8;              // 12500 blocks of 512
    const int zAggB = (int)((NH + 255) / 256);

    k_detect<<<1, 256, 0, stream>>>((const unsigned*)d_in[0], flag, pooled, counts);

    CvtArgs ca;
    const int srcIdx[15] = {0, 3, 4, 5, 6, 7, 8, 9, 10, 11, 12, 13, 14, 15, 16};
    float* dsts[15] = {xf, W1, b1, W2, b2, We1, be1, We2, be2, Wf1, bf1, Wf2, bf2, Wf3, bf3};
    for (int s = 0; s < 15; ++s) { ca.src[s] = d_in[srcIdx[s]]; ca.dst[s] = dsts[s]; }
    const int cvtTotal = 450000 + 1152 + 128 + 16384 + 128 + 32768 + 128 + 16384 + 128
                       + 16384 + 128 + 4096 + 32 + 32 + 1;       // 537873
    k_cvt_all<<<(cvtTotal + 255) / 256, 256, 0, stream>>>(ca, flag);

    k_prep_all<<<42, 256, 0, stream>>>(We1, W2, Wf1, Wf2, We2,
                                       WfU, WfV, WfW2, WfF1, WfF2, We2f);

    // CSR + tile-list build
    k_zero<<<nB, 256, 0, stream>>>((float*)cursor, N_NODES);
    k_hist<<<eB, 256, 0, stream>>>(dst, cursor);
    k_scan1d<<<scanB, 256, 0, stream>>>(cursor, rowptr, tstart, bsums, bsums2);
    k_scan2d<<<1, 1, 0, stream>>>(bsums, bsums2, scanB, rowptr, tstart, ntiles);
    k_scan3d<<<nB, 256, 0, stream>>>(rowptr, tstart, bsums, bsums2);
    k_zero<<<nB, 256, 0, stream>>>((float*)cursor, N_NODES);
    k_scatter<<<eB, 256, 0, stream>>>(src, dst, rowptr, cursor, csrsrc);
    k_dis_counts<<<nB, 256, 0, stream>>>(rowptr, dis, batch, counts);
    k_tfill<<<nB, 256, 0, stream>>>(rowptr, csrsrc, tstart, tileN, tileSrc);

    // GCN1
    k_gemm_f32bf_scale<<<(N_NODES + 7) / 8, 256, 0, stream>>>(xf, W1, dis, Ub, N_NODES);
    k_gcn_fused<<<gcnB, 256, 0, stream>>>(rowptr, csrsrc, Ub, dis, b1, hb);

    for (int iter = 0; iter < 3; ++iter) {
        k_gemm_dual<<<mfmaB, 512, 0, stream>>>(hb, WfU, WfV, be1, Ub, Vb, N_NODES);
        k_zero<<<zAggB, 256, 0, stream>>>((float*)aggEnc, (int)NH);
        k_edge_tile<<<tileB, 512, 0, stream>>>(tileN, tileSrc, ntiles, Ub, Vb, We2f, aggEnc);
        if (iter < 2) {
            k_gemm_scale_agg<<<mfmaB, 512, 0, stream>>>(aggEnc, be2, WfW2, dis, Ub, N_NODES);
            k_gcn_fused<<<gcnB, 256, 0, stream>>>(rowptr, csrsrc, Ub, dis, b2, hb);
        }
    }

    k_final_mlp_agg<<<mfmaB, 512, 0, stream>>>(aggEnc, be2, WfF1, WfF2, bf1, bf2, Wf3, bf3,
                                               batch, pooled, N_NODES);
    k_final<<<1, 64, 0, stream>>>(pooled, counts, d_out, flag);
}

// Round 12
// 501.302 us; speedup vs baseline: 3.5462x; 1.0552x over previous
//
#include <hip/hip_runtime.h>
#include <hip/hip_bf16.h>

#define N_NODES 50000
#define N_EDGES 800000
#define F_IN 9
#define H 128
#define G_GRAPHS 64
#define HH (H * H)
#define MAXT (N_EDGES / 16 + N_NODES)   // 100000 upper bound on tile count

typedef short bf16x8 __attribute__((ext_vector_type(8)));
typedef float f32x4 __attribute__((ext_vector_type(4)));
typedef float f32x2 __attribute__((ext_vector_type(2)));

static __device__ inline short f2b(float f) {
    __hip_bfloat16 h = __float2bfloat16(f);
    return *reinterpret_cast<short*>(&h);
}
static __device__ inline float blo(unsigned u) { return __uint_as_float(u << 16); }
static __device__ inline float bhi(unsigned u) { return __uint_as_float(u & 0xFFFF0000u); }
// packed unpack: lo exact, hi approximated by raw bits (low-16 garbage ~2^-9 relative,
// far below the bf16 rounding applied downstream)
static __device__ inline f32x2 up2(unsigned u) {
    f32x2 r; r.x = __uint_as_float(u << 16); r.y = __uint_as_float(u); return r;
}
static __device__ inline unsigned encodef(float f) {
    unsigned u = __float_as_uint(f);
    return (u & 0x80000000u) ? ~u : (u | 0x80000000u);
}
static __device__ inline float decodef(unsigned u) {
    return __uint_as_float((u & 0x80000000u) ? (u ^ 0x80000000u) : ~u);
}
// packed RNE f32->bf16 pair [gfx950, no builtin]
static __device__ inline unsigned cvtpk(float lo, float hi) {
    unsigned r;
    asm("v_cvt_pk_bf16_f32 %0, %1, %2" : "=v"(r) : "v"(lo), "v"(hi));
    return r;
}

// ---------- dtype detection (+ zero pooled/counts) ----------
__global__ __launch_bounds__(256) void k_detect(const unsigned* __restrict__ x, int* flag,
                                                float* pooled, float* counts) {
    __shared__ int cnt;
    if (threadIdx.x == 0) cnt = 0;
    __syncthreads();
    unsigned u = x[threadIdx.x];
    int e = (u >> 7) & 0xFF;
    if (e >= 0x70 && e <= 0x83) atomicAdd(&cnt, 1);
    if (threadIdx.x < G_GRAPHS) { pooled[threadIdx.x] = 0.f; counts[threadIdx.x] = 0.f; }
    __syncthreads();
    if (threadIdx.x == 0) *flag = (cnt >= 128) ? 1 : 0;
}

// ---------- batched convert of all float inputs ----------
struct CvtArgs { const void* src[15]; float* dst[15]; };

__global__ __launch_bounds__(256) void k_cvt_all(CvtArgs a, const int* __restrict__ flag) {
    const int sz[15] = {450000, 1152, 128, 16384, 128, 32768, 128, 16384, 128,
                        16384, 128, 4096, 32, 32, 1};
    int i = blockIdx.x * 256 + threadIdx.x;
    int fl = *flag;
    int base = 0;
    #pragma unroll
    for (int s = 0; s < 15; ++s) {
        if (i >= base && i < base + sz[s]) {
            int off = i - base;
            float v = fl ? __bfloat162float(((const __hip_bfloat16*)a.src[s])[off])
                         : ((const float*)a.src[s])[off];
            a.dst[s][off] = v;
        }
        base += sz[s];
    }
}

__global__ __launch_bounds__(256) void k_zero(float* p, int n) {
    int i = blockIdx.x * 256 + threadIdx.x;
    if (i < n) p[i] = 0.f;
}

// ---------- all weight fragment tables in one kernel (42 blocks) ----------
__global__ __launch_bounds__(256) void k_prep_all(const float* __restrict__ We1,
                                                  const float* __restrict__ W2,
                                                  const float* __restrict__ Wf1,
                                                  const float* __restrict__ Wf2,
                                                  const float* __restrict__ We2,
                                                  short* WfU, short* WfV, short* WfW2,
                                                  short* WfF1, short* WfF2, short* We2f) {
    int b = blockIdx.x;
    const float* W; const float* Wm = nullptr; short* out; int NT = 8; int tid;
    if (b < 8)       { W = We1;      Wm = We1 + HH; out = WfU;  tid = b * 256 + threadIdx.x; }
    else if (b < 16) { W = We1 + HH; out = WfV;  tid = (b - 8) * 256 + threadIdx.x; }
    else if (b < 24) { W = W2;       out = WfW2; tid = (b - 16) * 256 + threadIdx.x; }
    else if (b < 32) { W = Wf1;      out = WfF1; tid = (b - 24) * 256 + threadIdx.x; }
    else if (b < 40) { W = We2;      out = We2f; tid = (b - 32) * 256 + threadIdx.x; }
    else             { W = Wf2;      out = WfF2; NT = 2; tid = (b - 40) * 256 + threadIdx.x; }
    int total = 4 * NT * 64;
    if (tid >= total) return;
    int kc = tid / (NT * 64);
    int ct = (tid / 64) % NT;
    int lane = tid & 63;
    int Nc = NT * 16;
    int kb = kc * 32 + (lane >> 4) * 8;
    int col = ct * 16 + (lane & 15);
    #pragma unroll
    for (int j = 0; j < 8; ++j) {
        float w = W[(kb + j) * Nc + col];
        if (Wm) w -= Wm[(kb + j) * Nc + col];
        out[tid * 8 + j] = f2b(w);
    }
}

// ---------- CSR build ----------
__global__ __launch_bounds__(256) void k_hist(const int* __restrict__ dst, int* cnt) {
    int e = blockIdx.x * 256 + threadIdx.x;
    if (e < N_EDGES) atomicAdd(&cnt[dst[e]], 1);
}

// dual exclusive scan: A = deg, B = ceil(deg/16)
__global__ __launch_bounds__(256) void k_scan1d(const int* __restrict__ deg,
                                                int* __restrict__ outA, int* __restrict__ outB,
                                                int* __restrict__ bsA, int* __restrict__ bsB) {
    __shared__ int ldsA[256], ldsB[256];
    int base = blockIdx.x * 2048;
    int t = threadIdx.x;
    int localA[8], localB[8];
    int sA = 0, sB = 0;
    #pragma unroll
    for (int j = 0; j < 8; ++j) {
        int idx = base + t * 8 + j;
        int v = (idx < N_NODES) ? deg[idx] : 0;
        int tc = (v + 15) >> 4;
        localA[j] = sA; sA += v;
        localB[j] = sB; sB += tc;
    }
    ldsA[t] = sA; ldsB[t] = sB;
    __syncthreads();
    if (t == 0) {
        int run = 0;
        for (int i = 0; i < 256; ++i) { int v = ldsA[i]; ldsA[i] = run; run += v; }
        bsA[blockIdx.x] = run;
        run = 0;
        for (int i = 0; i < 256; ++i) { int v = ldsB[i]; ldsB[i] = run; run += v; }
        bsB[blockIdx.x] = run;
    }
    __syncthreads();
    int oA = ldsA[t], oB = ldsB[t];
    #pragma unroll
    for (int j = 0; j < 8; ++j) {
        int idx = base + t * 8 + j;
        if (idx < N_NODES) { outA[idx] = oA + localA[j]; outB[idx] = oB + localB[j]; }
    }
}

__global__ void k_scan2d(int* bsA, int* bsB, int nb, int* rowptr, int* tstart, int* ntiles) {
    int run = 0;
    for (int i = 0; i < nb; ++i) { int v = bsA[i]; bsA[i] = run; run += v; }
    rowptr[N_NODES] = N_EDGES;
    run = 0;
    for (int i = 0; i < nb; ++i) { int v = bsB[i]; bsB[i] = run; run += v; }
    tstart[N_NODES] = run;
    *ntiles = run;
}

__global__ __launch_bounds__(256) void k_scan3d(int* rowptr, int* tstart,
                                                const int* __restrict__ bsA,
                                                const int* __restrict__ bsB) {
    int idx = blockIdx.x * 256 + threadIdx.x;
    if (idx < N_NODES) {
        rowptr[idx] += bsA[idx >> 11];
        tstart[idx] += bsB[idx >> 11];
    }
}

// scatter with atomicSub on hist counts (reverse fill; edge order within node irrelevant)
__global__ __launch_bounds__(256) void k_scatter(const int* __restrict__ src, const int* __restrict__ dst,
                                                 const int* __restrict__ rowptr, int* cursor,
                                                 int* __restrict__ csr_src) {
    int e = blockIdx.x * 256 + threadIdx.x;
    if (e >= N_EDGES) return;
    int d = dst[e];
    int pos = rowptr[d] + atomicSub(&cursor[d], 1) - 1;
    csr_src[pos] = src[e];
}

// dis + per-graph counts in one pass
__global__ __launch_bounds__(256) void k_dis_counts(const int* __restrict__ rowptr, float* dis,
                                                    const int* __restrict__ batch, float* counts) {
    __shared__ float lc[G_GRAPHS];
    if (threadIdx.x < G_GRAPHS) lc[threadIdx.x] = 0.f;
    __syncthreads();
    int n = blockIdx.x * 256 + threadIdx.x;
    if (n < N_NODES) {
        int deg = rowptr[n + 1] - rowptr[n];
        dis[n] = rsqrtf((float)deg + 1.0f);
        atomicAdd(&lc[batch[n]], 1.0f);
    }
    __syncthreads();
    if (threadIdx.x < G_GRAPHS && lc[threadIdx.x] > 0.f)
        atomicAdd(&counts[threadIdx.x], lc[threadIdx.x]);
}

// ---------- tile list: tileN + padded per-tile src indices ----------
__global__ __launch_bounds__(256) void k_tfill(const int* __restrict__ rowptr,
                                               const int* __restrict__ csr_src,
                                               const int* __restrict__ tstart,
                                               int* __restrict__ tileN,
                                               int* __restrict__ tileSrc) {
    int n = blockIdx.x * 256 + threadIdx.x;
    if (n >= N_NODES) return;
    int t0 = tstart[n], t1 = tstart[n + 1];
    int beg = rowptr[n], end = rowptr[n + 1];
    for (int t = t0; t < t1; ++t) {
        tileN[t] = n;
        int tb = beg + (t - t0) * 16;
        #pragma unroll 4
        for (int j = 0; j < 16; ++j) {
            int ei = tb + j;
            tileSrc[t * 16 + j] = csr_src[ei < end ? ei : end - 1];
        }
    }
}

// ---------- GCN1 GEMM: out = (x[M,9] @ W1[9,128]) * dis[row], bf16 ----------
__global__ __launch_bounds__(256) void k_gemm_f32bf_scale(const float* __restrict__ A,
                                                          const float* __restrict__ W,
                                                          const float* __restrict__ dis,
                                                          short* __restrict__ out, int M) {
    __shared__ float w_lds[F_IN * H];
    for (int i = threadIdx.x; i < F_IN * H; i += 256) w_lds[i] = W[i];
    __syncthreads();
    int row = blockIdx.x * 8 + threadIdx.x / 32;
    int c4 = (threadIdx.x & 31) << 2;
    if (row >= M) return;
    const float* a = A + (size_t)row * F_IN;
    float acc0 = 0.f, acc1 = 0.f, acc2 = 0.f, acc3 = 0.f;
    #pragma unroll
    for (int k = 0; k < F_IN; ++k) {
        float av = a[k];
        float4 w = *reinterpret_cast<const float4*>(&w_lds[k * H + c4]);
        acc0 = fmaf(av, w.x, acc0);
        acc1 = fmaf(av, w.y, acc1);
        acc2 = fmaf(av, w.z, acc2);
        acc3 = fmaf(av, w.w, acc3);
    }
    float dv = dis[row];
    uint2 o = make_uint2(cvtpk(acc0 * dv, acc1 * dv), cvtpk(acc2 * dv, acc3 * dv));
    *reinterpret_cast<uint2*>(&out[(size_t)row * H + c4]) = o;
}

// ---------- dual MFMA GEMM (512 thr): U = A@WU + be1 ; V = A@WV ; zero aggEnc strip ----------
__global__ __launch_bounds__(512) void k_gemm_dual(const short* __restrict__ A,
                                                   const short* __restrict__ WfU,
                                                   const short* __restrict__ WfV,
                                                   const float* __restrict__ be1,
                                                   short* __restrict__ U,
                                                   short* __restrict__ V,
                                                   unsigned* __restrict__ aggEnc, int M) {
    __shared__ short wl[32768];
    for (int i = threadIdx.x * 8; i < 16384; i += 4096) {
        *reinterpret_cast<f32x4*>(&wl[i])         = *reinterpret_cast<const f32x4*>(&WfU[i]);
        *reinterpret_cast<f32x4*>(&wl[16384 + i]) = *reinterpret_cast<const f32x4*>(&WfV[i]);
    }
    // zero this block's aggEnc strip (rows blockIdx*128 .. +127); completes before k_edge_tile
    {
        int r0 = blockIdx.x * 128;
        uint4* base = reinterpret_cast<uint4*>(aggEnc + (size_t)r0 * H);
        const uint4 z = make_uint4(0, 0, 0, 0);
        #pragma unroll
        for (int i = 0; i < 8; ++i) {
            int idx = threadIdx.x + i * 512;            // 4096 uint4 per block
            int row = r0 + (idx >> 5);
            if (row < M) base[idx] = z;
        }
    }
    __syncthreads();
    int wv = threadIdx.x >> 6, lane = threadIdx.x & 63;
    int er = lane & 15, kg = lane >> 4;
    int row0 = (blockIdx.x * 8 + wv) * 16;
    if (row0 >= M) return;
    bf16x8 af[4];
    #pragma unroll
    for (int kc = 0; kc < 4; ++kc)
        af[kc] = *reinterpret_cast<const bf16x8*>(&A[(size_t)(row0 + er) * H + kc * 32 + kg * 8]);
    const f32x4 vzero = {0.f, 0.f, 0.f, 0.f};
    f32x4 acc[8];
    #pragma unroll
    for (int ct = 0; ct < 8; ++ct) acc[ct] = vzero;
    #pragma unroll
    for (int kc = 0; kc < 4; ++kc)
        #pragma unroll
        for (int ct = 0; ct < 8; ++ct) {
            bf16x8 bf = *reinterpret_cast<const bf16x8*>(&wl[((kc * 8 + ct) * 64 + lane) * 8]);
            acc[ct] = __builtin_amdgcn_mfma_f32_16x16x32_bf16(af[kc], bf, acc[ct], 0, 0, 0);
        }
    #pragma unroll
    for (int ct = 0; ct < 8; ++ct) {
        int col = ct * 16 + er;
        float bv = be1[col];
        #pragma unroll
        for (int r = 0; r < 4; ++r)
            U[(size_t)(row0 + kg * 4 + r) * H + col] = f2b(acc[ct][r] + bv);
    }
    #pragma unroll
    for (int ct = 0; ct < 8; ++ct) acc[ct] = vzero;
    #pragma unroll
    for (int kc = 0; kc < 4; ++kc)
        #pragma unroll
        for (int ct = 0; ct < 8; ++ct) {
            bf16x8 bf = *reinterpret_cast<const bf16x8*>(&wl[16384 + ((kc * 8 + ct) * 64 + lane) * 8]);
            acc[ct] = __builtin_amdgcn_mfma_f32_16x16x32_bf16(af[kc], bf, acc[ct], 0, 0, 0);
        }
    #pragma unroll
    for (int ct = 0; ct < 8; ++ct) {
        int col = ct * 16 + er;
        #pragma unroll
        for (int r = 0; r < 4; ++r)
            V[(size_t)(row0 + kg * 4 + r) * H + col] = f2b(acc[ct][r]);
    }
}

// ---------- MFMA GEMM reading EdgeConv aggregate (512 thr) ----------
__global__ __launch_bounds__(512) void k_gemm_scale_agg(const unsigned* __restrict__ aggEnc,
                                                        const float* __restrict__ be2,
                                                        const short* __restrict__ Wf,
                                                        const float* __restrict__ dis,
                                                        short* __restrict__ out, int M) {
    __shared__ short wl[16384];
    for (int i = threadIdx.x * 8; i < 16384; i += 4096)
        *reinterpret_cast<f32x4*>(&wl[i]) = *reinterpret_cast<const f32x4*>(&Wf[i]);
    __syncthreads();
    int wv = threadIdx.x >> 6, lane = threadIdx.x & 63;
    int er = lane & 15, kg = lane >> 4;
    int row0 = (blockIdx.x * 8 + wv) * 16;
    if (row0 >= M) return;
    bf16x8 af[4];
    #pragma unroll
    for (int kc = 0; kc < 4; ++kc) {
        int basec = kc * 32 + kg * 8;
        const unsigned* ap = &aggEnc[(size_t)(row0 + er) * H + basec];
        uint4 q0 = *reinterpret_cast<const uint4*>(ap);
        uint4 q1 = *reinterpret_cast<const uint4*>(ap + 4);
        float f0 = q0.x ? tanhf(decodef(q0.x) + be2[basec + 0]) : 0.f;
        float f1 = q0.y ? tanhf(decodef(q0.y) + be2[basec + 1]) : 0.f;
        float f2 = q0.z ? tanhf(decodef(q0.z) + be2[basec + 2]) : 0.f;
        float f3 = q0.w ? tanhf(decodef(q0.w) + be2[basec + 3]) : 0.f;
        float f4 = q1.x ? tanhf(decodef(q1.x) + be2[basec + 4]) : 0.f;
        float f5 = q1.y ? tanhf(decodef(q1.y) + be2[basec + 5]) : 0.f;
        float f6 = q1.z ? tanhf(decodef(q1.z) + be2[basec + 6]) : 0.f;
        float f7 = q1.w ? tanhf(decodef(q1.w) + be2[basec + 7]) : 0.f;
        union { unsigned u[4]; bf16x8 v; } A;
        A.u[0] = cvtpk(f0, f1); A.u[1] = cvtpk(f2, f3);
        A.u[2] = cvtpk(f4, f5); A.u[3] = cvtpk(f6, f7);
        af[kc] = A.v;
    }
    const f32x4 vzero = {0.f, 0.f, 0.f, 0.f};
    f32x4 acc[8];
    #pragma unroll
    for (int ct = 0; ct < 8; ++ct) acc[ct] = vzero;
    #pragma unroll
    for (int kc = 0; kc < 4; ++kc)
        #pragma unroll
        for (int ct = 0; ct < 8; ++ct) {
            bf16x8 bf = *reinterpret_cast<const bf16x8*>(&wl[((kc * 8 + ct) * 64 + lane) * 8]);
            acc[ct] = __builtin_amdgcn_mfma_f32_16x16x32_bf16(af[kc], bf, acc[ct], 0, 0, 0);
        }
    float dv[4];
    #pragma unroll
    for (int r = 0; r < 4; ++r) dv[r] = dis[row0 + kg * 4 + r];
    #pragma unroll
    for (int ct = 0; ct < 8; ++ct) {
        int col = ct * 16 + er;
        #pragma unroll
        for (int r = 0; r < 4; ++r)
            out[(size_t)(row0 + kg * 4 + r) * H + col] = f2b(acc[ct][r] * dv[r]);
    }
}

// ---------- GCN fused agg+combine (CSR, pre-scaled rows, packed-f32 accumulation) ----------
__global__ __launch_bounds__(256) void k_gcn_fused(const int* __restrict__ rowptr,
                                                   const int* __restrict__ csr_src,
                                                   const short* __restrict__ hWs,
                                                   const float* __restrict__ dis,
                                                   const float* __restrict__ bias,
                                                   short* __restrict__ out) {
    int wv = threadIdx.x >> 6, lane = threadIdx.x & 63;
    const unsigned* hw = (const unsigned*)hWs;
    const f32x2 z2 = {0.f, 0.f};
    for (int n = blockIdx.x * 4 + wv; n < N_NODES; n += gridDim.x * 4) {
        int beg = rowptr[n], end = rowptr[n + 1];
        f32x2 sa = z2, sb = z2, sc = z2, sd = z2;
        int e = beg;
        for (; e + 8 <= end; e += 8) {
            int s0 = csr_src[e],     s1 = csr_src[e + 1], s2 = csr_src[e + 2], s3 = csr_src[e + 3];
            int s4 = csr_src[e + 4], s5 = csr_src[e + 5], s6 = csr_src[e + 6], s7 = csr_src[e + 7];
            unsigned w0 = hw[(size_t)s0 * 64 + lane];
            unsigned w1 = hw[(size_t)s1 * 64 + lane];
            unsigned w2 = hw[(size_t)s2 * 64 + lane];
            unsigned w3 = hw[(size_t)s3 * 64 + lane];
            unsigned w4 = hw[(size_t)s4 * 64 + lane];
            unsigned w5 = hw[(size_t)s5 * 64 + lane];
            unsigned w6 = hw[(size_t)s6 * 64 + lane];
            unsigned w7 = hw[(size_t)s7 * 64 + lane];
            sa += up2(w0); sb += up2(w1); sc += up2(w2); sd += up2(w3);
            sa += up2(w4); sb += up2(w5); sc += up2(w6); sd += up2(w7);
        }
        for (; e + 4 <= end; e += 4) {
            int s0 = csr_src[e], s1 = csr_src[e + 1], s2 = csr_src[e + 2], s3 = csr_src[e + 3];
            unsigned w0 = hw[(size_t)s0 * 64 + lane];
            unsigned w1 = hw[(size_t)s1 * 64 + lane];
            unsigned w2 = hw[(size_t)s2 * 64 + lane];
            unsigned w3 = hw[(size_t)s3 * 64 + lane];
            sa += up2(w0); sb += up2(w1); sc += up2(w2); sd += up2(w3);
        }
        for (; e < end; ++e) sa += up2(hw[(size_t)csr_src[e] * 64 + lane]);
        f32x2 s = (sa + sb) + (sc + sd);
        float dn = dis[n];
        f32x2 wn2 = up2(hw[(size_t)n * 64 + lane]);
        float r0 = tanhf(dn * (s.x + wn2.x) + bias[lane * 2]);
        float r1 = tanhf(dn * (s.y + wn2.y) + bias[lane * 2 + 1]);
        *reinterpret_cast<unsigned*>(&out[(size_t)n * H + lane * 2]) = cvtpk(r0, r1);
    }
}

// ---------- EdgeConv: one wave per 16-edge tile (512 thr); packed-f32 A-build ----------
__global__ __launch_bounds__(512) void k_edge_tile(const int* __restrict__ tileN,
                                                   const int* __restrict__ tileSrc,
                                                   const int* __restrict__ ntilesp,
                                                   const short* __restrict__ U,
                                                   const short* __restrict__ V,
                                                   const short* __restrict__ We2f,
                                                   unsigned* aggEnc) {
    int nt = *ntilesp;
    if ((int)(blockIdx.x * 8) >= nt) return;
    __shared__ short wl[16384];
    for (int i = threadIdx.x * 8; i < 16384; i += 4096)
        *reinterpret_cast<f32x4*>(&wl[i]) = *reinterpret_cast<const f32x4*>(&We2f[i]);
    __syncthreads();
    int wv = threadIdx.x >> 6, lane = threadIdx.x & 63;
    int er = lane & 15, kg = lane >> 4, kseg = kg * 8;
    int tid = blockIdx.x * 8 + wv;
    if (tid >= nt) return;
    int n = tileN[tid];
    int s = tileSrc[tid * 16 + er];
    const f32x4 vzero = {0.f, 0.f, 0.f, 0.f};
    const f32x2 z2 = {0.f, 0.f};
    f32x4 acc[8];
    #pragma unroll
    for (int ct = 0; ct < 8; ++ct) acc[ct] = vzero;
    #pragma unroll
    for (int kc = 0; kc < 4; ++kc) {
        uint4 uu4 = *reinterpret_cast<const uint4*>(&U[(size_t)n * H + kc * 32 + kseg]);
        uint4 vv4 = *reinterpret_cast<const uint4*>(&V[(size_t)s * H + kc * 32 + kseg]);
        union { unsigned u[4]; bf16x8 v; } A;
        f32x2 t;
        t = __builtin_elementwise_max(up2(uu4.x) + up2(vv4.x), z2); A.u[0] = cvtpk(t.x, t.y);
        t = __builtin_elementwise_max(up2(uu4.y) + up2(vv4.y), z2); A.u[1] = cvtpk(t.x, t.y);
        t = __builtin_elementwise_max(up2(uu4.z) + up2(vv4.z), z2); A.u[2] = cvtpk(t.x, t.y);
        t = __builtin_elementwise_max(up2(uu4.w) + up2(vv4.w), z2); A.u[3] = cvtpk(t.x, t.y);
        #pragma unroll
        for (int ct = 0; ct < 8; ++ct) {
            bf16x8 bf = *reinterpret_cast<const bf16x8*>(&wl[((kc * 8 + ct) * 64 + lane) * 8]);
            acc[ct] = __builtin_amdgcn_mfma_f32_16x16x32_bf16(A.v, bf, acc[ct], 0, 0, 0);
        }
    }
    float cm[8];
    #pragma unroll
    for (int ct = 0; ct < 8; ++ct) {
        // chained for v_max3 fusion
        float v = fmaxf(fmaxf(fmaxf(acc[ct][0], acc[ct][1]), acc[ct][2]), acc[ct][3]);
        v = fmaxf(v, __shfl_xor(v, 16));
        v = fmaxf(v, __shfl_xor(v, 32));
        cm[ct] = v;
    }
    float vA, vB;
    if (kg == 0)      { vA = cm[0]; vB = cm[1]; }
    else if (kg == 1) { vA = cm[2]; vB = cm[3]; }
    else if (kg == 2) { vA = cm[4]; vB = cm[5]; }
    else              { vA = cm[6]; vB = cm[7]; }
    int colA = (kg * 2) * 16 + er;
    int colB = (kg * 2 + 1) * 16 + er;
    atomicMax(&aggEnc[(size_t)n * H + colA], encodef(vA));
    atomicMax(&aggEnc[(size_t)n * H + colB], encodef(vB));
}

// ---------- fused final MLP + pooling, reading EdgeConv aggregate directly ----------
__global__ __launch_bounds__(512) void k_final_mlp_agg(const unsigned* __restrict__ aggEnc,
                                                       const float* __restrict__ be2,
                                                       const short* __restrict__ WfF1,
                                                       const short* __restrict__ WfF2,
                                                       const float* __restrict__ bf1,
                                                       const float* __restrict__ bf2,
                                                       const float* __restrict__ Wf3,
                                                       const float* __restrict__ bf3,
                                                       const int* __restrict__ batch,
                                                       float* pooled, int M) {
    __shared__ short wl1[16384];
    __shared__ short wl2[4096];
    __shared__ short tb[8][2048];
    __shared__ float lp[G_GRAPHS];
    for (int i = threadIdx.x * 8; i < 16384; i += 4096)
        *reinterpret_cast<f32x4*>(&wl1[i]) = *reinterpret_cast<const f32x4*>(&WfF1[i]);
    {
        int i = threadIdx.x * 8;
        if (i < 4096)
            *reinterpret_cast<f32x4*>(&wl2[i]) = *reinterpret_cast<const f32x4*>(&WfF2[i]);
    }
    if (threadIdx.x < G_GRAPHS) lp[threadIdx.x] = 0.f;
    __syncthreads();
    int wv = threadIdx.x >> 6, lane = threadIdx.x & 63;
    int er = lane & 15, kg = lane >> 4;
    int row0 = (blockIdx.x * 8 + wv) * 16;
    bool active = row0 < M;
    const f32x4 vzero = {0.f, 0.f, 0.f, 0.f};
    if (active) {
        bf16x8 af[4];
        #pragma unroll
        for (int kc = 0; kc < 4; ++kc) {
            int basec = kc * 32 + kg * 8;
            const unsigned* ap = &aggEnc[(size_t)(row0 + er) * H + basec];
            uint4 q0 = *reinterpret_cast<const uint4*>(ap);
            uint4 q1 = *reinterpret_cast<const uint4*>(ap + 4);
            float f0 = q0.x ? tanhf(decodef(q0.x) + be2[basec + 0]) : 0.f;
            float f1 = q0.y ? tanhf(decodef(q0.y) + be2[basec + 1]) : 0.f;
            float f2 = q0.z ? tanhf(decodef(q0.z) + be2[basec + 2]) : 0.f;
            float f3 = q0.w ? tanhf(decodef(q0.w) + be2[basec + 3]) : 0.f;
            float f4 = q1.x ? tanhf(decodef(q1.x) + be2[basec + 4]) : 0.f;
            float f5 = q1.y ? tanhf(decodef(q1.y) + be2[basec + 5]) : 0.f;
            float f6 = q1.z ? tanhf(decodef(q1.z) + be2[basec + 6]) : 0.f;
            float f7 = q1.w ? tanhf(decodef(q1.w) + be2[basec + 7]) : 0.f;
            union { unsigned u[4]; bf16x8 v; } A;
            A.u[0] = cvtpk(f0, f1); A.u[1] = cvtpk(f2, f3);
            A.u[2] = cvtpk(f4, f5); A.u[3] = cvtpk(f6, f7);
            af[kc] = A.v;
        }
        f32x4 acc[8];
        #pragma unroll
        for (int ct = 0; ct < 8; ++ct) acc[ct] = vzero;
        #pragma unroll
        for (int kc = 0; kc < 4; ++kc)
            #pragma unroll
            for (int ct = 0; ct < 8; ++ct) {
                bf16x8 bf = *reinterpret_cast<const bf16x8*>(&wl1[((kc * 8 + ct) * 64 + lane) * 8]);
                acc[ct] = __builtin_amdgcn_mfma_f32_16x16x32_bf16(af[kc], bf, acc[ct], 0, 0, 0);
            }
        #pragma unroll
        for (int ct = 0; ct < 8; ++ct) {
            int col = ct * 16 + er;
            float bv = bf1[col];
            #pragma unroll
            for (int r = 0; r < 4; ++r)
                tb[wv][(kg * 4 + r) * 128 + col] = f2b(tanhf(acc[ct][r] + bv));
        }
    }
    __syncthreads();
    if (active) {
        bf16x8 af2[4];
        #pragma unroll
        for (int kc = 0; kc < 4; ++kc)
            af2[kc] = *reinterpret_cast<const bf16x8*>(&tb[wv][er * 128 + kc * 32 + kg * 8]);
        f32x4 a2[2];
        a2[0] = vzero; a2[1] = vzero;
        #pragma unroll
        for (int kc = 0; kc < 4; ++kc)
            #pragma unroll
            for (int ct = 0; ct < 2; ++ct) {
                bf16x8 bf = *reinterpret_cast<const bf16x8*>(&wl2[((kc * 2 + ct) * 64 + lane) * 8]);
                a2[ct] = __builtin_amdgcn_mfma_f32_16x16x32_bf16(af2[kc], bf, a2[ct], 0, 0, 0);
            }
        float w3a = Wf3[er], w3b = Wf3[16 + er];
        float b2a = bf2[er], b2b = bf2[16 + er];
        float bf3v = bf3[0];
        float psum[4];
        #pragma unroll
        for (int r = 0; r < 4; ++r) {
            float f2a = tanhf(a2[0][r] + b2a);
            float f2c = tanhf(a2[1][r] + b2b);
            float p = f2a * w3a + f2c * w3b;
            p += __shfl_xor(p, 1);
            p += __shfl_xor(p, 2);
            p += __shfl_xor(p, 4);
            p += __shfl_xor(p, 8);
            psum[r] = p + bf3v;
        }
        if (er == 0) {
            #pragma unroll
            for (int r = 0; r < 4; ++r) {
                int n = row0 + kg * 4 + r;
                if (n < M) atomicAdd(&lp[batch[n]], psum[r]);
            }
        }
    }
    __syncthreads();
    if (threadIdx.x < G_GRAPHS && lp[threadIdx.x] != 0.f)
        atomicAdd(&pooled[threadIdx.x], lp[threadIdx.x]);
}

__global__ __launch_bounds__(64) void k_final(const float* pooled, const float* counts,
                                              void* out, const int* __restrict__ flag) {
    int g = threadIdx.x;
    if (g < G_GRAPHS) {
        float v = pooled[g] / fmaxf(counts[g], 1.0f);
        float s = 1.0f / (1.0f + expf(-v));
        if (*flag) ((__hip_bfloat16*)out)[g] = __float2bfloat16(s);
        else       ((float*)out)[g] = s;
    }
}

extern "C" void kernel_launch(void* const* d_in, const int* in_sizes, int n_in,
                              void* d_out, int out_size, void* d_ws, size_t ws_size,
                              hipStream_t stream) {
    const int* ei    = (const int*)d_in[1];
    const int* src   = ei;
    const int* dst   = ei + N_EDGES;
    const int* batch = (const int*)d_in[2];

    float* ws = (float*)d_ws;
    size_t off = 0;
    auto alloc = [&](size_t n) { off = (off + 3) & ~(size_t)3; float* p = ws + off; off += n; return p; };

    const size_t NH = (size_t)N_NODES * H;
    short* hb     = (short*)alloc(NH / 2);
    short* Ub     = (short*)alloc(NH / 2);
    short* Vb     = (short*)alloc(NH / 2);
    unsigned* aggEnc = (unsigned*)alloc(NH);
    float* xf     = alloc((size_t)N_NODES * F_IN);
    float* dis    = alloc(N_NODES);
    float* pooled = alloc(G_GRAPHS);
    float* counts = alloc(G_GRAPHS);
    int*   flag   = (int*)alloc(1);
    int*   rowptr = (int*)alloc(N_NODES + 1);
    int*   cursor = (int*)alloc(N_NODES);
    int*   csrsrc = (int*)alloc(N_EDGES);
    int*   bsums  = (int*)alloc(32);
    int*   bsums2 = (int*)alloc(32);
    int*   tstart = (int*)alloc(N_NODES + 1);
    int*   ntiles = (int*)alloc(1);
    int*   tileN  = (int*)alloc(MAXT);
    int*   tileSrc= (int*)alloc((size_t)MAXT * 16);

    float* W1  = alloc(F_IN * H);
    float* b1  = alloc(H);
    float* W2  = alloc(HH);
    float* b2  = alloc(H);
    float* We1 = alloc(2 * HH);
    float* be1 = alloc(H);
    float* We2 = alloc(HH);
    float* be2 = alloc(H);
    float* Wf1 = alloc(HH);
    float* bf1 = alloc(H);
    float* Wf2 = alloc(H * 32);
    float* bf2 = alloc(32);
    float* Wf3 = alloc(32);
    float* bf3 = alloc(4);
    short* WfU  = (short*)alloc(8192);
    short* WfV  = (short*)alloc(8192);
    short* WfW2 = (short*)alloc(8192);
    short* WfF1 = (short*)alloc(8192);
    short* WfF2 = (short*)alloc(2048);
    short* We2f = (short*)alloc(8192);

    const int eB    = (N_EDGES + 255) / 256;
    const int nB    = (N_NODES + 255) / 256;
    const int scanB = (N_NODES + 2047) / 2048;
    const int mfmaB = (N_NODES / 16 + 7) / 8;      // 391 blocks of 512
    const int gcnB  = (N_NODES + 3) / 4;           // 12500
    const int tileB = (MAXT + 7) / 8;              // 12500 blocks of 512

    k_detect<<<1, 256, 0, stream>>>((const unsigned*)d_in[0], flag, pooled, counts);

    CvtArgs ca;
    const int srcIdx[15] = {0, 3, 4, 5, 6, 7, 8, 9, 10, 11, 12, 13, 14, 15, 16};
    float* dsts[15] = {xf, W1, b1, W2, b2, We1, be1, We2, be2, Wf1, bf1, Wf2, bf2, Wf3, bf3};
    for (int s = 0; s < 15; ++s) { ca.src[s] = d_in[srcIdx[s]]; ca.dst[s] = dsts[s]; }
    const int cvtTotal = 450000 + 1152 + 128 + 16384 + 128 + 32768 + 128 + 16384 + 128
                       + 16384 + 128 + 4096 + 32 + 32 + 1;       // 537873
    k_cvt_all<<<(cvtTotal + 255) / 256, 256, 0, stream>>>(ca, flag);

    k_prep_all<<<42, 256, 0, stream>>>(We1, W2, Wf1, Wf2, We2,
                                       WfU, WfV, WfW2, WfF1, WfF2, We2f);

    // CSR + tile-list build (scatter consumes hist counts via atomicSub — no re-zero)
    k_zero<<<nB, 256, 0, stream>>>((float*)cursor, N_NODES);
    k_hist<<<eB, 256, 0, stream>>>(dst, cursor);
    k_scan1d<<<scanB, 256, 0, stream>>>(cursor, rowptr, tstart, bsums, bsums2);
    k_scan2d<<<1, 1, 0, stream>>>(bsums, bsums2, scanB, rowptr, tstart, ntiles);
    k_scan3d<<<nB, 256, 0, stream>>>(rowptr, tstart, bsums, bsums2);
    k_scatter<<<eB, 256, 0, stream>>>(src, dst, rowptr, cursor, csrsrc);
    k_dis_counts<<<nB, 256, 0, stream>>>(rowptr, dis, batch, counts);
    k_tfill<<<nB, 256, 0, stream>>>(rowptr, csrsrc, tstart, tileN, tileSrc);

    // GCN1
    k_gemm_f32bf_scale<<<(N_NODES + 7) / 8, 256, 0, stream>>>(xf, W1, dis, Ub, N_NODES);
    k_gcn_fused<<<gcnB, 256, 0, stream>>>(rowptr, csrsrc, Ub, dis, b1, hb);

    for (int iter = 0; iter < 3; ++iter) {
        k_gemm_dual<<<mfmaB, 512, 0, stream>>>(hb, WfU, WfV, be1, Ub, Vb, aggEnc, N_NODES);
        k_edge_tile<<<tileB, 512, 0, stream>>>(tileN, tileSrc, ntiles, Ub, Vb, We2f, aggEnc);
        if (iter < 2) {
            k_gemm_scale_agg<<<mfmaB, 512, 0, stream>>>(aggEnc, be2, WfW2, dis, Ub, N_NODES);
            k_gcn_fused<<<gcnB, 256, 0, stream>>>(rowptr, csrsrc, Ub, dis, b2, hb);
        }
    }

    k_final_mlp_agg<<<mfmaB, 512, 0, stream>>>(aggEnc, be2, WfF1, WfF2, bf1, bf2, Wf3, bf3,
                                               batch, pooled, N_NODES);
    k_final<<<1, 64, 0, stream>>>(pooled, counts, d_out, flag);
}

// Round 13
// 480.802 us; speedup vs baseline: 3.6974x; 1.0426x over previous
//
#include <hip/hip_runtime.h>
#include <hip/hip_bf16.h>

#define N_NODES 50000
#define N_EDGES 800000
#define F_IN 9
#define H 128
#define G_GRAPHS 64
#define HH (H * H)
#define MAXT (N_EDGES / 16 + N_NODES)   // 100000 upper bound on tile count

typedef short bf16x8 __attribute__((ext_vector_type(8)));
typedef float f32x4 __attribute__((ext_vector_type(4)));
typedef float f32x2 __attribute__((ext_vector_type(2)));

static __device__ inline short f2b(float f) {
    __hip_bfloat16 h = __float2bfloat16(f);
    return *reinterpret_cast<short*>(&h);
}
static __device__ inline float blo(unsigned u) { return __uint_as_float(u << 16); }
// packed unpack: lo exact, hi by raw bits (low-16 garbage ~2^-9 relative, below bf16 rounding)
static __device__ inline f32x2 up2(unsigned u) {
    f32x2 r; r.x = __uint_as_float(u << 16); r.y = __uint_as_float(u); return r;
}
static __device__ inline unsigned encodef(float f) {
    unsigned u = __float_as_uint(f);
    return (u & 0x80000000u) ? ~u : (u | 0x80000000u);
}
static __device__ inline float decodef(unsigned u) {
    return __uint_as_float((u & 0x80000000u) ? (u ^ 0x80000000u) : ~u);
}
// packed RNE f32->bf16 pair [gfx950, no builtin]
static __device__ inline unsigned cvtpk(float lo, float hi) {
    unsigned r;
    asm("v_cvt_pk_bf16_f32 %0, %1, %2" : "=v"(r) : "v"(lo), "v"(hi));
    return r;
}

// ---------- dtype detection (+ zero pooled/counts) ----------
__global__ __launch_bounds__(256) void k_detect(const unsigned* __restrict__ x, int* flag,
                                                float* pooled, float* counts) {
    __shared__ int cnt;
    if (threadIdx.x == 0) cnt = 0;
    __syncthreads();
    unsigned u = x[threadIdx.x];
    int e = (u >> 7) & 0xFF;
    if (e >= 0x70 && e <= 0x83) atomicAdd(&cnt, 1);
    if (threadIdx.x < G_GRAPHS) { pooled[threadIdx.x] = 0.f; counts[threadIdx.x] = 0.f; }
    __syncthreads();
    if (threadIdx.x == 0) *flag = (cnt >= 128) ? 1 : 0;
}

// ---------- batched convert of all float inputs (+ zero cursor) ----------
struct CvtArgs { const void* src[15]; float* dst[15]; };

__global__ __launch_bounds__(256) void k_cvt_all(CvtArgs a, const int* __restrict__ flag,
                                                 int* __restrict__ cursor) {
    const int sz[15] = {450000, 1152, 128, 16384, 128, 32768, 128, 16384, 128,
                        16384, 128, 4096, 32, 32, 1};
    const int cvtTotal = 537873;
    int i = blockIdx.x * 256 + threadIdx.x;
    if (i >= cvtTotal) {
        int c = i - cvtTotal;
        if (c < N_NODES) cursor[c] = 0;
        return;
    }
    int fl = *flag;
    int base = 0;
    #pragma unroll
    for (int s = 0; s < 15; ++s) {
        if (i >= base && i < base + sz[s]) {
            int off = i - base;
            float v = fl ? __bfloat162float(((const __hip_bfloat16*)a.src[s])[off])
                         : ((const float*)a.src[s])[off];
            a.dst[s][off] = v;
        }
        base += sz[s];
    }
}

// ---------- all weight fragment tables in one kernel (42 blocks) ----------
__global__ __launch_bounds__(256) void k_prep_all(const float* __restrict__ We1,
                                                  const float* __restrict__ W2,
                                                  const float* __restrict__ Wf1,
                                                  const float* __restrict__ Wf2,
                                                  const float* __restrict__ We2,
                                                  short* WfU, short* WfV, short* WfW2,
                                                  short* WfF1, short* WfF2, short* We2f) {
    int b = blockIdx.x;
    const float* W; const float* Wm = nullptr; short* out; int NT = 8; int tid;
    if (b < 8)       { W = We1;      Wm = We1 + HH; out = WfU;  tid = b * 256 + threadIdx.x; }
    else if (b < 16) { W = We1 + HH; out = WfV;  tid = (b - 8) * 256 + threadIdx.x; }
    else if (b < 24) { W = W2;       out = WfW2; tid = (b - 16) * 256 + threadIdx.x; }
    else if (b < 32) { W = Wf1;      out = WfF1; tid = (b - 24) * 256 + threadIdx.x; }
    else if (b < 40) { W = We2;      out = We2f; tid = (b - 32) * 256 + threadIdx.x; }
    else             { W = Wf2;      out = WfF2; NT = 2; tid = (b - 40) * 256 + threadIdx.x; }
    int total = 4 * NT * 64;
    if (tid >= total) return;
    int kc = tid / (NT * 64);
    int ct = (tid / 64) % NT;
    int lane = tid & 63;
    int Nc = NT * 16;
    int kb = kc * 32 + (lane >> 4) * 8;
    int col = ct * 16 + (lane & 15);
    #pragma unroll
    for (int j = 0; j < 8; ++j) {
        float w = W[(kb + j) * Nc + col];
        if (Wm) w -= Wm[(kb + j) * Nc + col];
        out[tid * 8 + j] = f2b(w);
    }
}

// ---------- CSR build ----------
__global__ __launch_bounds__(256) void k_hist(const int* __restrict__ dst, int* cnt) {
    int e = blockIdx.x * 256 + threadIdx.x;
    if (e < N_EDGES) atomicAdd(&cnt[dst[e]], 1);
}

// dual exclusive scan (deg, ceil(deg/16)) + dis + per-graph counts
__global__ __launch_bounds__(256) void k_scan1d(const int* __restrict__ deg,
                                                int* __restrict__ outA, int* __restrict__ outB,
                                                int* __restrict__ bsA, int* __restrict__ bsB,
                                                float* __restrict__ dis,
                                                const int* __restrict__ batch,
                                                float* __restrict__ counts) {
    __shared__ int ldsA[256], ldsB[256];
    __shared__ float lc[G_GRAPHS];
    if (threadIdx.x < G_GRAPHS) lc[threadIdx.x] = 0.f;
    int base = blockIdx.x * 2048;
    int t = threadIdx.x;
    int localA[8], localB[8];
    int sA = 0, sB = 0;
    #pragma unroll
    for (int j = 0; j < 8; ++j) {
        int idx = base + t * 8 + j;
        int v = (idx < N_NODES) ? deg[idx] : 0;
        int tc = (v + 15) >> 4;
        localA[j] = sA; sA += v;
        localB[j] = sB; sB += tc;
        if (idx < N_NODES) {
            dis[idx] = rsqrtf((float)v + 1.0f);
            atomicAdd(&lc[batch[idx]], 1.0f);
        }
    }
    ldsA[t] = sA; ldsB[t] = sB;
    __syncthreads();
    if (t == 0) {
        int run = 0;
        for (int i = 0; i < 256; ++i) { int v = ldsA[i]; ldsA[i] = run; run += v; }
        bsA[blockIdx.x] = run;
        run = 0;
        for (int i = 0; i < 256; ++i) { int v = ldsB[i]; ldsB[i] = run; run += v; }
        bsB[blockIdx.x] = run;
    }
    __syncthreads();
    int oA = ldsA[t], oB = ldsB[t];
    #pragma unroll
    for (int j = 0; j < 8; ++j) {
        int idx = base + t * 8 + j;
        if (idx < N_NODES) { outA[idx] = oA + localA[j]; outB[idx] = oB + localB[j]; }
    }
    if (threadIdx.x < G_GRAPHS && lc[threadIdx.x] > 0.f)
        atomicAdd(&counts[threadIdx.x], lc[threadIdx.x]);
}

__global__ void k_scan2d(int* bsA, int* bsB, int nb, int* rowptr, int* tstart, int* ntiles) {
    int run = 0;
    for (int i = 0; i < nb; ++i) { int v = bsA[i]; bsA[i] = run; run += v; }
    rowptr[N_NODES] = N_EDGES;
    run = 0;
    for (int i = 0; i < nb; ++i) { int v = bsB[i]; bsB[i] = run; run += v; }
    tstart[N_NODES] = run;
    *ntiles = run;
}

__global__ __launch_bounds__(256) void k_scan3d(int* rowptr, int* tstart,
                                                const int* __restrict__ bsA,
                                                const int* __restrict__ bsB) {
    int idx = blockIdx.x * 256 + threadIdx.x;
    if (idx < N_NODES) {
        rowptr[idx] += bsA[idx >> 11];
        tstart[idx] += bsB[idx >> 11];
    }
}

// scatter: fills csr_src AND tileSrc (reverse fill via atomicSub on hist counts)
__global__ __launch_bounds__(256) void k_scatter(const int* __restrict__ src, const int* __restrict__ dst,
                                                 const int* __restrict__ rowptr,
                                                 const int* __restrict__ tstart,
                                                 int* cursor,
                                                 int* __restrict__ csr_src,
                                                 int* __restrict__ tileSrc) {
    int e = blockIdx.x * 256 + threadIdx.x;
    if (e >= N_EDGES) return;
    int d = dst[e];
    int sv = src[e];
    int local = atomicSub(&cursor[d], 1) - 1;
    csr_src[rowptr[d] + local] = sv;
    tileSrc[(tstart[d] + (local >> 4)) * 16 + (local & 15)] = sv;
}

// tile pad: tileN for every tile; duplicate last edge into final tile's tail
__global__ __launch_bounds__(256) void k_tpad(const int* __restrict__ rowptr,
                                              const int* __restrict__ csr_src,
                                              const int* __restrict__ tstart,
                                              int* __restrict__ tileN,
                                              int* __restrict__ tileSrc) {
    int n = blockIdx.x * 256 + threadIdx.x;
    if (n >= N_NODES) return;
    int t0 = tstart[n], t1 = tstart[n + 1];
    if (t0 == t1) return;
    for (int t = t0; t < t1; ++t) tileN[t] = n;
    int deg = rowptr[n + 1] - rowptr[n];
    int rem = deg & 15;
    if (rem) {
        int lastS = csr_src[rowptr[n + 1] - 1];
        int tb = (t1 - 1) * 16;
        for (int j = rem; j < 16; ++j) tileSrc[tb + j] = lastS;
    }
}

// ---------- GCN1 GEMM: out = (x[M,9] @ W1[9,128]) * dis[row], bf16 ----------
__global__ __launch_bounds__(256) void k_gemm_f32bf_scale(const float* __restrict__ A,
                                                          const float* __restrict__ W,
                                                          const float* __restrict__ dis,
                                                          short* __restrict__ out, int M) {
    __shared__ float w_lds[F_IN * H];
    for (int i = threadIdx.x; i < F_IN * H; i += 256) w_lds[i] = W[i];
    __syncthreads();
    int row = blockIdx.x * 8 + threadIdx.x / 32;
    int c4 = (threadIdx.x & 31) << 2;
    if (row >= M) return;
    const float* a = A + (size_t)row * F_IN;
    float acc0 = 0.f, acc1 = 0.f, acc2 = 0.f, acc3 = 0.f;
    #pragma unroll
    for (int k = 0; k < F_IN; ++k) {
        float av = a[k];
        float4 w = *reinterpret_cast<const float4*>(&w_lds[k * H + c4]);
        acc0 = fmaf(av, w.x, acc0);
        acc1 = fmaf(av, w.y, acc1);
        acc2 = fmaf(av, w.z, acc2);
        acc3 = fmaf(av, w.w, acc3);
    }
    float dv = dis[row];
    uint2 o = make_uint2(cvtpk(acc0 * dv, acc1 * dv), cvtpk(acc2 * dv, acc3 * dv));
    *reinterpret_cast<uint2*>(&out[(size_t)row * H + c4]) = o;
}

// ---------- dual MFMA GEMM (512 thr): U = A@WU + be1 ; V = A@WV ; zero aggEnc strip ----------
__global__ __launch_bounds__(512) void k_gemm_dual(const short* __restrict__ A,
                                                   const short* __restrict__ WfU,
                                                   const short* __restrict__ WfV,
                                                   const float* __restrict__ be1,
                                                   short* __restrict__ U,
                                                   short* __restrict__ V,
                                                   unsigned* __restrict__ aggEnc, int M) {
    __shared__ short wl[32768];
    for (int i = threadIdx.x * 8; i < 16384; i += 4096) {
        *reinterpret_cast<f32x4*>(&wl[i])         = *reinterpret_cast<const f32x4*>(&WfU[i]);
        *reinterpret_cast<f32x4*>(&wl[16384 + i]) = *reinterpret_cast<const f32x4*>(&WfV[i]);
    }
    {
        int r0 = blockIdx.x * 128;
        uint4* base = reinterpret_cast<uint4*>(aggEnc + (size_t)r0 * H);
        const uint4 z = make_uint4(0, 0, 0, 0);
        #pragma unroll
        for (int i = 0; i < 8; ++i) {
            int idx = threadIdx.x + i * 512;
            int row = r0 + (idx >> 5);
            if (row < M) base[idx] = z;
        }
    }
    __syncthreads();
    int wv = threadIdx.x >> 6, lane = threadIdx.x & 63;
    int er = lane & 15, kg = lane >> 4;
    int row0 = (blockIdx.x * 8 + wv) * 16;
    if (row0 >= M) return;
    bf16x8 af[4];
    #pragma unroll
    for (int kc = 0; kc < 4; ++kc)
        af[kc] = *reinterpret_cast<const bf16x8*>(&A[(size_t)(row0 + er) * H + kc * 32 + kg * 8]);
    const f32x4 vzero = {0.f, 0.f, 0.f, 0.f};
    f32x4 acc[8];
    #pragma unroll
    for (int ct = 0; ct < 8; ++ct) acc[ct] = vzero;
    #pragma unroll
    for (int kc = 0; kc < 4; ++kc)
        #pragma unroll
        for (int ct = 0; ct < 8; ++ct) {
            bf16x8 bf = *reinterpret_cast<const bf16x8*>(&wl[((kc * 8 + ct) * 64 + lane) * 8]);
            acc[ct] = __builtin_amdgcn_mfma_f32_16x16x32_bf16(af[kc], bf, acc[ct], 0, 0, 0);
        }
    #pragma unroll
    for (int ct = 0; ct < 8; ++ct) {
        int col = ct * 16 + er;
        float bv = be1[col];
        #pragma unroll
        for (int r = 0; r < 4; ++r)
            U[(size_t)(row0 + kg * 4 + r) * H + col] = f2b(acc[ct][r] + bv);
    }
    #pragma unroll
    for (int ct = 0; ct < 8; ++ct) acc[ct] = vzero;
    #pragma unroll
    for (int kc = 0; kc < 4; ++kc)
        #pragma unroll
        for (int ct = 0; ct < 8; ++ct) {
            bf16x8 bf = *reinterpret_cast<const bf16x8*>(&wl[16384 + ((kc * 8 + ct) * 64 + lane) * 8]);
            acc[ct] = __builtin_amdgcn_mfma_f32_16x16x32_bf16(af[kc], bf, acc[ct], 0, 0, 0);
        }
    #pragma unroll
    for (int ct = 0; ct < 8; ++ct) {
        int col = ct * 16 + er;
        #pragma unroll
        for (int r = 0; r < 4; ++r)
            V[(size_t)(row0 + kg * 4 + r) * H + col] = f2b(acc[ct][r]);
    }
}

// ---------- MFMA GEMM reading EdgeConv aggregate (512 thr) ----------
__global__ __launch_bounds__(512) void k_gemm_scale_agg(const unsigned* __restrict__ aggEnc,
                                                        const float* __restrict__ be2,
                                                        const short* __restrict__ Wf,
                                                        const float* __restrict__ dis,
                                                        short* __restrict__ out, int M) {
    __shared__ short wl[16384];
    for (int i = threadIdx.x * 8; i < 16384; i += 4096)
        *reinterpret_cast<f32x4*>(&wl[i]) = *reinterpret_cast<const f32x4*>(&Wf[i]);
    __syncthreads();
    int wv = threadIdx.x >> 6, lane = threadIdx.x & 63;
    int er = lane & 15, kg = lane >> 4;
    int row0 = (blockIdx.x * 8 + wv) * 16;
    if (row0 >= M) return;
    bf16x8 af[4];
    #pragma unroll
    for (int kc = 0; kc < 4; ++kc) {
        int basec = kc * 32 + kg * 8;
        const unsigned* ap = &aggEnc[(size_t)(row0 + er) * H + basec];
        uint4 q0 = *reinterpret_cast<const uint4*>(ap);
        uint4 q1 = *reinterpret_cast<const uint4*>(ap + 4);
        float f0 = q0.x ? tanhf(decodef(q0.x) + be2[basec + 0]) : 0.f;
        float f1 = q0.y ? tanhf(decodef(q0.y) + be2[basec + 1]) : 0.f;
        float f2 = q0.z ? tanhf(decodef(q0.z) + be2[basec + 2]) : 0.f;
        float f3 = q0.w ? tanhf(decodef(q0.w) + be2[basec + 3]) : 0.f;
        float f4 = q1.x ? tanhf(decodef(q1.x) + be2[basec + 4]) : 0.f;
        float f5 = q1.y ? tanhf(decodef(q1.y) + be2[basec + 5]) : 0.f;
        float f6 = q1.z ? tanhf(decodef(q1.z) + be2[basec + 6]) : 0.f;
        float f7 = q1.w ? tanhf(decodef(q1.w) + be2[basec + 7]) : 0.f;
        union { unsigned u[4]; bf16x8 v; } Afr;
        Afr.u[0] = cvtpk(f0, f1); Afr.u[1] = cvtpk(f2, f3);
        Afr.u[2] = cvtpk(f4, f5); Afr.u[3] = cvtpk(f6, f7);
        af[kc] = Afr.v;
    }
    const f32x4 vzero = {0.f, 0.f, 0.f, 0.f};
    f32x4 acc[8];
    #pragma unroll
    for (int ct = 0; ct < 8; ++ct) acc[ct] = vzero;
    #pragma unroll
    for (int kc = 0; kc < 4; ++kc)
        #pragma unroll
        for (int ct = 0; ct < 8; ++ct) {
            bf16x8 bf = *reinterpret_cast<const bf16x8*>(&wl[((kc * 8 + ct) * 64 + lane) * 8]);
            acc[ct] = __builtin_amdgcn_mfma_f32_16x16x32_bf16(af[kc], bf, acc[ct], 0, 0, 0);
        }
    float dv[4];
    #pragma unroll
    for (int r = 0; r < 4; ++r) dv[r] = dis[row0 + kg * 4 + r];
    #pragma unroll
    for (int ct = 0; ct < 8; ++ct) {
        int col = ct * 16 + er;
        #pragma unroll
        for (int r = 0; r < 4; ++r)
            out[(size_t)(row0 + kg * 4 + r) * H + col] = f2b(acc[ct][r] * dv[r]);
    }
}

// ---------- GCN fused agg+combine (CSR, pre-scaled rows, packed-f32 accumulation) ----------
__global__ __launch_bounds__(256) void k_gcn_fused(const int* __restrict__ rowptr,
                                                   const int* __restrict__ csr_src,
                                                   const short* __restrict__ hWs,
                                                   const float* __restrict__ dis,
                                                   const float* __restrict__ bias,
                                                   short* __restrict__ out) {
    int wv = threadIdx.x >> 6, lane = threadIdx.x & 63;
    const unsigned* hw = (const unsigned*)hWs;
    const f32x2 z2 = {0.f, 0.f};
    for (int n = blockIdx.x * 4 + wv; n < N_NODES; n += gridDim.x * 4) {
        int beg = rowptr[n], end = rowptr[n + 1];
        f32x2 sa = z2, sb = z2, sc = z2, sd = z2;
        int e = beg;
        for (; e + 8 <= end; e += 8) {
            int s0 = csr_src[e],     s1 = csr_src[e + 1], s2 = csr_src[e + 2], s3 = csr_src[e + 3];
            int s4 = csr_src[e + 4], s5 = csr_src[e + 5], s6 = csr_src[e + 6], s7 = csr_src[e + 7];
            unsigned w0 = hw[(size_t)s0 * 64 + lane];
            unsigned w1 = hw[(size_t)s1 * 64 + lane];
            unsigned w2 = hw[(size_t)s2 * 64 + lane];
            unsigned w3 = hw[(size_t)s3 * 64 + lane];
            unsigned w4 = hw[(size_t)s4 * 64 + lane];
            unsigned w5 = hw[(size_t)s5 * 64 + lane];
            unsigned w6 = hw[(size_t)s6 * 64 + lane];
            unsigned w7 = hw[(size_t)s7 * 64 + lane];
            sa += up2(w0); sb += up2(w1); sc += up2(w2); sd += up2(w3);
            sa += up2(w4); sb += up2(w5); sc += up2(w6); sd += up2(w7);
        }
        for (; e + 4 <= end; e += 4) {
            int s0 = csr_src[e], s1 = csr_src[e + 1], s2 = csr_src[e + 2], s3 = csr_src[e + 3];
            unsigned w0 = hw[(size_t)s0 * 64 + lane];
            unsigned w1 = hw[(size_t)s1 * 64 + lane];
            unsigned w2 = hw[(size_t)s2 * 64 + lane];
            unsigned w3 = hw[(size_t)s3 * 64 + lane];
            sa += up2(w0); sb += up2(w1); sc += up2(w2); sd += up2(w3);
        }
        for (; e < end; ++e) sa += up2(hw[(size_t)csr_src[e] * 64 + lane]);
        f32x2 s = (sa + sb) + (sc + sd);
        float dn = dis[n];
        f32x2 wn2 = up2(hw[(size_t)n * 64 + lane]);
        float r0 = tanhf(dn * (s.x + wn2.x) + bias[lane * 2]);
        float r1 = tanhf(dn * (s.y + wn2.y) + bias[lane * 2 + 1]);
        *reinterpret_cast<unsigned*>(&out[(size_t)n * H + lane * 2]) = cvtpk(r0, r1);
    }
}

// ---------- EdgeConv: persistent blocks, one wave per 16-edge tile, stage-once ----------
__global__ __launch_bounds__(512) void k_edge_tile(const int* __restrict__ tileN,
                                                   const int* __restrict__ tileSrc,
                                                   const int* __restrict__ ntilesp,
                                                   const short* __restrict__ U,
                                                   const short* __restrict__ V,
                                                   const short* __restrict__ We2f,
                                                   unsigned* aggEnc) {
    __shared__ short wl[16384];
    for (int i = threadIdx.x * 8; i < 16384; i += 4096)
        *reinterpret_cast<f32x4*>(&wl[i]) = *reinterpret_cast<const f32x4*>(&We2f[i]);
    __syncthreads();
    int nt = *ntilesp;
    int wv = threadIdx.x >> 6, lane = threadIdx.x & 63;
    int er = lane & 15, kg = lane >> 4, kseg = kg * 8;
    const f32x4 vzero = {0.f, 0.f, 0.f, 0.f};
    const f32x2 z2 = {0.f, 0.f};
    for (int tid = blockIdx.x * 8 + wv; tid < nt; tid += gridDim.x * 8) {
        int n = tileN[tid];
        int s = tileSrc[tid * 16 + er];
        f32x4 acc[8];
        #pragma unroll
        for (int ct = 0; ct < 8; ++ct) acc[ct] = vzero;
        #pragma unroll
        for (int kc = 0; kc < 4; ++kc) {
            uint4 uu4 = *reinterpret_cast<const uint4*>(&U[(size_t)n * H + kc * 32 + kseg]);
            uint4 vv4 = *reinterpret_cast<const uint4*>(&V[(size_t)s * H + kc * 32 + kseg]);
            union { unsigned u[4]; bf16x8 v; } A;
            f32x2 t;
            t = __builtin_elementwise_max(up2(uu4.x) + up2(vv4.x), z2); A.u[0] = cvtpk(t.x, t.y);
            t = __builtin_elementwise_max(up2(uu4.y) + up2(vv4.y), z2); A.u[1] = cvtpk(t.x, t.y);
            t = __builtin_elementwise_max(up2(uu4.z) + up2(vv4.z), z2); A.u[2] = cvtpk(t.x, t.y);
            t = __builtin_elementwise_max(up2(uu4.w) + up2(vv4.w), z2); A.u[3] = cvtpk(t.x, t.y);
            #pragma unroll
            for (int ct = 0; ct < 8; ++ct) {
                bf16x8 bf = *reinterpret_cast<const bf16x8*>(&wl[((kc * 8 + ct) * 64 + lane) * 8]);
                acc[ct] = __builtin_amdgcn_mfma_f32_16x16x32_bf16(A.v, bf, acc[ct], 0, 0, 0);
            }
        }
        float cm[8];
        #pragma unroll
        for (int ct = 0; ct < 8; ++ct) {
            float v = fmaxf(fmaxf(fmaxf(acc[ct][0], acc[ct][1]), acc[ct][2]), acc[ct][3]);
            v = fmaxf(v, __shfl_xor(v, 16));
            v = fmaxf(v, __shfl_xor(v, 32));
            cm[ct] = v;
        }
        float vA, vB;
        if (kg == 0)      { vA = cm[0]; vB = cm[1]; }
        else if (kg == 1) { vA = cm[2]; vB = cm[3]; }
        else if (kg == 2) { vA = cm[4]; vB = cm[5]; }
        else              { vA = cm[6]; vB = cm[7]; }
        int colA = (kg * 2) * 16 + er;
        int colB = (kg * 2 + 1) * 16 + er;
        atomicMax(&aggEnc[(size_t)n * H + colA], encodef(vA));
        atomicMax(&aggEnc[(size_t)n * H + colB], encodef(vB));
    }
}

// ---------- fused final MLP + pooling, reading EdgeConv aggregate directly ----------
__global__ __launch_bounds__(512) void k_final_mlp_agg(const unsigned* __restrict__ aggEnc,
                                                       const float* __restrict__ be2,
                                                       const short* __restrict__ WfF1,
                                                       const short* __restrict__ WfF2,
                                                       const float* __restrict__ bf1,
                                                       const float* __restrict__ bf2,
                                                       const float* __restrict__ Wf3,
                                                       const float* __restrict__ bf3,
                                                       const int* __restrict__ batch,
                                                       float* pooled, int M) {
    __shared__ short wl1[16384];
    __shared__ short wl2[4096];
    __shared__ short tb[8][2048];
    __shared__ float lp[G_GRAPHS];
    for (int i = threadIdx.x * 8; i < 16384; i += 4096)
        *reinterpret_cast<f32x4*>(&wl1[i]) = *reinterpret_cast<const f32x4*>(&WfF1[i]);
    {
        int i = threadIdx.x * 8;
        if (i < 4096)
            *reinterpret_cast<f32x4*>(&wl2[i]) = *reinterpret_cast<const f32x4*>(&WfF2[i]);
    }
    if (threadIdx.x < G_GRAPHS) lp[threadIdx.x] = 0.f;
    __syncthreads();
    int wv = threadIdx.x >> 6, lane = threadIdx.x & 63;
    int er = lane & 15, kg = lane >> 4;
    int row0 = (blockIdx.x * 8 + wv) * 16;
    bool active = row0 < M;
    const f32x4 vzero = {0.f, 0.f, 0.f, 0.f};
    if (active) {
        bf16x8 af[4];
        #pragma unroll
        for (int kc = 0; kc < 4; ++kc) {
            int basec = kc * 32 + kg * 8;
            const unsigned* ap = &aggEnc[(size_t)(row0 + er) * H + basec];
            uint4 q0 = *reinterpret_cast<const uint4*>(ap);
            uint4 q1 = *reinterpret_cast<const uint4*>(ap + 4);
            float f0 = q0.x ? tanhf(decodef(q0.x) + be2[basec + 0]) : 0.f;
            float f1 = q0.y ? tanhf(decodef(q0.y) + be2[basec + 1]) : 0.f;
            float f2 = q0.z ? tanhf(decodef(q0.z) + be2[basec + 2]) : 0.f;
            float f3 = q0.w ? tanhf(decodef(q0.w) + be2[basec + 3]) : 0.f;
            float f4 = q1.x ? tanhf(decodef(q1.x) + be2[basec + 4]) : 0.f;
            float f5 = q1.y ? tanhf(decodef(q1.y) + be2[basec + 5]) : 0.f;
            float f6 = q1.z ? tanhf(decodef(q1.z) + be2[basec + 6]) : 0.f;
            float f7 = q1.w ? tanhf(decodef(q1.w) + be2[basec + 7]) : 0.f;
            union { unsigned u[4]; bf16x8 v; } A;
            A.u[0] = cvtpk(f0, f1); A.u[1] = cvtpk(f2, f3);
            A.u[2] = cvtpk(f4, f5); A.u[3] = cvtpk(f6, f7);
            af[kc] = A.v;
        }
        f32x4 acc[8];
        #pragma unroll
        for (int ct = 0; ct < 8; ++ct) acc[ct] = vzero;
        #pragma unroll
        for (int kc = 0; kc < 4; ++kc)
            #pragma unroll
            for (int ct = 0; ct < 8; ++ct) {
                bf16x8 bf = *reinterpret_cast<const bf16x8*>(&wl1[((kc * 8 + ct) * 64 + lane) * 8]);
                acc[ct] = __builtin_amdgcn_mfma_f32_16x16x32_bf16(af[kc], bf, acc[ct], 0, 0, 0);
            }
        #pragma unroll
        for (int ct = 0; ct < 8; ++ct) {
            int col = ct * 16 + er;
            float bv = bf1[col];
            #pragma unroll
            for (int r = 0; r < 4; ++r)
                tb[wv][(kg * 4 + r) * 128 + col] = f2b(tanhf(acc[ct][r] + bv));
        }
    }
    __syncthreads();
    if (active) {
        bf16x8 af2[4];
        #pragma unroll
        for (int kc = 0; kc < 4; ++kc)
            af2[kc] = *reinterpret_cast<const bf16x8*>(&tb[wv][er * 128 + kc * 32 + kg * 8]);
        f32x4 a2[2];
        a2[0] = vzero; a2[1] = vzero;
        #pragma unroll
        for (int kc = 0; kc < 4; ++kc)
            #pragma unroll
            for (int ct = 0; ct < 2; ++ct) {
                bf16x8 bf = *reinterpret_cast<const bf16x8*>(&wl2[((kc * 2 + ct) * 64 + lane) * 8]);
                a2[ct] = __builtin_amdgcn_mfma_f32_16x16x32_bf16(af2[kc], bf, a2[ct], 0, 0, 0);
            }
        float w3a = Wf3[er], w3b = Wf3[16 + er];
        float b2a = bf2[er], b2b = bf2[16 + er];
        float bf3v = bf3[0];
        float psum[4];
        #pragma unroll
        for (int r = 0; r < 4; ++r) {
            float f2a = tanhf(a2[0][r] + b2a);
            float f2c = tanhf(a2[1][r] + b2b);
            float p = f2a * w3a + f2c * w3b;
            p += __shfl_xor(p, 1);
            p += __shfl_xor(p, 2);
            p += __shfl_xor(p, 4);
            p += __shfl_xor(p, 8);
            psum[r] = p + bf3v;
        }
        if (er == 0) {
            #pragma unroll
            for (int r = 0; r < 4; ++r) {
                int n = row0 + kg * 4 + r;
                if (n < M) atomicAdd(&lp[batch[n]], psum[r]);
            }
        }
    }
    __syncthreads();
    if (threadIdx.x < G_GRAPHS && lp[threadIdx.x] != 0.f)
        atomicAdd(&pooled[threadIdx.x], lp[threadIdx.x]);
}

__global__ __launch_bounds__(64) void k_final(const float* pooled, const float* counts,
                                              void* out, const int* __restrict__ flag) {
    int g = threadIdx.x;
    if (g < G_GRAPHS) {
        float v = pooled[g] / fmaxf(counts[g], 1.0f);
        float s = 1.0f / (1.0f + expf(-v));
        if (*flag) ((__hip_bfloat16*)out)[g] = __float2bfloat16(s);
        else       ((float*)out)[g] = s;
    }
}

extern "C" void kernel_launch(void* const* d_in, const int* in_sizes, int n_in,
                              void* d_out, int out_size, void* d_ws, size_t ws_size,
                              hipStream_t stream) {
    const int* ei    = (const int*)d_in[1];
    const int* src   = ei;
    const int* dst   = ei + N_EDGES;
    const int* batch = (const int*)d_in[2];

    float* ws = (float*)d_ws;
    size_t off = 0;
    auto alloc = [&](size_t n) { off = (off + 3) & ~(size_t)3; float* p = ws + off; off += n; return p; };

    const size_t NH = (size_t)N_NODES * H;
    short* hb     = (short*)alloc(NH / 2);
    short* Ub     = (short*)alloc(NH / 2);
    short* Vb     = (short*)alloc(NH / 2);
    unsigned* aggEnc = (unsigned*)alloc(NH);
    float* xf     = alloc((size_t)N_NODES * F_IN);
    float* dis    = alloc(N_NODES);
    float* pooled = alloc(G_GRAPHS);
    float* counts = alloc(G_GRAPHS);
    int*   flag   = (int*)alloc(1);
    int*   rowptr = (int*)alloc(N_NODES + 1);
    int*   cursor = (int*)alloc(N_NODES);
    int*   csrsrc = (int*)alloc(N_EDGES);
    int*   bsums  = (int*)alloc(32);
    int*   bsums2 = (int*)alloc(32);
    int*   tstart = (int*)alloc(N_NODES + 1);
    int*   ntiles = (int*)alloc(1);
    int*   tileN  = (int*)alloc(MAXT);
    int*   tileSrc= (int*)alloc((size_t)MAXT * 16);

    float* W1  = alloc(F_IN * H);
    float* b1  = alloc(H);
    float* W2  = alloc(HH);
    float* b2  = alloc(H);
    float* We1 = alloc(2 * HH);
    float* be1 = alloc(H);
    float* We2 = alloc(HH);
    float* be2 = alloc(H);
    float* Wf1 = alloc(HH);
    float* bf1 = alloc(H);
    float* Wf2 = alloc(H * 32);
    float* bf2 = alloc(32);
    float* Wf3 = alloc(32);
    float* bf3 = alloc(4);
    short* WfU  = (short*)alloc(8192);
    short* WfV  = (short*)alloc(8192);
    short* WfW2 = (short*)alloc(8192);
    short* WfF1 = (short*)alloc(8192);
    short* WfF2 = (short*)alloc(2048);
    short* We2f = (short*)alloc(8192);

    const int eB    = (N_EDGES + 255) / 256;
    const int nB    = (N_NODES + 255) / 256;
    const int scanB = (N_NODES + 2047) / 2048;
    const int mfmaB = (N_NODES / 16 + 7) / 8;      // 391 blocks of 512
    const int gcnB  = (N_NODES + 3) / 4;           // 12500
    const int edgeB = 1024;                        // persistent grid-stride

    k_detect<<<1, 256, 0, stream>>>((const unsigned*)d_in[0], flag, pooled, counts);

    CvtArgs ca;
    const int srcIdx[15] = {0, 3, 4, 5, 6, 7, 8, 9, 10, 11, 12, 13, 14, 15, 16};
    float* dsts[15] = {xf, W1, b1, W2, b2, We1, be1, We2, be2, Wf1, bf1, Wf2, bf2, Wf3, bf3};
    for (int s = 0; s < 15; ++s) { ca.src[s] = d_in[srcIdx[s]]; ca.dst[s] = dsts[s]; }
    const int cvtTotal = 537873 + N_NODES;         // + cursor zero range
    k_cvt_all<<<(cvtTotal + 255) / 256, 256, 0, stream>>>(ca, flag, cursor);

    k_prep_all<<<42, 256, 0, stream>>>(We1, W2, Wf1, Wf2, We2,
                                       WfU, WfV, WfW2, WfF1, WfF2, We2f);

    // CSR + tile-list build
    k_hist<<<eB, 256, 0, stream>>>(dst, cursor);
    k_scan1d<<<scanB, 256, 0, stream>>>(cursor, rowptr, tstart, bsums, bsums2,
                                        dis, batch, counts);
    k_scan2d<<<1, 1, 0, stream>>>(bsums, bsums2, scanB, rowptr, tstart, ntiles);
    k_scan3d<<<nB, 256, 0, stream>>>(rowptr, tstart, bsums, bsums2);
    k_scatter<<<eB, 256, 0, stream>>>(src, dst, rowptr, tstart, cursor, csrsrc, tileSrc);
    k_tpad<<<nB, 256, 0, stream>>>(rowptr, csrsrc, tstart, tileN, tileSrc);

    // GCN1
    k_gemm_f32bf_scale<<<(N_NODES + 7) / 8, 256, 0, stream>>>(xf, W1, dis, Ub, N_NODES);
    k_gcn_fused<<<gcnB, 256, 0, stream>>>(rowptr, csrsrc, Ub, dis, b1, hb);

    for (int iter = 0; iter < 3; ++iter) {
        k_gemm_dual<<<mfmaB, 512, 0, stream>>>(hb, WfU, WfV, be1, Ub, Vb, aggEnc, N_NODES);
        k_edge_tile<<<edgeB, 512, 0, stream>>>(tileN, tileSrc, ntiles, Ub, Vb, We2f, aggEnc);
        if (iter < 2) {
            k_gemm_scale_agg<<<mfmaB, 512, 0, stream>>>(aggEnc, be2, WfW2, dis, Ub, N_NODES);
            k_gcn_fused<<<gcnB, 256, 0, stream>>>(rowptr, csrsrc, Ub, dis, b2, hb);
        }
    }

    k_final_mlp_agg<<<mfmaB, 512, 0, stream>>>(aggEnc, be2, WfF1, WfF2, bf1, bf2, Wf3, bf3,
                                               batch, pooled, N_NODES);
    k_final<<<1, 64, 0, stream>>>(pooled, counts, d_out, flag);
}

// Round 14
// 466.971 us; speedup vs baseline: 3.8069x; 1.0296x over previous
//
#include <hip/hip_runtime.h>
#include <hip/hip_bf16.h>

#define N_NODES 50000
#define N_EDGES 800000
#define F_IN 9
#define H 128
#define G_GRAPHS 64
#define HH (H * H)
#define MAXT (N_EDGES / 16 + N_NODES)   // 100000 upper bound on tile count

typedef short bf16x8 __attribute__((ext_vector_type(8)));
typedef float f32x4 __attribute__((ext_vector_type(4)));
typedef float f32x2 __attribute__((ext_vector_type(2)));

static __device__ inline short f2b(float f) {
    __hip_bfloat16 h = __float2bfloat16(f);
    return *reinterpret_cast<short*>(&h);
}
// packed unpack: lo exact, hi by raw bits (low-16 garbage ~2^-9 relative, below bf16 rounding)
static __device__ inline f32x2 up2(unsigned u) {
    f32x2 r; r.x = __uint_as_float(u << 16); r.y = __uint_as_float(u); return r;
}
static __device__ inline unsigned encodef(float f) {
    unsigned u = __float_as_uint(f);
    return (u & 0x80000000u) ? ~u : (u | 0x80000000u);
}
static __device__ inline float decodef(unsigned u) {
    return __uint_as_float((u & 0x80000000u) ? (u ^ 0x80000000u) : ~u);
}
// packed RNE f32->bf16 pair [gfx950, no builtin]
static __device__ inline unsigned cvtpk(float lo, float hi) {
    unsigned r;
    asm("v_cvt_pk_bf16_f32 %0, %1, %2" : "=v"(r) : "v"(lo), "v"(hi));
    return r;
}

// ---------- dtype detection (+ zero pooled/counts) ----------
__global__ __launch_bounds__(256) void k_detect(const unsigned* __restrict__ x, int* flag,
                                                float* pooled, float* counts) {
    __shared__ int cnt;
    if (threadIdx.x == 0) cnt = 0;
    __syncthreads();
    unsigned u = x[threadIdx.x];
    int e = (u >> 7) & 0xFF;
    if (e >= 0x70 && e <= 0x83) atomicAdd(&cnt, 1);
    if (threadIdx.x < G_GRAPHS) { pooled[threadIdx.x] = 0.f; counts[threadIdx.x] = 0.f; }
    __syncthreads();
    if (threadIdx.x == 0) *flag = (cnt >= 128) ? 1 : 0;
}

// ---------- batched convert of all float inputs (+ zero cursor) ----------
struct CvtArgs { const void* src[15]; float* dst[15]; };

__global__ __launch_bounds__(256) void k_cvt_all(CvtArgs a, const int* __restrict__ flag,
                                                 int* __restrict__ cursor) {
    const int sz[15] = {450000, 1152, 128, 16384, 128, 32768, 128, 16384, 128,
                        16384, 128, 4096, 32, 32, 1};
    const int cvtTotal = 537873;
    int i = blockIdx.x * 256 + threadIdx.x;
    if (i >= cvtTotal) {
        int c = i - cvtTotal;
        if (c < N_NODES) cursor[c] = 0;
        return;
    }
    int fl = *flag;
    int base = 0;
    #pragma unroll
    for (int s = 0; s < 15; ++s) {
        if (i >= base && i < base + sz[s]) {
            int off = i - base;
            float v = fl ? __bfloat162float(((const __hip_bfloat16*)a.src[s])[off])
                         : ((const float*)a.src[s])[off];
            a.dst[s][off] = v;
        }
        base += sz[s];
    }
}

// ---------- all weight fragment tables in one kernel (42 blocks) ----------
__global__ __launch_bounds__(256) void k_prep_all(const float* __restrict__ We1,
                                                  const float* __restrict__ W2,
                                                  const float* __restrict__ Wf1,
                                                  const float* __restrict__ Wf2,
                                                  const float* __restrict__ We2,
                                                  short* WfU, short* WfV, short* WfW2,
                                                  short* WfF1, short* WfF2, short* We2f) {
    int b = blockIdx.x;
    const float* W; const float* Wm = nullptr; short* out; int NT = 8; int tid;
    if (b < 8)       { W = We1;      Wm = We1 + HH; out = WfU;  tid = b * 256 + threadIdx.x; }
    else if (b < 16) { W = We1 + HH; out = WfV;  tid = (b - 8) * 256 + threadIdx.x; }
    else if (b < 24) { W = W2;       out = WfW2; tid = (b - 16) * 256 + threadIdx.x; }
    else if (b < 32) { W = Wf1;      out = WfF1; tid = (b - 24) * 256 + threadIdx.x; }
    else if (b < 40) { W = We2;      out = We2f; tid = (b - 32) * 256 + threadIdx.x; }
    else             { W = Wf2;      out = WfF2; NT = 2; tid = (b - 40) * 256 + threadIdx.x; }
    int total = 4 * NT * 64;
    if (tid >= total) return;
    int kc = tid / (NT * 64);
    int ct = (tid / 64) % NT;
    int lane = tid & 63;
    int Nc = NT * 16;
    int kb = kc * 32 + (lane >> 4) * 8;
    int col = ct * 16 + (lane & 15);
    #pragma unroll
    for (int j = 0; j < 8; ++j) {
        float w = W[(kb + j) * Nc + col];
        if (Wm) w -= Wm[(kb + j) * Nc + col];
        out[tid * 8 + j] = f2b(w);
    }
}

// ---------- CSR build ----------
__global__ __launch_bounds__(256) void k_hist(const int* __restrict__ dst, int* cnt) {
    int e = blockIdx.x * 256 + threadIdx.x;
    if (e < N_EDGES) atomicAdd(&cnt[dst[e]], 1);
}

// dual exclusive scan (deg, ceil(deg/16)) + dis + per-graph counts
__global__ __launch_bounds__(256) void k_scan1d(const int* __restrict__ deg,
                                                int* __restrict__ outA, int* __restrict__ outB,
                                                int* __restrict__ bsA, int* __restrict__ bsB,
                                                float* __restrict__ dis,
                                                const int* __restrict__ batch,
                                                float* __restrict__ counts) {
    __shared__ int ldsA[256], ldsB[256];
    __shared__ float lc[G_GRAPHS];
    if (threadIdx.x < G_GRAPHS) lc[threadIdx.x] = 0.f;
    int base = blockIdx.x * 2048;
    int t = threadIdx.x;
    int localA[8], localB[8];
    int sA = 0, sB = 0;
    #pragma unroll
    for (int j = 0; j < 8; ++j) {
        int idx = base + t * 8 + j;
        int v = (idx < N_NODES) ? deg[idx] : 0;
        int tc = (v + 15) >> 4;
        localA[j] = sA; sA += v;
        localB[j] = sB; sB += tc;
        if (idx < N_NODES) {
            dis[idx] = rsqrtf((float)v + 1.0f);
            atomicAdd(&lc[batch[idx]], 1.0f);
        }
    }
    ldsA[t] = sA; ldsB[t] = sB;
    __syncthreads();
    if (t == 0) {
        int run = 0;
        for (int i = 0; i < 256; ++i) { int v = ldsA[i]; ldsA[i] = run; run += v; }
        bsA[blockIdx.x] = run;
        run = 0;
        for (int i = 0; i < 256; ++i) { int v = ldsB[i]; ldsB[i] = run; run += v; }
        bsB[blockIdx.x] = run;
    }
    __syncthreads();
    int oA = ldsA[t], oB = ldsB[t];
    #pragma unroll
    for (int j = 0; j < 8; ++j) {
        int idx = base + t * 8 + j;
        if (idx < N_NODES) { outA[idx] = oA + localA[j]; outB[idx] = oB + localB[j]; }
    }
    if (threadIdx.x < G_GRAPHS && lc[threadIdx.x] > 0.f)
        atomicAdd(&counts[threadIdx.x], lc[threadIdx.x]);
}

__global__ void k_scan2d(int* bsA, int* bsB, int nb, int* rowptr, int* tstart, int* ntiles) {
    int run = 0;
    for (int i = 0; i < nb; ++i) { int v = bsA[i]; bsA[i] = run; run += v; }
    rowptr[N_NODES] = N_EDGES;
    run = 0;
    for (int i = 0; i < nb; ++i) { int v = bsB[i]; bsB[i] = run; run += v; }
    tstart[N_NODES] = run;
    *ntiles = run;
}

__global__ __launch_bounds__(256) void k_scan3d(int* rowptr, int* tstart,
                                                const int* __restrict__ bsA,
                                                const int* __restrict__ bsB) {
    int idx = blockIdx.x * 256 + threadIdx.x;
    if (idx < N_NODES) {
        rowptr[idx] += bsA[idx >> 11];
        tstart[idx] += bsB[idx >> 11];
    }
}

// scatter: single packed write per edge. tileSrc slot = src | (dst << 16).
// (tiles of a node are contiguous: slot index = tstart[d]*16 + local)
__global__ __launch_bounds__(256) void k_scatter(const int* __restrict__ src, const int* __restrict__ dst,
                                                 const int* __restrict__ tstart,
                                                 int* cursor,
                                                 unsigned* __restrict__ tileSrc) {
    int e = blockIdx.x * 256 + threadIdx.x;
    if (e >= N_EDGES) return;
    int d = dst[e];
    int local = atomicSub(&cursor[d], 1) - 1;
    tileSrc[tstart[d] * 16 + local] = (unsigned)src[e] | ((unsigned)d << 16);
}

// tile pad: duplicate last edge into final tile's tail (packed)
__global__ __launch_bounds__(256) void k_tpad(const int* __restrict__ rowptr,
                                              const int* __restrict__ tstart,
                                              unsigned* __restrict__ tileSrc) {
    int n = blockIdx.x * 256 + threadIdx.x;
    if (n >= N_NODES) return;
    int deg = rowptr[n + 1] - rowptr[n];
    int rem = deg & 15;
    if (deg > 0 && rem) {
        int base = tstart[n] * 16;
        unsigned lastV = tileSrc[base + deg - 1];
        int tb = base + (deg & ~15);
        for (int j = rem; j < 16; ++j) tileSrc[tb + j] = lastV;
    }
}

// ---------- GCN1 GEMM: out = (x[M,9] @ W1[9,128]) * dis[row], bf16 ----------
__global__ __launch_bounds__(256) void k_gemm_f32bf_scale(const float* __restrict__ A,
                                                          const float* __restrict__ W,
                                                          const float* __restrict__ dis,
                                                          short* __restrict__ out, int M) {
    __shared__ float w_lds[F_IN * H];
    for (int i = threadIdx.x; i < F_IN * H; i += 256) w_lds[i] = W[i];
    __syncthreads();
    int row = blockIdx.x * 8 + threadIdx.x / 32;
    int c4 = (threadIdx.x & 31) << 2;
    if (row >= M) return;
    const float* a = A + (size_t)row * F_IN;
    float acc0 = 0.f, acc1 = 0.f, acc2 = 0.f, acc3 = 0.f;
    #pragma unroll
    for (int k = 0; k < F_IN; ++k) {
        float av = a[k];
        float4 w = *reinterpret_cast<const float4*>(&w_lds[k * H + c4]);
        acc0 = fmaf(av, w.x, acc0);
        acc1 = fmaf(av, w.y, acc1);
        acc2 = fmaf(av, w.z, acc2);
        acc3 = fmaf(av, w.w, acc3);
    }
    float dv = dis[row];
    uint2 o = make_uint2(cvtpk(acc0 * dv, acc1 * dv), cvtpk(acc2 * dv, acc3 * dv));
    *reinterpret_cast<uint2*>(&out[(size_t)row * H + c4]) = o;
}

// ---------- dual MFMA GEMM (512 thr): U = A@WU + be1 ; V = A@WV ; zero aggEnc strip ----------
__global__ __launch_bounds__(512) void k_gemm_dual(const short* __restrict__ A,
                                                   const short* __restrict__ WfU,
                                                   const short* __restrict__ WfV,
                                                   const float* __restrict__ be1,
                                                   short* __restrict__ U,
                                                   short* __restrict__ V,
                                                   unsigned* __restrict__ aggEnc, int M) {
    __shared__ short wl[32768];
    for (int i = threadIdx.x * 8; i < 16384; i += 4096) {
        *reinterpret_cast<f32x4*>(&wl[i])         = *reinterpret_cast<const f32x4*>(&WfU[i]);
        *reinterpret_cast<f32x4*>(&wl[16384 + i]) = *reinterpret_cast<const f32x4*>(&WfV[i]);
    }
    {
        int r0 = blockIdx.x * 128;
        uint4* base = reinterpret_cast<uint4*>(aggEnc + (size_t)r0 * H);
        const uint4 z = make_uint4(0, 0, 0, 0);
        #pragma unroll
        for (int i = 0; i < 8; ++i) {
            int idx = threadIdx.x + i * 512;
            int row = r0 + (idx >> 5);
            if (row < M) base[idx] = z;
        }
    }
    __syncthreads();
    int wv = threadIdx.x >> 6, lane = threadIdx.x & 63;
    int er = lane & 15, kg = lane >> 4;
    int row0 = (blockIdx.x * 8 + wv) * 16;
    if (row0 >= M) return;
    bf16x8 af[4];
    #pragma unroll
    for (int kc = 0; kc < 4; ++kc)
        af[kc] = *reinterpret_cast<const bf16x8*>(&A[(size_t)(row0 + er) * H + kc * 32 + kg * 8]);
    const f32x4 vzero = {0.f, 0.f, 0.f, 0.f};
    f32x4 acc[8];
    #pragma unroll
    for (int ct = 0; ct < 8; ++ct) acc[ct] = vzero;
    #pragma unroll
    for (int kc = 0; kc < 4; ++kc)
        #pragma unroll
        for (int ct = 0; ct < 8; ++ct) {
            bf16x8 bf = *reinterpret_cast<const bf16x8*>(&wl[((kc * 8 + ct) * 64 + lane) * 8]);
            acc[ct] = __builtin_amdgcn_mfma_f32_16x16x32_bf16(af[kc], bf, acc[ct], 0, 0, 0);
        }
    #pragma unroll
    for (int ct = 0; ct < 8; ++ct) {
        int col = ct * 16 + er;
        float bv = be1[col];
        #pragma unroll
        for (int r = 0; r < 4; ++r)
            U[(size_t)(row0 + kg * 4 + r) * H + col] = f2b(acc[ct][r] + bv);
    }
    #pragma unroll
    for (int ct = 0; ct < 8; ++ct) acc[ct] = vzero;
    #pragma unroll
    for (int kc = 0; kc < 4; ++kc)
        #pragma unroll
        for (int ct = 0; ct < 8; ++ct) {
            bf16x8 bf = *reinterpret_cast<const bf16x8*>(&wl[16384 + ((kc * 8 + ct) * 64 + lane) * 8]);
            acc[ct] = __builtin_amdgcn_mfma_f32_16x16x32_bf16(af[kc], bf, acc[ct], 0, 0, 0);
        }
    #pragma unroll
    for (int ct = 0; ct < 8; ++ct) {
        int col = ct * 16 + er;
        #pragma unroll
        for (int r = 0; r < 4; ++r)
            V[(size_t)(row0 + kg * 4 + r) * H + col] = f2b(acc[ct][r]);
    }
}

// ---------- MFMA GEMM reading EdgeConv aggregate (512 thr) ----------
__global__ __launch_bounds__(512) void k_gemm_scale_agg(const unsigned* __restrict__ aggEnc,
                                                        const float* __restrict__ be2,
                                                        const short* __restrict__ Wf,
                                                        const float* __restrict__ dis,
                                                        short* __restrict__ out, int M) {
    __shared__ short wl[16384];
    for (int i = threadIdx.x * 8; i < 16384; i += 4096)
        *reinterpret_cast<f32x4*>(&wl[i]) = *reinterpret_cast<const f32x4*>(&Wf[i]);
    __syncthreads();
    int wv = threadIdx.x >> 6, lane = threadIdx.x & 63;
    int er = lane & 15, kg = lane >> 4;
    int row0 = (blockIdx.x * 8 + wv) * 16;
    if (row0 >= M) return;
    bf16x8 af[4];
    #pragma unroll
    for (int kc = 0; kc < 4; ++kc) {
        int basec = kc * 32 + kg * 8;
        const unsigned* ap = &aggEnc[(size_t)(row0 + er) * H + basec];
        uint4 q0 = *reinterpret_cast<const uint4*>(ap);
        uint4 q1 = *reinterpret_cast<const uint4*>(ap + 4);
        float f0 = q0.x ? tanhf(decodef(q0.x) + be2[basec + 0]) : 0.f;
        float f1 = q0.y ? tanhf(decodef(q0.y) + be2[basec + 1]) : 0.f;
        float f2 = q0.z ? tanhf(decodef(q0.z) + be2[basec + 2]) : 0.f;
        float f3 = q0.w ? tanhf(decodef(q0.w) + be2[basec + 3]) : 0.f;
        float f4 = q1.x ? tanhf(decodef(q1.x) + be2[basec + 4]) : 0.f;
        float f5 = q1.y ? tanhf(decodef(q1.y) + be2[basec + 5]) : 0.f;
        float f6 = q1.z ? tanhf(decodef(q1.z) + be2[basec + 6]) : 0.f;
        float f7 = q1.w ? tanhf(decodef(q1.w) + be2[basec + 7]) : 0.f;
        union { unsigned u[4]; bf16x8 v; } Afr;
        Afr.u[0] = cvtpk(f0, f1); Afr.u[1] = cvtpk(f2, f3);
        Afr.u[2] = cvtpk(f4, f5); Afr.u[3] = cvtpk(f6, f7);
        af[kc] = Afr.v;
    }
    const f32x4 vzero = {0.f, 0.f, 0.f, 0.f};
    f32x4 acc[8];
    #pragma unroll
    for (int ct = 0; ct < 8; ++ct) acc[ct] = vzero;
    #pragma unroll
    for (int kc = 0; kc < 4; ++kc)
        #pragma unroll
        for (int ct = 0; ct < 8; ++ct) {
            bf16x8 bf = *reinterpret_cast<const bf16x8*>(&wl[((kc * 8 + ct) * 64 + lane) * 8]);
            acc[ct] = __builtin_amdgcn_mfma_f32_16x16x32_bf16(af[kc], bf, acc[ct], 0, 0, 0);
        }
    float dv[4];
    #pragma unroll
    for (int r = 0; r < 4; ++r) dv[r] = dis[row0 + kg * 4 + r];
    #pragma unroll
    for (int ct = 0; ct < 8; ++ct) {
        int col = ct * 16 + er;
        #pragma unroll
        for (int r = 0; r < 4; ++r)
            out[(size_t)(row0 + kg * 4 + r) * H + col] = f2b(acc[ct][r] * dv[r]);
    }
}

// ---------- GCN fused agg+combine (packed tileSrc as CSR, packed-f32 accumulation) ----------
__global__ __launch_bounds__(256) void k_gcn_fused(const int* __restrict__ rowptr,
                                                   const int* __restrict__ tstart,
                                                   const unsigned* __restrict__ tileSrc,
                                                   const short* __restrict__ hWs,
                                                   const float* __restrict__ dis,
                                                   const float* __restrict__ bias,
                                                   short* __restrict__ out) {
    int wv = threadIdx.x >> 6, lane = threadIdx.x & 63;
    const unsigned* hw = (const unsigned*)hWs;
    const f32x2 z2 = {0.f, 0.f};
    for (int n = blockIdx.x * 4 + wv; n < N_NODES; n += gridDim.x * 4) {
        int deg = rowptr[n + 1] - rowptr[n];
        const unsigned* es = &tileSrc[tstart[n] * 16];
        f32x2 sa = z2, sb = z2, sc = z2, sd = z2;
        int e = 0;
        for (; e + 8 <= deg; e += 8) {
            int s0 = es[e] & 0xFFFF,     s1 = es[e + 1] & 0xFFFF;
            int s2 = es[e + 2] & 0xFFFF, s3 = es[e + 3] & 0xFFFF;
            int s4 = es[e + 4] & 0xFFFF, s5 = es[e + 5] & 0xFFFF;
            int s6 = es[e + 6] & 0xFFFF, s7 = es[e + 7] & 0xFFFF;
            unsigned w0 = hw[(size_t)s0 * 64 + lane];
            unsigned w1 = hw[(size_t)s1 * 64 + lane];
            unsigned w2 = hw[(size_t)s2 * 64 + lane];
            unsigned w3 = hw[(size_t)s3 * 64 + lane];
            unsigned w4 = hw[(size_t)s4 * 64 + lane];
            unsigned w5 = hw[(size_t)s5 * 64 + lane];
            unsigned w6 = hw[(size_t)s6 * 64 + lane];
            unsigned w7 = hw[(size_t)s7 * 64 + lane];
            sa += up2(w0); sb += up2(w1); sc += up2(w2); sd += up2(w3);
            sa += up2(w4); sb += up2(w5); sc += up2(w6); sd += up2(w7);
        }
        for (; e + 4 <= deg; e += 4) {
            int s0 = es[e] & 0xFFFF,     s1 = es[e + 1] & 0xFFFF;
            int s2 = es[e + 2] & 0xFFFF, s3 = es[e + 3] & 0xFFFF;
            unsigned w0 = hw[(size_t)s0 * 64 + lane];
            unsigned w1 = hw[(size_t)s1 * 64 + lane];
            unsigned w2 = hw[(size_t)s2 * 64 + lane];
            unsigned w3 = hw[(size_t)s3 * 64 + lane];
            sa += up2(w0); sb += up2(w1); sc += up2(w2); sd += up2(w3);
        }
        for (; e < deg; ++e) sa += up2(hw[(size_t)(es[e] & 0xFFFF) * 64 + lane]);
        f32x2 s = (sa + sb) + (sc + sd);
        float dn = dis[n];
        f32x2 wn2 = up2(hw[(size_t)n * 64 + lane]);
        float r0 = tanhf(dn * (s.x + wn2.x) + bias[lane * 2]);
        float r1 = tanhf(dn * (s.y + wn2.y) + bias[lane * 2 + 1]);
        *reinterpret_cast<unsigned*>(&out[(size_t)n * H + lane * 2]) = cvtpk(r0, r1);
    }
}

// ---------- EdgeConv: persistent blocks, one wave per 16-edge tile, packed tileSrc ----------
__global__ __launch_bounds__(512) void k_edge_tile(const unsigned* __restrict__ tileSrc,
                                                   const int* __restrict__ ntilesp,
                                                   const short* __restrict__ U,
                                                   const short* __restrict__ V,
                                                   const short* __restrict__ We2f,
                                                   unsigned* aggEnc) {
    __shared__ short wl[16384];
    for (int i = threadIdx.x * 8; i < 16384; i += 4096)
        *reinterpret_cast<f32x4*>(&wl[i]) = *reinterpret_cast<const f32x4*>(&We2f[i]);
    __syncthreads();
    int nt = *ntilesp;
    int wv = threadIdx.x >> 6, lane = threadIdx.x & 63;
    int er = lane & 15, kg = lane >> 4, kseg = kg * 8;
    const f32x4 vzero = {0.f, 0.f, 0.f, 0.f};
    const f32x2 z2 = {0.f, 0.f};
    for (int tid = blockIdx.x * 8 + wv; tid < nt; tid += gridDim.x * 8) {
        unsigned pk = tileSrc[tid * 16 + er];
        int s = pk & 0xFFFF;
        int n = pk >> 16;                      // uniform across the wave
        f32x4 acc[8];
        #pragma unroll
        for (int ct = 0; ct < 8; ++ct) acc[ct] = vzero;
        #pragma unroll
        for (int kc = 0; kc < 4; ++kc) {
            uint4 uu4 = *reinterpret_cast<const uint4*>(&U[(size_t)n * H + kc * 32 + kseg]);
            uint4 vv4 = *reinterpret_cast<const uint4*>(&V[(size_t)s * H + kc * 32 + kseg]);
            union { unsigned u[4]; bf16x8 v; } A;
            f32x2 t;
            t = __builtin_elementwise_max(up2(uu4.x) + up2(vv4.x), z2); A.u[0] = cvtpk(t.x, t.y);
            t = __builtin_elementwise_max(up2(uu4.y) + up2(vv4.y), z2); A.u[1] = cvtpk(t.x, t.y);
            t = __builtin_elementwise_max(up2(uu4.z) + up2(vv4.z), z2); A.u[2] = cvtpk(t.x, t.y);
            t = __builtin_elementwise_max(up2(uu4.w) + up2(vv4.w), z2); A.u[3] = cvtpk(t.x, t.y);
            #pragma unroll
            for (int ct = 0; ct < 8; ++ct) {
                bf16x8 bf = *reinterpret_cast<const bf16x8*>(&wl[((kc * 8 + ct) * 64 + lane) * 8]);
                acc[ct] = __builtin_amdgcn_mfma_f32_16x16x32_bf16(A.v, bf, acc[ct], 0, 0, 0);
            }
        }
        float cm[8];
        #pragma unroll
        for (int ct = 0; ct < 8; ++ct) {
            float v = fmaxf(fmaxf(fmaxf(acc[ct][0], acc[ct][1]), acc[ct][2]), acc[ct][3]);
            v = fmaxf(v, __shfl_xor(v, 16));
            v = fmaxf(v, __shfl_xor(v, 32));
            cm[ct] = v;
        }
        float vA, vB;
        if (kg == 0)      { vA = cm[0]; vB = cm[1]; }
        else if (kg == 1) { vA = cm[2]; vB = cm[3]; }
        else if (kg == 2) { vA = cm[4]; vB = cm[5]; }
        else              { vA = cm[6]; vB = cm[7]; }
        int colA = (kg * 2) * 16 + er;
        int colB = (kg * 2 + 1) * 16 + er;
        atomicMax(&aggEnc[(size_t)n * H + colA], encodef(vA));
        atomicMax(&aggEnc[(size_t)n * H + colB], encodef(vB));
    }
}

// ---------- fused final MLP + pooling, reading EdgeConv aggregate directly ----------
__global__ __launch_bounds__(512) void k_final_mlp_agg(const unsigned* __restrict__ aggEnc,
                                                       const float* __restrict__ be2,
                                                       const short* __restrict__ WfF1,
                                                       const short* __restrict__ WfF2,
                                                       const float* __restrict__ bf1,
                                                       const float* __restrict__ bf2,
                                                       const float* __restrict__ Wf3,
                                                       const float* __restrict__ bf3,
                                                       const int* __restrict__ batch,
                                                       float* pooled, int M) {
    __shared__ short wl1[16384];
    __shared__ short wl2[4096];
    __shared__ short tb[8][2048];
    __shared__ float lp[G_GRAPHS];
    for (int i = threadIdx.x * 8; i < 16384; i += 4096)
        *reinterpret_cast<f32x4*>(&wl1[i]) = *reinterpret_cast<const f32x4*>(&WfF1[i]);
    {
        int i = threadIdx.x * 8;
        if (i < 4096)
            *reinterpret_cast<f32x4*>(&wl2[i]) = *reinterpret_cast<const f32x4*>(&WfF2[i]);
    }
    if (threadIdx.x < G_GRAPHS) lp[threadIdx.x] = 0.f;
    __syncthreads();
    int wv = threadIdx.x >> 6, lane = threadIdx.x & 63;
    int er = lane & 15, kg = lane >> 4;
    int row0 = (blockIdx.x * 8 + wv) * 16;
    bool active = row0 < M;
    const f32x4 vzero = {0.f, 0.f, 0.f, 0.f};
    if (active) {
        bf16x8 af[4];
        #pragma unroll
        for (int kc = 0; kc < 4; ++kc) {
            int basec = kc * 32 + kg * 8;
            const unsigned* ap = &aggEnc[(size_t)(row0 + er) * H + basec];
            uint4 q0 = *reinterpret_cast<const uint4*>(ap);
            uint4 q1 = *reinterpret_cast<const uint4*>(ap + 4);
            float f0 = q0.x ? tanhf(decodef(q0.x) + be2[basec + 0]) : 0.f;
            float f1 = q0.y ? tanhf(decodef(q0.y) + be2[basec + 1]) : 0.f;
            float f2 = q0.z ? tanhf(decodef(q0.z) + be2[basec + 2]) : 0.f;
            float f3 = q0.w ? tanhf(decodef(q0.w) + be2[basec + 3]) : 0.f;
            float f4 = q1.x ? tanhf(decodef(q1.x) + be2[basec + 4]) : 0.f;
            float f5 = q1.y ? tanhf(decodef(q1.y) + be2[basec + 5]) : 0.f;
            float f6 = q1.z ? tanhf(decodef(q1.z) + be2[basec + 6]) : 0.f;
            float f7 = q1.w ? tanhf(decodef(q1.w) + be2[basec + 7]) : 0.f;
            union { unsigned u[4]; bf16x8 v; } A;
            A.u[0] = cvtpk(f0, f1); A.u[1] = cvtpk(f2, f3);
            A.u[2] = cvtpk(f4, f5); A.u[3] = cvtpk(f6, f7);
            af[kc] = A.v;
        }
        f32x4 acc[8];
        #pragma unroll
        for (int ct = 0; ct < 8; ++ct) acc[ct] = vzero;
        #pragma unroll
        for (int kc = 0; kc < 4; ++kc)
            #pragma unroll
            for (int ct = 0; ct < 8; ++ct) {
                bf16x8 bf = *reinterpret_cast<const bf16x8*>(&wl1[((kc * 8 + ct) * 64 + lane) * 8]);
                acc[ct] = __builtin_amdgcn_mfma_f32_16x16x32_bf16(af[kc], bf, acc[ct], 0, 0, 0);
            }
        #pragma unroll
        for (int ct = 0; ct < 8; ++ct) {
            int col = ct * 16 + er;
            float bv = bf1[col];
            #pragma unroll
            for (int r = 0; r < 4; ++r)
                tb[wv][(kg * 4 + r) * 128 + col] = f2b(tanhf(acc[ct][r] + bv));
        }
    }
    __syncthreads();
    if (active) {
        bf16x8 af2[4];
        #pragma unroll
        for (int kc = 0; kc < 4; ++kc)
            af2[kc] = *reinterpret_cast<const bf16x8*>(&tb[wv][er * 128 + kc * 32 + kg * 8]);
        f32x4 a2[2];
        a2[0] = vzero; a2[1] = vzero;
        #pragma unroll
        for (int kc = 0; kc < 4; ++kc)
            #pragma unroll
            for (int ct = 0; ct < 2; ++ct) {
                bf16x8 bf = *reinterpret_cast<const bf16x8*>(&wl2[((kc * 2 + ct) * 64 + lane) * 8]);
                a2[ct] = __builtin_amdgcn_mfma_f32_16x16x32_bf16(af2[kc], bf, a2[ct], 0, 0, 0);
            }
        float w3a = Wf3[er], w3b = Wf3[16 + er];
        float b2a = bf2[er], b2b = bf2[16 + er];
        float bf3v = bf3[0];
        float psum[4];
        #pragma unroll
        for (int r = 0; r < 4; ++r) {
            float f2a = tanhf(a2[0][r] + b2a);
            float f2c = tanhf(a2[1][r] + b2b);
            float p = f2a * w3a + f2c * w3b;
            p += __shfl_xor(p, 1);
            p += __shfl_xor(p, 2);
            p += __shfl_xor(p, 4);
            p += __shfl_xor(p, 8);
            psum[r] = p + bf3v;
        }
        if (er == 0) {
            #pragma unroll
            for (int r = 0; r < 4; ++r) {
                int n = row0 + kg * 4 + r;
                if (n < M) atomicAdd(&lp[batch[n]], psum[r]);
            }
        }
    }
    __syncthreads();
    if (threadIdx.x < G_GRAPHS && lp[threadIdx.x] != 0.f)
        atomicAdd(&pooled[threadIdx.x], lp[threadIdx.x]);
}

__global__ __launch_bounds__(64) void k_final(const float* pooled, const float* counts,
                                              void* out, const int* __restrict__ flag) {
    int g = threadIdx.x;
    if (g < G_GRAPHS) {
        float v = pooled[g] / fmaxf(counts[g], 1.0f);
        float s = 1.0f / (1.0f + expf(-v));
        if (*flag) ((__hip_bfloat16*)out)[g] = __float2bfloat16(s);
        else       ((float*)out)[g] = s;
    }
}

extern "C" void kernel_launch(void* const* d_in, const int* in_sizes, int n_in,
                              void* d_out, int out_size, void* d_ws, size_t ws_size,
                              hipStream_t stream) {
    const int* ei    = (const int*)d_in[1];
    const int* src   = ei;
    const int* dst   = ei + N_EDGES;
    const int* batch = (const int*)d_in[2];

    float* ws = (float*)d_ws;
    size_t off = 0;
    auto alloc = [&](size_t n) { off = (off + 3) & ~(size_t)3; float* p = ws + off; off += n; return p; };

    const size_t NH = (size_t)N_NODES * H;
    short* hb     = (short*)alloc(NH / 2);
    short* Ub     = (short*)alloc(NH / 2);
    short* Vb     = (short*)alloc(NH / 2);
    unsigned* aggEnc = (unsigned*)alloc(NH);
    float* xf     = alloc((size_t)N_NODES * F_IN);
    float* dis    = alloc(N_NODES);
    float* pooled = alloc(G_GRAPHS);
    float* counts = alloc(G_GRAPHS);
    int*   flag   = (int*)alloc(1);
    int*   rowptr = (int*)alloc(N_NODES + 1);
    int*   cursor = (int*)alloc(N_NODES);
    int*   bsums  = (int*)alloc(32);
    int*   bsums2 = (int*)alloc(32);
    int*   tstart = (int*)alloc(N_NODES + 1);
    int*   ntiles = (int*)alloc(1);
    unsigned* tileSrc = (unsigned*)alloc((size_t)MAXT * 16);

    float* W1  = alloc(F_IN * H);
    float* b1  = alloc(H);
    float* W2  = alloc(HH);
    float* b2  = alloc(H);
    float* We1 = alloc(2 * HH);
    float* be1 = alloc(H);
    float* We2 = alloc(HH);
    float* be2 = alloc(H);
    float* Wf1 = alloc(HH);
    float* bf1 = alloc(H);
    float* Wf2 = alloc(H * 32);
    float* bf2 = alloc(32);
    float* Wf3 = alloc(32);
    float* bf3 = alloc(4);
    short* WfU  = (short*)alloc(8192);
    short* WfV  = (short*)alloc(8192);
    short* WfW2 = (short*)alloc(8192);
    short* WfF1 = (short*)alloc(8192);
    short* WfF2 = (short*)alloc(2048);
    short* We2f = (short*)alloc(8192);

    const int eB    = (N_EDGES + 255) / 256;
    const int nB    = (N_NODES + 255) / 256;
    const int scanB = (N_NODES + 2047) / 2048;
    const int mfmaB = (N_NODES / 16 + 7) / 8;      // 391 blocks of 512
    const int gcnB  = (N_NODES + 3) / 4;           // 12500
    const int edgeB = 1024;                        // persistent grid-stride

    k_detect<<<1, 256, 0, stream>>>((const unsigned*)d_in[0], flag, pooled, counts);

    CvtArgs ca;
    const int srcIdx[15] = {0, 3, 4, 5, 6, 7, 8, 9, 10, 11, 12, 13, 14, 15, 16};
    float* dsts[15] = {xf, W1, b1, W2, b2, We1, be1, We2, be2, Wf1, bf1, Wf2, bf2, Wf3, bf3};
    for (int s = 0; s < 15; ++s) { ca.src[s] = d_in[srcIdx[s]]; ca.dst[s] = dsts[s]; }
    const int cvtTotal = 537873 + N_NODES;         // + cursor zero range
    k_cvt_all<<<(cvtTotal + 255) / 256, 256, 0, stream>>>(ca, flag, cursor);

    k_prep_all<<<42, 256, 0, stream>>>(We1, W2, Wf1, Wf2, We2,
                                       WfU, WfV, WfW2, WfF1, WfF2, We2f);

    // CSR + tile-list build (packed tileSrc doubles as CSR)
    k_hist<<<eB, 256, 0, stream>>>(dst, cursor);
    k_scan1d<<<scanB, 256, 0, stream>>>(cursor, rowptr, tstart, bsums, bsums2,
                                        dis, batch, counts);
    k_scan2d<<<1, 1, 0, stream>>>(bsums, bsums2, scanB, rowptr, tstart, ntiles);
    k_scan3d<<<nB, 256, 0, stream>>>(rowptr, tstart, bsums, bsums2);
    k_scatter<<<eB, 256, 0, stream>>>(src, dst, tstart, cursor, tileSrc);
    k_tpad<<<nB, 256, 0, stream>>>(rowptr, tstart, tileSrc);

    // GCN1
    k_gemm_f32bf_scale<<<(N_NODES + 7) / 8, 256, 0, stream>>>(xf, W1, dis, Ub, N_NODES);
    k_gcn_fused<<<gcnB, 256, 0, stream>>>(rowptr, tstart, tileSrc, Ub, dis, b1, hb);

    for (int iter = 0; iter < 3; ++iter) {
        k_gemm_dual<<<mfmaB, 512, 0, stream>>>(hb, WfU, WfV, be1, Ub, Vb, aggEnc, N_NODES);
        k_edge_tile<<<edgeB, 512, 0, stream>>>(tileSrc, ntiles, Ub, Vb, We2f, aggEnc);
        if (iter < 2) {
            k_gemm_scale_agg<<<mfmaB, 512, 0, stream>>>(aggEnc, be2, WfW2, dis, Ub, N_NODES);
            k_gcn_fused<<<gcnB, 256, 0, stream>>>(rowptr, tstart, tileSrc, Ub, dis, b2, hb);
        }
    }

    k_final_mlp_agg<<<mfmaB, 512, 0, stream>>>(aggEnc, be2, WfF1, WfF2, bf1, bf2, Wf3, bf3,
                                               batch, pooled, N_NODES);
    k_final<<<1, 64, 0, stream>>>(pooled, counts, d_out, flag);
}